// Round 5
// baseline (599.397 us; speedup 1.0000x reference)
//
#include <hip/hip_runtime.h>

typedef unsigned short u16;
typedef unsigned int u32;
typedef short short8 __attribute__((ext_vector_type(8)));
typedef float float4v __attribute__((ext_vector_type(4)));

#define L_SEQ 1024
#define NB 4
#define NH 16
#define DK 128
#define DV 128
#define HID 2048
#define NQKVZ 8192
#define CONV_DIM 6144
#define GDN_SCALE 0.08838834764831845f  // 128^-0.5

static __device__ __forceinline__ float bf2f(u16 u) {
    union { u32 i; float f; } x; x.i = ((u32)u) << 16; return x.f;
}
static __device__ __forceinline__ u16 f2bf(float f) {
    union { float f; u32 u; } x; x.f = f;
    u32 r = x.u + 0x7FFF + ((x.u >> 16) & 1);
    return (u16)(r >> 16);
}

union FragU { short8 v; uint4 u; };

// async global->LDS, 16B per lane (lane-contiguous LDS dest required).
#define GLOAD_LDS16(g, l)                                        \
    __builtin_amdgcn_global_load_lds(                            \
        (const __attribute__((address_space(1))) void*)(g),      \
        (__attribute__((address_space(3))) void*)(l), 16, 0, 0)

// ---------------- fp32 -> bf16 elementwise convert ---------------------------
__global__ __launch_bounds__(256) void f32_to_bf16(
    const float* __restrict__ in, u16* __restrict__ out) {
    long i = ((long)blockIdx.x * 256 + threadIdx.x) * 8;
    float4 a = *(const float4*)(in + i);
    float4 b = *(const float4*)(in + i + 4);
    u16 tmp[8];
    tmp[0] = f2bf(a.x); tmp[1] = f2bf(a.y); tmp[2] = f2bf(a.z); tmp[3] = f2bf(a.w);
    tmp[4] = f2bf(b.x); tmp[5] = f2bf(b.y); tmp[6] = f2bf(b.z); tmp[7] = f2bf(b.w);
    *(uint4*)(out + i) = *(const uint4*)tmp;
}

// ---------------- transpose fp32 (RxC) -> bf16 (CxR) -------------------------
__global__ __launch_bounds__(256) void transpose_f32_bf16(
    const float* __restrict__ in, u16* __restrict__ out, int R, int C) {
    __shared__ float tile[32][33];
    int bx = blockIdx.x, by = blockIdx.y;
    int c = threadIdx.x & 31;
    int r0 = threadIdx.x >> 5;
#pragma unroll
    for (int i = 0; i < 4; i++) {
        int r = r0 + i * 8;
        tile[r][c] = in[(long)(by * 32 + r) * C + bx * 32 + c];
    }
    __syncthreads();
#pragma unroll
    for (int i = 0; i < 4; i++) {
        int r = r0 + i * 8;
        out[(long)(bx * 32 + r) * R + by * 32 + c] = f2bf(tile[c][r]);
    }
}

// ---------------- GEMM (m97 structure): C = A * BT^T, bf16 in, OutT out ------
#define BM 128
#define BN 128
#define BKK 32

static __device__ __forceinline__ void store_out(u16* p, float v)  { *p = f2bf(v); }
static __device__ __forceinline__ void store_out(float* p, float v){ *p = v; }

template <typename OutT>
__global__ __launch_bounds__(256) void gemm_abT(
    const u16* __restrict__ A, const u16* __restrict__ BT,
    OutT* __restrict__ C, int M, int N, int K) {
    __shared__ u16 As[BM * BKK];
    __shared__ u16 Bs[BN * BKK];
    int t = threadIdx.x;
    int lane = t & 63;
    int w = t >> 6;
    int wm = (w & 1) * 64;
    int wn = (w >> 1) * 64;
    int l15 = lane & 15;
    int quad = lane >> 4;
    long blockM = (long)blockIdx.y * BM;
    long blockN = (long)blockIdx.x * BN;

    float4v acc[4][4];
#pragma unroll
    for (int i = 0; i < 4; i++)
#pragma unroll
        for (int j = 0; j < 4; j++) acc[i][j] = (float4v){0.f, 0.f, 0.f, 0.f};

    const u16* Ab = A + blockM * K;
    const u16* Bb = BT + blockN * K;

    const int r0 = t >> 2,         c0 = (t & 3) * 8;
    const int r1 = (t + 256) >> 2, c1 = ((t + 256) & 3) * 8;
    u16* As0 = As + t * 8;         u16* As1 = As + (t + 256) * 8;
    u16* Bs0 = Bs + t * 8;         u16* Bs1 = Bs + (t + 256) * 8;
    const u16* Ag0 = Ab + (long)r0 * K + c0;
    const u16* Ag1 = Ab + (long)r1 * K + c1;
    const u16* Bg0 = Bb + (long)r0 * K + c0;
    const u16* Bg1 = Bb + (long)r1 * K + c1;

    for (int k0 = 0; k0 < K; k0 += BKK) {
        __syncthreads();
        GLOAD_LDS16(Ag0 + k0, As0);
        GLOAD_LDS16(Ag1 + k0, As1);
        GLOAD_LDS16(Bg0 + k0, Bs0);
        GLOAD_LDS16(Bg1 + k0, Bs1);
        __syncthreads();

        FragU fa[4], fb[4];
#pragma unroll
        for (int i = 0; i < 4; i++) {
            fa[i].u = *(const uint4*)(As + (wm + i * 16 + l15) * BKK + quad * 8);
            fb[i].u = *(const uint4*)(Bs + (wn + i * 16 + l15) * BKK + quad * 8);
        }
#pragma unroll
        for (int i = 0; i < 4; i++)
#pragma unroll
            for (int j = 0; j < 4; j++)
                acc[i][j] = __builtin_amdgcn_mfma_f32_16x16x32_bf16(
                    fa[i].v, fb[j].v, acc[i][j], 0, 0, 0);
    }

#pragma unroll
    for (int i = 0; i < 4; i++) {
        long mrow = blockM + wm + i * 16 + quad * 4;
#pragma unroll
        for (int j = 0; j < 4; j++) {
            long col = blockN + wn + j * 16 + l15;
#pragma unroll
            for (int r = 0; r < 4; r++) {
                store_out(&C[(mrow + r) * N + col], acc[i][j][r]);
            }
        }
    }
}

// ---------------- GEMM1: 256x256 tile, BK=64, m201-style 4-phase groups ------
// (r2 schedule, measured 130 us / MfmaUtil 47.6 — FROZEN, r3 remap regressed)
#define G1_LDSU 32768  // u16 per dbuf (64 KB)

__global__ __launch_bounds__(512, 2) void gemm1_8ph(
    const u16* __restrict__ A, const u16* __restrict__ BT,
    u16* __restrict__ C) {
    const int K = HID, N = NQKVZ;
    __shared__ __align__(16) u16 lds[2 * G1_LDSU];  // 128 KB

    int t = threadIdx.x;
    int lane = t & 63, w = t >> 6, l15 = lane & 15, quad = lane >> 4;
    int wm = w & 1, wn = w >> 1;

    // XCD patch swizzle: 512 wgs, XCD = orig&7 owns patch of 8x8 tiles
    int orig = blockIdx.x;
    int wg = (orig & 7) * 64 + (orig >> 3);
    int p = wg >> 6, q = wg & 63;
    long blockM = (long)((p >> 2) * 8 + (q >> 3)) * 256;  // 0..15
    long blockN = (long)((p & 3) * 8 + (q & 7)) * 256;    // 0..31

    int srow = t >> 3;
    int scol = ((t & 7) ^ (srow & 7)) * 8;
    const u16* Ast = A + (blockM + srow) * (long)K + scol;
    const u16* Bst = BT + (blockN + srow) * (long)K + scol;

#define STA(db, qq, T) GLOAD_LDS16(Ast + (long)(qq) * 64 * K + (T) * 64,      \
                                   lds + (db) * G1_LDSU + (qq) * 4096 + t * 8)
#define STB(db, qq, T) GLOAD_LDS16(Bst + (long)(qq) * 64 * K + (T) * 64,      \
                                   lds + (db) * G1_LDSU + 16384 + (qq) * 4096 + t * 8)

    const int rowA0 = (wm * 128 + l15) * 64;
    const int rowB0 = 16384 + (wn * 64 + l15) * 64;
    const int cs0 = ((quad) ^ (l15 & 7)) * 8;        // kk=0 chunk
    const int cs1 = ((4 + quad) ^ (l15 & 7)) * 8;    // kk=1 chunk

    float4v acc[8][4];
#pragma unroll
    for (int mi = 0; mi < 8; mi++)
#pragma unroll
        for (int nj = 0; nj < 4; nj++) acc[mi][nj] = (float4v){0.f, 0.f, 0.f, 0.f};

    STA(0, 0, 0); STA(0, 1, 0); STA(0, 2, 0); STA(0, 3, 0);
    STB(0, 0, 0); STB(0, 1, 0); STB(0, 2, 0); STB(0, 3, 0);
    STA(1, 0, 1); STA(1, 2, 1);
    asm volatile("s_waitcnt vmcnt(2)" ::: "memory");
    __builtin_amdgcn_s_barrier();

    FragU bA[4][2], bB0[2][2], bB1[2][2];

    for (int g = 0; g < 32; ++g) {
        const int c = g & 1, db = c ^ 1;
        const u16* sb = lds + c * G1_LDSU;

        // ---- ph1 (mh0,nh0): 8 A-reads + 4 B-reads; stage T(g+1).Aq1,Aq3 ----
#pragma unroll
        for (int i = 0; i < 4; i++) {
            bA[i][0].u = *(const uint4*)(sb + rowA0 + i * 1024 + cs0);
            bA[i][1].u = *(const uint4*)(sb + rowA0 + i * 1024 + cs1);
        }
#pragma unroll
        for (int j = 0; j < 2; j++) {
            bB0[j][0].u = *(const uint4*)(sb + rowB0 + j * 1024 + cs0);
            bB0[j][1].u = *(const uint4*)(sb + rowB0 + j * 1024 + cs1);
        }
        if (g + 1 < 32) { STA(db, 1, g + 1); STA(db, 3, g + 1); }
        __builtin_amdgcn_s_barrier();
        asm volatile("s_waitcnt lgkmcnt(0)" ::: "memory");
        __builtin_amdgcn_s_setprio(1);
#pragma unroll
        for (int i = 0; i < 4; i++)
#pragma unroll
            for (int j = 0; j < 2; j++) {
                acc[i][j] = __builtin_amdgcn_mfma_f32_16x16x32_bf16(
                    bA[i][0].v, bB0[j][0].v, acc[i][j], 0, 0, 0);
                acc[i][j] = __builtin_amdgcn_mfma_f32_16x16x32_bf16(
                    bA[i][1].v, bB0[j][1].v, acc[i][j], 0, 0, 0);
            }
        __builtin_amdgcn_s_setprio(0);

        // ---- ph2 (mh0,nh1): 4 B-reads; stage T(g+1).Bq0,Bq1 ----
#pragma unroll
        for (int j = 0; j < 2; j++) {
            bB1[j][0].u = *(const uint4*)(sb + rowB0 + (2 + j) * 1024 + cs0);
            bB1[j][1].u = *(const uint4*)(sb + rowB0 + (2 + j) * 1024 + cs1);
        }
        if (g + 1 < 32) { STB(db, 0, g + 1); STB(db, 1, g + 1); }
        __builtin_amdgcn_s_barrier();
        asm volatile("s_waitcnt lgkmcnt(0)" ::: "memory");
        __builtin_amdgcn_s_setprio(1);
#pragma unroll
        for (int i = 0; i < 4; i++)
#pragma unroll
            for (int j = 0; j < 2; j++) {
                acc[i][2 + j] = __builtin_amdgcn_mfma_f32_16x16x32_bf16(
                    bA[i][0].v, bB1[j][0].v, acc[i][2 + j], 0, 0, 0);
                acc[i][2 + j] = __builtin_amdgcn_mfma_f32_16x16x32_bf16(
                    bA[i][1].v, bB1[j][1].v, acc[i][2 + j], 0, 0, 0);
            }
        __builtin_amdgcn_s_setprio(0);

        // ---- ph3 (mh1,nh0): 8 A-reads; stage T(g+1).Bq2,Bq3 ----
#pragma unroll
        for (int i = 0; i < 4; i++) {
            bA[i][0].u = *(const uint4*)(sb + rowA0 + (4 + i) * 1024 + cs0);
            bA[i][1].u = *(const uint4*)(sb + rowA0 + (4 + i) * 1024 + cs1);
        }
        if (g + 1 < 32) { STB(db, 2, g + 1); STB(db, 3, g + 1); }
        __builtin_amdgcn_s_barrier();
        asm volatile("s_waitcnt lgkmcnt(0)" ::: "memory");
        __builtin_amdgcn_s_setprio(1);
#pragma unroll
        for (int i = 0; i < 4; i++)
#pragma unroll
            for (int j = 0; j < 2; j++) {
                acc[4 + i][j] = __builtin_amdgcn_mfma_f32_16x16x32_bf16(
                    bA[i][0].v, bB0[j][0].v, acc[4 + i][j], 0, 0, 0);
                acc[4 + i][j] = __builtin_amdgcn_mfma_f32_16x16x32_bf16(
                    bA[i][1].v, bB0[j][1].v, acc[4 + i][j], 0, 0, 0);
            }
        __builtin_amdgcn_s_setprio(0);

        // ---- ph4 (mh1,nh1): 0 reads; stage T(g+2).Aq0,Aq2 into CURRENT dbuf
#pragma unroll
        for (int i = 0; i < 4; i++) { (void)0; }
        if (g + 2 < 32) { STA(c, 0, g + 2); STA(c, 2, g + 2); }
        __builtin_amdgcn_s_barrier();
        __builtin_amdgcn_s_setprio(1);
#pragma unroll
        for (int i = 0; i < 4; i++)
#pragma unroll
            for (int j = 0; j < 2; j++) {
                acc[4 + i][2 + j] = __builtin_amdgcn_mfma_f32_16x16x32_bf16(
                    bA[i][0].v, bB1[j][0].v, acc[4 + i][2 + j], 0, 0, 0);
                acc[4 + i][2 + j] = __builtin_amdgcn_mfma_f32_16x16x32_bf16(
                    bA[i][1].v, bB1[j][1].v, acc[4 + i][2 + j], 0, 0, 0);
            }
        __builtin_amdgcn_s_setprio(0);

        if (g < 30)       { asm volatile("s_waitcnt vmcnt(2)" ::: "memory"); }
        else if (g == 30) { asm volatile("s_waitcnt vmcnt(0)" ::: "memory"); }
        __builtin_amdgcn_s_barrier();
    }

#pragma unroll
    for (int mi = 0; mi < 8; mi++) {
        long row0 = blockM + wm * 128 + mi * 16 + quad * 4;
#pragma unroll
        for (int nj = 0; nj < 4; nj++) {
            long col = blockN + wn * 64 + nj * 16 + l15;
#pragma unroll
            for (int r = 0; r < 4; r++)
                C[(row0 + r) * N + col] = f2bf(acc[mi][nj][r]);
        }
    }
#undef STA
#undef STB
}

// ---------------- GEMM2: 256x128 tile, BK=64, 2-phase, counted vmcnt ---------
#define G2_LDSU 24576  // u16 per dbuf (48 KB)

__global__ __launch_bounds__(512) void gemm2_2ph(
    const u16* __restrict__ A, const u16* __restrict__ BT,
    float* __restrict__ C) {
    const int K = HID, N = 2048;
    __shared__ __align__(16) u16 lds[2 * G2_LDSU];  // 96 KB

    int t = threadIdx.x;
    int lane = t & 63, w = t >> 6, l15 = lane & 15, quad = lane >> 4;
    int wm = w & 1, wn = w >> 1;

    int orig = blockIdx.x;
    int x = orig & 7, q = orig >> 3;           // q in 0..31
    long blockM = (long)((x >> 2) * 8 + (q >> 2)) * 256;   // 0..15
    long blockN = (long)((x & 3) * 4 + (q & 3)) * 128;     // 0..15

    int srow = t >> 3;
    int scol = ((t & 7) ^ (srow & 7)) * 8;
    const u16* Ast = A + (blockM + srow) * (long)K + scol;
    const u16* Bst = BT + (blockN + srow) * (long)K + scol;

#define STA2(db, qq, T) GLOAD_LDS16(Ast + (long)(qq) * 64 * K + (T) * 64,     \
                                    lds + (db) * G2_LDSU + (qq) * 4096 + t * 8)
#define STB2(db, hh, T) GLOAD_LDS16(Bst + (long)(hh) * 64 * K + (T) * 64,     \
                                    lds + (db) * G2_LDSU + 16384 + (hh) * 4096 + t * 8)

    const int cs0 = ((quad) ^ (l15 & 7)) * 8;
    const int cs1 = ((4 + quad) ^ (l15 & 7)) * 8;
    int offA[8], offB[2];
#pragma unroll
    for (int mi = 0; mi < 8; mi++)
        offA[mi] = (wm * 2 + (mi >> 2)) * 4096 + (((mi & 3) * 16 + l15)) * 64;
#pragma unroll
    for (int nj = 0; nj < 2; nj++)
        offB[nj] = 16384 + (wn >> 1) * 4096 + ((wn & 1) * 32 + nj * 16 + l15) * 64;

    float4v acc[8][2];
#pragma unroll
    for (int mi = 0; mi < 8; mi++)
#pragma unroll
        for (int nj = 0; nj < 2; nj++) acc[mi][nj] = (float4v){0.f, 0.f, 0.f, 0.f};

    STA2(0, 0, 0); STA2(0, 2, 0); STB2(0, 0, 0); STB2(0, 1, 0);
    STA2(0, 1, 0); STA2(0, 3, 0);
    STA2(1, 0, 1); STA2(1, 2, 1); STB2(1, 0, 1); STB2(1, 1, 1);
    asm volatile("s_waitcnt vmcnt(6)" ::: "memory");
    __builtin_amdgcn_s_barrier();

    FragU fA[4][2], fB[2][2];

    for (int g = 0; g < 32; ++g) {
        const int c = g & 1, db = c ^ 1;
        const u16* sb = lds + c * G2_LDSU;

        // ---- ph1 (mh0): reads A0-3 (8) + B (4); stage A13(g+1) -> db ----
#pragma unroll
        for (int i = 0; i < 4; i++) {
            fA[i][0].u = *(const uint4*)(sb + offA[i] + cs0);
            fA[i][1].u = *(const uint4*)(sb + offA[i] + cs1);
        }
#pragma unroll
        for (int j = 0; j < 2; j++) {
            fB[j][0].u = *(const uint4*)(sb + offB[j] + cs0);
            fB[j][1].u = *(const uint4*)(sb + offB[j] + cs1);
        }
        if (g < 31) { STA2(db, 1, g + 1); STA2(db, 3, g + 1); }
        asm volatile("s_waitcnt lgkmcnt(8)" ::: "memory");
        __builtin_amdgcn_s_barrier();
        __builtin_amdgcn_s_setprio(1);
#pragma unroll
        for (int i = 0; i < 4; i++)
#pragma unroll
            for (int j = 0; j < 2; j++) {
                acc[i][j] = __builtin_amdgcn_mfma_f32_16x16x32_bf16(
                    fA[i][0].v, fB[j][0].v, acc[i][j], 0, 0, 0);
                acc[i][j] = __builtin_amdgcn_mfma_f32_16x16x32_bf16(
                    fA[i][1].v, fB[j][1].v, acc[i][j], 0, 0, 0);
            }
        __builtin_amdgcn_s_setprio(0);

        // ---- ph2 (mh1): W2 wait; reads A4-7; stage A02+B(g+2) -> cur ----
        if (g < 31) { asm volatile("s_waitcnt vmcnt(6)" ::: "memory"); }
        else        { asm volatile("s_waitcnt vmcnt(0)" ::: "memory"); }
        __builtin_amdgcn_s_barrier();
        if (g < 30) { STA2(c, 0, g + 2); STA2(c, 2, g + 2);
                      STB2(c, 0, g + 2); STB2(c, 1, g + 2); }
#pragma unroll
        for (int i = 0; i < 4; i++) {
            fA[i][0].u = *(const uint4*)(sb + offA[4 + i] + cs0);
            fA[i][1].u = *(const uint4*)(sb + offA[4 + i] + cs1);
        }
        __builtin_amdgcn_s_setprio(1);
#pragma unroll
        for (int i = 0; i < 4; i++)
#pragma unroll
            for (int j = 0; j < 2; j++) {
                acc[4 + i][j] = __builtin_amdgcn_mfma_f32_16x16x32_bf16(
                    fA[i][0].v, fB[j][0].v, acc[4 + i][j], 0, 0, 0);
                acc[4 + i][j] = __builtin_amdgcn_mfma_f32_16x16x32_bf16(
                    fA[i][1].v, fB[j][1].v, acc[4 + i][j], 0, 0, 0);
            }
        __builtin_amdgcn_s_setprio(0);

        if (g < 30)       { asm volatile("s_waitcnt vmcnt(6)" ::: "memory"); }
        else if (g == 30) { asm volatile("s_waitcnt vmcnt(2)" ::: "memory"); }
        if (g < 31) __builtin_amdgcn_s_barrier();
    }

#pragma unroll
    for (int mi = 0; mi < 8; mi++) {
        long row0 = blockM + wm * 128 + mi * 16 + quad * 4;
#pragma unroll
        for (int nj = 0; nj < 2; nj++) {
            long col = blockN + wn * 32 + nj * 16 + l15;
#pragma unroll
            for (int r = 0; r < 4; r++)
                C[(row0 + r) * N + col] = acc[mi][nj][r];
        }
    }
#undef STA2
#undef STB2
}

// ---------------- ba as MFMA GEMM, 128 blocks, wave-split staging ------------
// M=32/block, N=32, K=2048. Waves 0-1 stage A (1 gload/wave), waves 2-3 stage
// B (1 gload/wave) -> per-wave vmcnt exact. 2-slot ring, vmcnt(1), raw
// barriers. Each wave computes one 16x16 output tile.
__global__ __launch_bounds__(256) void ba_gemm(
    const u16* __restrict__ hsb, const u16* __restrict__ WbaTb,
    const float* __restrict__ A_log, const float* __restrict__ dtb,
    float* __restrict__ gout, float* __restrict__ bout) {
    __shared__ u16 As[2][32 * 32];
    __shared__ u16 Bs[2][32 * 32];
    int t = threadIdx.x;
    int lane = t & 63, w = t >> 6, l15 = lane & 15, quad = lane >> 4;
    long blockM = (long)blockIdx.x * 32;

    float4v acc = (float4v){0.f, 0.f, 0.f, 0.f};

    // staging sources: t<128 -> A (row t>>2, col (t&3)*8); t>=128 -> B.
    int sidx = t & 127;
    const u16* Sg = (t < 128)
        ? hsb + (blockM + (sidx >> 2)) * (long)HID + (sidx & 3) * 8
        : WbaTb + (long)(sidx >> 2) * HID + (sidx & 3) * 8;
    u16* Sl0 = (t < 128) ? As[0] + sidx * 8 : Bs[0] + sidx * 8;
    u16* Sl1 = (t < 128) ? As[1] + sidx * 8 : Bs[1] + sidx * 8;

    GLOAD_LDS16(Sg + 0, Sl0);
    GLOAD_LDS16(Sg + 32, Sl1);

    const int wr = (w >> 1) * 16, wc = (w & 1) * 16;

    for (int k0 = 0; k0 < HID; k0 += 32) {
        int buf = (k0 >> 5) & 1;
        if (k0 < HID - 64) { asm volatile("s_waitcnt vmcnt(1)" ::: "memory"); }
        else               { asm volatile("s_waitcnt vmcnt(0)" ::: "memory"); }
        __builtin_amdgcn_s_barrier();
        FragU fa, fb;
        fa.u = *(const uint4*)(As[buf] + (wr + l15) * 32 + quad * 8);
        fb.u = *(const uint4*)(Bs[buf] + (wc + l15) * 32 + quad * 8);
        asm volatile("s_waitcnt lgkmcnt(0)" ::: "memory");
        __builtin_amdgcn_sched_barrier(0);
        __builtin_amdgcn_s_barrier();     // all reads done before overwrite
        if (k0 + 64 < HID) GLOAD_LDS16(Sg + k0 + 64, buf ? Sl1 : Sl0);
        acc = __builtin_amdgcn_mfma_f32_16x16x32_bf16(fa.v, fb.v, acc, 0, 0, 0);
    }

    {
        int n = wc + l15;
#pragma unroll
        for (int r = 0; r < 4; r++) {
            long m = blockM + wr + quad * 4 + r;
            int b = (int)(m >> 10), l = (int)(m & 1023);
            float v = acc[r];
            if (n < 16) {
                bout[((long)(b * NH + n)) * L_SEQ + l] = 1.f / (1.f + expf(-v));
            } else {
                int h = n - 16;
                float x = v + dtb[h];
                float sp = (x > 20.f) ? x : log1pf(expf(x));
                gout[((long)(b * NH + h)) * L_SEQ + l] = -expf(A_log[h]) * sp;
            }
        }
    }
}

// ---------------- conv(KS=4) + l2norm(q,k) + split v -> bf16 -----------------
// Vectorized: each thread owns 8 consecutive channels; uint4 qkvz loads,
// float4 weight loads, uint4 packed stores. Pass 0/1/2 == q/k/v exactly.
__global__ __launch_bounds__(256) void conv_qkv(
    const u16* __restrict__ qkvz, const float* __restrict__ conv_w,
    const float* __restrict__ conv_b,
    u16* __restrict__ qs, u16* __restrict__ ks, u16* __restrict__ vs) {
    // XCD swizzle: consecutive bl (which share 3 of 4 qkvz rows) on same XCD.
    int orig = blockIdx.x;
    int bl = ((orig & 7) << 9) + (orig >> 3);   // 4096 = 8 x 512, bijective
    int b = bl >> 10, l = bl & 1023;
    int t = threadIdx.x;
    __shared__ float xb[CONV_DIM];
    __shared__ float red[32][9];
    __shared__ float rbuf[32];

    const int ok3 = (l >= 3), ok2 = (l >= 2), ok1 = (l >= 1);
#pragma unroll
    for (int pass = 0; pass < 3; pass++) {
        int c = pass * 2048 + t * 8;
        long rowbase = (long)(b * L_SEQ + l) * NQKVZ + c;
        uint4 x3 = ok3 ? *(const uint4*)(qkvz + rowbase - 3L * NQKVZ) : (uint4){0,0,0,0};
        uint4 x2 = ok2 ? *(const uint4*)(qkvz + rowbase - 2L * NQKVZ) : (uint4){0,0,0,0};
        uint4 x1 = ok1 ? *(const uint4*)(qkvz + rowbase - 1L * NQKVZ) : (uint4){0,0,0,0};
        uint4 x0 = *(const uint4*)(qkvz + rowbase);
        const u16* p3 = (const u16*)&x3;
        const u16* p2 = (const u16*)&x2;
        const u16* p1 = (const u16*)&x1;
        const u16* p0 = (const u16*)&x0;
        float4 cb0 = *(const float4*)(conv_b + c);
        float4 cb1 = *(const float4*)(conv_b + c + 4);
        const float* cbp = &cb0.x;
#pragma unroll
        for (int j = 0; j < 8; j++) {
            float4 wv = *(const float4*)(conv_w + (c + j) * 4);
            float accv = ((j < 4) ? (&cb0.x)[j] : (&cb1.x)[j - 4]);
            if (ok3) accv += bf2f(p3[j]) * wv.x;
            if (ok2) accv += bf2f(p2[j]) * wv.y;
            if (ok1) accv += bf2f(p1[j]) * wv.z;
            accv += bf2f(p0[j]) * wv.w;
            xb[c + j] = accv;
        }
        (void)cbp;
    }
    __syncthreads();
    {
        int grp = t >> 3;
        int j8 = t & 7;
        float s = 0.f;
#pragma unroll
        for (int i = 0; i < 16; i++) {
            float xv = xb[grp * 128 + j8 * 16 + i];
            s += xv * xv;
        }
        red[grp][j8] = s;
    }
    __syncthreads();
    if (t < 32) {
        float s = 0.f;
#pragma unroll
        for (int i = 0; i < 8; i++) s += red[t][i];
        rbuf[t] = rsqrtf(s + 1e-6f);
    }
    __syncthreads();
    {
        // pass 0: q (scaled), pass 1: k (scaled), pass 2: v (raw)
        int c0 = t * 8;
        int h = c0 >> 7, d = c0 & 127;
        u16 outv[8];
        float sq = rbuf[h];
#pragma unroll
        for (int j = 0; j < 8; j++) outv[j] = f2bf(xb[c0 + j] * sq);
        *(uint4*)&qs[(((long)(b * NH + h)) * L_SEQ + l) * DK + d] = *(const uint4*)outv;

        int c1 = 2048 + t * 8;
        int h1 = (c1 - 2048) >> 7, d1 = (c1 - 2048) & 127;
        float sk = rbuf[16 + h1];
#pragma unroll
        for (int j = 0; j < 8; j++) outv[j] = f2bf(xb[c1 + j] * sk);
        *(uint4*)&ks[(((long)(b * NH + h1)) * L_SEQ + l) * DK + d1] = *(const uint4*)outv;

        int c2 = 4096 + t * 8;
        int h2 = (c2 - 4096) >> 7, d2 = (c2 - 4096) & 127;
#pragma unroll
        for (int j = 0; j < 8; j++) outv[j] = f2bf(xb[c2 + j]);
        *(uint4*)&vs[(((long)(b * NH + h2)) * L_SEQ + l) * DV + d2] = *(const uint4*)outv;
    }
}

// ---------------- gdn_prep v2: per-chunk T, P, wb, ql, kd, gam ---------------
__global__ __launch_bounds__(256) void gdn_prep(
    const u16* __restrict__ ks_g, const u16* __restrict__ qs_g,
    const float* __restrict__ g_g, const float* __restrict__ b_g,
    u16* __restrict__ Tbuf, u16* __restrict__ Pbuf,
    u16* __restrict__ wbq, u16* __restrict__ qlq, u16* __restrict__ kdq,
    float* __restrict__ gam_g) {
    int cid = blockIdx.x;
    int bh = cid >> 4;
    int ch = cid & 15;
    long rowbase = (long)bh * L_SEQ + ch * 64;
    int t = threadIdx.x;
    int lane = t & 63, w = t >> 6, l15 = lane & 15, quad = lane >> 4;

    __shared__ u16 Kl[64 * 136];
    __shared__ u16 Ql[64 * 136];
    __shared__ float Am[64 * 66];
    __shared__ float Tm[64 * 66];
    __shared__ float Tt[32 * 33];
    __shared__ float Gs[64], lamL[64], betaL[64], dlL[64];

    {   // stage K,Q rows bf16 -> padded LDS; stage g, beta
        int row = t >> 2, seg = (t & 3) * 32;
        const u16* ksrc = ks_g + (rowbase + row) * DK + seg;
        const u16* qsrc = qs_g + (rowbase + row) * DK + seg;
        *(uint4*)&Kl[row * 136 + seg]      = *(const uint4*)ksrc;
        *(uint4*)&Kl[row * 136 + seg + 8]  = *(const uint4*)(ksrc + 8);
        *(uint4*)&Kl[row * 136 + seg + 16] = *(const uint4*)(ksrc + 16);
        *(uint4*)&Kl[row * 136 + seg + 24] = *(const uint4*)(ksrc + 24);
        *(uint4*)&Ql[row * 136 + seg]      = *(const uint4*)qsrc;
        *(uint4*)&Ql[row * 136 + seg + 8]  = *(const uint4*)(qsrc + 8);
        *(uint4*)&Ql[row * 136 + seg + 16] = *(const uint4*)(qsrc + 16);
        *(uint4*)&Ql[row * 136 + seg + 24] = *(const uint4*)(qsrc + 24);
        if (t < 64) Gs[t] = g_g[rowbase + t];
        else if (t < 128) betaL[t - 64] = b_g[rowbase + t - 64];
    }
    __syncthreads();
    if (t < 64) {   // inclusive prefix scan (Kogge-Stone, wave 0)
        float gv = Gs[t];
#pragma unroll
        for (int off = 1; off < 64; off <<= 1) {
            float n = __shfl_up(gv, off);
            if (lane >= off) gv += n;
        }
        Gs[t] = gv;
    }
    __syncthreads();
    if (t < 64) {
        float G63 = Gs[63];
        float lm = expf(Gs[t]);
        lamL[t] = lm;
        dlL[t] = expf(G63 - Gs[t]);
        if (t == 0) gam_g[cid] = expf(G63);
    }
    // MFMA: KK^T and QK^T (wave w = row-stripe w*16)
    float4v accKK[4], accQK[4];
#pragma unroll
    for (int tj = 0; tj < 4; tj++) {
        accKK[tj] = (float4v){0.f, 0.f, 0.f, 0.f};
        accQK[tj] = (float4v){0.f, 0.f, 0.f, 0.f};
    }
#pragma unroll
    for (int k0 = 0; k0 < 128; k0 += 32) {
        FragU ka, qa;
        ka.u = *(const uint4*)&Kl[(w * 16 + l15) * 136 + k0 + quad * 8];
        qa.u = *(const uint4*)&Ql[(w * 16 + l15) * 136 + k0 + quad * 8];
#pragma unroll
        for (int tj = 0; tj < 4; tj++) {
            FragU kb;
            kb.u = *(const uint4*)&Kl[(tj * 16 + l15) * 136 + k0 + quad * 8];
            accKK[tj] = __builtin_amdgcn_mfma_f32_16x16x32_bf16(ka.v, kb.v, accKK[tj], 0, 0, 0);
            accQK[tj] = __builtin_amdgcn_mfma_f32_16x16x32_bf16(qa.v, kb.v, accQK[tj], 0, 0, 0);
        }
    }
    __syncthreads();   // lamL/betaL/dlL visible
    // mask + scale; Am -> LDS fp32, P -> global bf16
#pragma unroll
    for (int tj = 0; tj < 4; tj++) {
#pragma unroll
        for (int r = 0; r < 4; r++) {
            int ti_ = w * 16 + quad * 4 + r;
            int j = tj * 16 + l15;
            float e = (j <= ti_) ? expf(Gs[ti_] - Gs[j]) : 0.f;
            Am[ti_ * 66 + j] = (j < ti_) ? betaL[ti_] * e * accKK[tj][r] : 0.f;
            Pbuf[(long)cid * 4096 + ti_ * 64 + j] =
                (j <= ti_) ? f2bf(GDN_SCALE * e * accQK[tj][r]) : (u16)0;
        }
    }
    // wbq, qlq (row-major [64][128])
    {
        int row = t >> 2, seg = (t & 3) * 32;
        float sw = -betaL[row] * lamL[row];
        float sq = GDN_SCALE * lamL[row];
#pragma unroll
        for (int c0 = 0; c0 < 32; c0 += 8) {
            u16 wt[8], qt2[8];
#pragma unroll
            for (int j2 = 0; j2 < 8; j2++) {
                wt[j2]  = f2bf(sw * bf2f(Kl[row * 136 + seg + c0 + j2]));
                qt2[j2] = f2bf(sq * bf2f(Ql[row * 136 + seg + c0 + j2]));
            }
            *(uint4*)&wbq[(long)cid * 8192 + row * 128 + seg + c0] = *(uint4*)wt;
            *(uint4*)&qlq[(long)cid * 8192 + row * 128 + seg + c0] = *(uint4*)qt2;
        }
    }
    // kdq (transposed [128 k][64 t]) — all 256 threads
    {
        int k = t & 127, t0b = (t >> 7) * 32;
#pragma unroll
        for (int t0 = 0; t0 < 32; t0 += 8) {
            u16 tmp[8];
#pragma unroll
            for (int j2 = 0; j2 < 8; j2++)
                tmp[j2] = f2bf(dlL[t0b + t0 + j2] * bf2f(Kl[(t0b + t0 + j2) * 136 + k]));
            *(uint4*)&kdq[(long)cid * 8192 + k * 64 + t0b + t0] = *(uint4*)tmp;
        }
    }
    __syncthreads();
    // fwd-subst: T11 (lanes 0-31 of wave 0), T22 (lanes 0-31 of wave 1), zero T12
    if (t < 32) {
        int c = t;
        for (int i = 0; i < 32; i++) {
            float s = (i == c) ? 1.f : 0.f;
            for (int j = 0; j < i; j++) s -= Am[i * 66 + j] * Tm[j * 66 + c];
            Tm[i * 66 + c] = s;
        }
    } else if (t >= 64 && t < 96) {
        int c = 32 + (t - 64);
        for (int i = 32; i < 64; i++) {
            float s = (i == c) ? 1.f : 0.f;
            for (int j = 32; j < i; j++) s -= Am[i * 66 + j] * Tm[j * 66 + c];
            Tm[i * 66 + c] = s;
        }
    } else if (t >= 128 && t < 192) {
        int idx = t - 128;
        for (int kk = 0; kk < 16; kk++) {
            int e = idx * 16 + kk;
            Tm[(e >> 5) * 66 + 32 + (e & 31)] = 0.f;
        }
    }
    __syncthreads();
    {   // Tt = A21 * T11  (32x32, 4 elems/thread)
        int e0 = t * 4;
#pragma unroll
        for (int kk = 0; kk < 4; kk++) {
            int e = e0 + kk; int i = e >> 5, c = e & 31;
            float s = 0.f;
            for (int j = 0; j < 32; j++) s += Am[(32 + i) * 66 + j] * Tm[j * 66 + c];
            Tt[i * 33 + c] = s;
        }
    }
    __syncthreads();
    {   // T21 = -T22 * Tt
        int e0 = t * 4;
#pragma unroll
        for (int kk = 0; kk < 4; kk++) {
            int e = e0 + kk; int i = e >> 5, c = e & 31;
            float s = 0.f;
            for (int j = 0; j < 32; j++) s -= Tm[(32 + i) * 66 + 32 + j] * Tt[j * 33 + c];
            Tm[(32 + i) * 66 + c] = s;
        }
    }
    __syncthreads();
    {   // T -> global bf16
        int row = t >> 2, c0 = (t & 3) * 16;
        u16 tmp[16];
#pragma unroll
        for (int i = 0; i < 16; i++) tmp[i] = f2bf(Tm[row * 66 + c0 + i]);
        *(uint4*)&Tbuf[(long)cid * 4096 + row * 64 + c0]     = *(uint4*)tmp;
        *(uint4*)&Tbuf[(long)cid * 4096 + row * 64 + c0 + 8] = *(uint4*)(tmp + 8);
    }
}

// ---------------- gdn_chunk v3: direct-global fragments, 512 blocks ----------
__global__ __launch_bounds__(256) void gdn_chunk(
    const u16* __restrict__ vs_g, const float* __restrict__ b_g,
    const u16* __restrict__ Tq, const u16* __restrict__ Pq,
    const u16* __restrict__ wbq, const u16* __restrict__ qlq,
    const u16* __restrict__ kdq, const float* __restrict__ gam_g,
    float* __restrict__ o_g) {
    int orig = blockIdx.x;
    int bid = ((orig & 7) << 6) + (orig >> 3);   // 512 = 8 x 64, bijective
    int dc = bid & 7;
    int bh = bid >> 3;
    int b = bh >> 4, h = bh & 15;
    int t = threadIdx.x;
    int lane = t & 63, w = t >> 6, l15 = lane & 15, quad = lane >> 4;

    __shared__ u16 s0h[16 * 136], s0l[16 * 136];   // S0^T [v][k] hi/lo
    __shared__ float vO[64 * 20];                  // vb / O, [t][v]
    __shared__ u16 rhsT[16 * 72], DT[16 * 72];     // [v][t]

    float4v S0r[2];
    S0r[0] = (float4v){0.f, 0.f, 0.f, 0.f};
    S0r[1] = (float4v){0.f, 0.f, 0.f, 0.f};

    const int orow = t >> 2, oseg = (t & 3) * 4;   // 64 rows x 16 cols

    for (int ch = 0; ch < 16; ch++) {
        int cid = bh * 16 + ch;
        long rowbase = (long)bh * L_SEQ + ch * 64;
        float gam = gam_g[cid];

        const u16* wbp = wbq + (long)cid * 8192 + (w * 16 + l15) * 128 + quad * 8;
        uint4 wbf0 = *(const uint4*)(wbp);
        uint4 wbf1 = *(const uint4*)(wbp + 32);
        uint4 wbf2 = *(const uint4*)(wbp + 64);
        uint4 wbf3 = *(const uint4*)(wbp + 96);

        // ---- phase a: store prev O, load vb, split S0 ----
        if (ch > 0) {
            float4 a = *(const float4*)&vO[orow * 20 + oseg];
            float* d2 = o_g + (((long)b * L_SEQ + (ch - 1) * 64 + orow) * 16 + h) * 128L
                        + dc * 16 + oseg;
            *(float4*)d2 = a;
        }
        {
            float beta = b_g[rowbase + orow];
            uint2 vv = *(const uint2*)(vs_g + (rowbase + orow) * DV + dc * 16 + oseg);
            const u16* vp = (const u16*)&vv;
#pragma unroll
            for (int j2 = 0; j2 < 4; j2++)
                vO[orow * 20 + oseg + j2] = beta * bf2f(vp[j2]);
        }
#pragma unroll
        for (int ktl = 0; ktl < 2; ktl++) {
            int kc = (2 * w + ktl) * 16 + l15;
#pragma unroll
            for (int r = 0; r < 4; r++) {
                float x = S0r[ktl][r];
                u16 hi = f2bf(x);
                float lo = x - bf2f(hi);
                s0h[(quad * 4 + r) * 136 + kc] = hi;
                s0l[(quad * 4 + r) * 136 + kc] = f2bf(lo);
            }
        }
        __syncthreads();

        // ---- phase b: RHS[t][v] = vb + wb*(S0h+S0l) -> rhsT ----
        const u16* Tp = Tq + (long)cid * 4096 + (w * 16 + l15) * 64 + quad * 8;
        uint4 Tf0 = *(const uint4*)(Tp);
        uint4 Tf1 = *(const uint4*)(Tp + 32);
        {
            float4v acc;
#pragma unroll
            for (int r = 0; r < 4; r++)
                acc[r] = vO[(w * 16 + quad * 4 + r) * 20 + l15];
            uint4 wbf[4] = {wbf0, wbf1, wbf2, wbf3};
#pragma unroll
            for (int k0 = 0; k0 < 4; k0++) {
                FragU a, bh_, bl_;
                a.u = wbf[k0];
                bh_.u = *(const uint4*)&s0h[l15 * 136 + k0 * 32 + quad * 8];
                acc = __builtin_amdgcn_mfma_f32_16x16x32_bf16(a.v, bh_.v, acc, 0, 0, 0);
                bl_.u = *(const uint4*)&s0l[l15 * 136 + k0 * 32 + quad * 8];
                acc = __builtin_amdgcn_mfma_f32_16x16x32_bf16(a.v, bl_.v, acc, 0, 0, 0);
            }
            u16 tmp[4] = {f2bf(acc[0]), f2bf(acc[1]), f2bf(acc[2]), f2bf(acc[3])};
            *(uint2*)&rhsT[l15 * 72 + w * 16 + quad * 4] = *(uint2*)tmp;
        }
        __syncthreads();

        // ---- phase c: D = T*RHS -> DT ----
        const u16* qlp = qlq + (long)cid * 8192 + (w * 16 + l15) * 128 + quad * 8;
        uint4 qlf0 = *(const uint4*)(qlp);
        uint4 qlf1 = *(const uint4*)(qlp + 32);
        uint4 qlf2 = *(const uint4*)(qlp + 64);
        uint4 qlf3 = *(const uint4*)(qlp + 96);
        const u16* Pp = Pq + (long)cid * 4096 + (w * 16 + l15) * 64 + quad * 8;
        uint4 Pf0 = *(const uint4*)(Pp);
        uint4 Pf1 = *(const uint4*)(Pp + 32);
        {
            float4v acc = (float4v){0.f, 0.f, 0.f, 0.f};
            uint4 Tf[2] = {Tf0, Tf1};
#pragma unroll
            for (int k0 = 0; k0 < 2; k0++) {
                FragU a, b_;
                a.u = Tf[k0];
                b_.u = *(const uint4*)&rhsT[l15 * 72 + k0 * 32 + quad * 8];
                acc = __builtin_amdgcn_mfma_f32_16x16x32_bf16(a.v, b_.v, acc, 0, 0, 0);
            }
            u16 tmp[4] = {f2bf(acc[0]), f2bf(acc[1]), f2bf(acc[2]), f2bf(acc[3])};
            *(uint2*)&DT[l15 * 72 + w * 16 + quad * 4] = *(uint2*)tmp;
        }
        __syncthreads();

        // ---- phase d: O = ql*S0 + P*D ; S0 = gam*S0 + kd^T D ----
        uint4 kdf[2][2];
#pragma unroll
        for (int ktl = 0; ktl < 2; ktl++) {
            const u16* kdp = kdq + (long)cid * 8192 + ((2 * w + ktl) * 16 + l15) * 64 + quad * 8;
            kdf[ktl][0] = *(const uint4*)(kdp);
            kdf[ktl][1] = *(const uint4*)(kdp + 32);
        }
        {
            float4v acc = (float4v){0.f, 0.f, 0.f, 0.f};
            uint4 qlf[4] = {qlf0, qlf1, qlf2, qlf3};
#pragma unroll
            for (int k0 = 0; k0 < 4; k0++) {
                FragU a, bh_, bl_;
                a.u = qlf[k0];
                bh_.u = *(const uint4*)&s0h[l15 * 136 + k0 * 32 + quad * 8];
                acc = __builtin_amdgcn_mfma_f32_16x16x32_bf16(a.v, bh_.v, acc, 0, 0, 0);
                bl_.u = *(const uint4*)&s0l[l15 * 136 + k0 * 32 + quad * 8];
                acc = __builtin_amdgcn_mfma_f32_16x16x32_bf16(a.v, bl_.v, acc, 0, 0, 0);
            }
            uint4 Pf[2] = {Pf0, Pf1};
#pragma unroll
            for (int k0 = 0; k0 < 2; k0++) {
                FragU a, b_;
                a.u = Pf[k0];
                b_.u = *(const uint4*)&DT[l15 * 72 + k0 * 32 + quad * 8];
                acc = __builtin_amdgcn_mfma_f32_16x16x32_bf16(a.v, b_.v, acc, 0, 0, 0);
            }
#pragma unroll
            for (int r = 0; r < 4; r++)
                vO[(w * 16 + quad * 4 + r) * 20 + l15] = acc[r];
        }
#pragma unroll
        for (int ktl = 0; ktl < 2; ktl++) {
            float4v acc = S0r[ktl];
#pragma unroll
            for (int r = 0; r < 4; r++) acc[r] *= gam;
#pragma unroll
            for (int t0 = 0; t0 < 2; t0++) {
                FragU a, b_;
                a.u = *(const uint4*)&DT[l15 * 72 + t0 * 32 + quad * 8];
                b_.u = kdf[ktl][t0];
                acc = __builtin_amdgcn_mfma_f32_16x16x32_bf16(a.v, b_.v, acc, 0, 0, 0);
            }
            S0r[ktl] = acc;
        }
        __syncthreads();
    }
    {
        float4 a = *(const float4*)&vO[orow * 20 + oseg];
        float* d2 = o_g + (((long)b * L_SEQ + 15 * 64 + orow) * 16 + h) * 128L
                    + dc * 16 + oseg;
        *(float4*)d2 = a;
    }
}

// ---------------- gated RMS norm -> bf16 A2 ----------------------------------
__global__ __launch_bounds__(128) void gated_norm(
    const float* __restrict__ o, const u16* __restrict__ qkvz,
    const float* __restrict__ norm_w, u16* __restrict__ A2) {
    int bid = blockIdx.x;  // (b*L+l)*16 + h
    int t = threadIdx.x;   // 0..127
    float ov = o[(long)bid * 128 + t];
    float s = ov * ov;
#pragma unroll
    for (int off = 32; off > 0; off >>= 1) s += __shfl_down(s, off);
    __shared__ float ws2[2];
    if ((t & 63) == 0) ws2[t >> 6] = s;
    __syncthreads();
    float tot = ws2[0] + ws2[1];
    float rinv = rsqrtf(tot * (1.f / 128.f) + 1e-6f);
    int bl = bid >> 4, h = bid & 15;
    float z = bf2f(qkvz[(long)bl * NQKVZ + CONV_DIM + h * 128 + t]);
    float sig = 1.f / (1.f + expf(-z));
    float val = ov * rinv * norm_w[t] * sig;
    A2[(long)bl * 2048 + h * 128 + t] = f2bf(val);
}

// ---------------- host-side launcher -----------------------------------------
extern "C" void kernel_launch(void* const* d_in, const int* in_sizes, int n_in,
                              void* d_out, int out_size, void* d_ws, size_t ws_size,
                              hipStream_t stream) {
    const float* hs    = (const float*)d_in[0];
    const float* Wqkvz = (const float*)d_in[1];
    const float* Wba   = (const float*)d_in[2];
    const float* convw = (const float*)d_in[3];
    const float* convb = (const float*)d_in[4];
    const float* A_log = (const float*)d_in[5];
    const float* dtb   = (const float*)d_in[6];
    const float* normw = (const float*)d_in[7];
    const float* Wout  = (const float*)d_in[8];

    char* ws = (char*)d_ws;
    size_t off = 0;
    auto alloc = [&](size_t bytes) {
        size_t o = off;
        off = (off + bytes + 255) & ~(size_t)255;
        return o;
    };
    // region0: WqkvzT (bf16) — dead after GEMM1, reused for os (fp32)
    size_t r0 = alloc((size_t)NQKVZ * HID * 2);
    // region1: hs_bf16 — kept through ba_gemm; A2 aliases after
    size_t r1 = alloc((size_t)4096 * HID * 2);
    u16*   WqkvzT = (u16*)(ws + r0);
    float* os     = (float*)(ws + r0);
    u16*   hsb    = (u16*)(ws + r1);
    u16*   A2     = (u16*)(ws + r1);   // written by gated_norm after ba_gemm done
    u16*   qkvz   = (u16*)(ws + alloc((size_t)4096 * NQKVZ * 2));
    u16*   qs     = (u16*)(ws + alloc((size_t)64 * L_SEQ * DK * 2));
    u16*   ks     = (u16*)(ws + alloc((size_t)64 * L_SEQ * DK * 2));
    u16*   vs     = (u16*)(ws + alloc((size_t)64 * L_SEQ * DV * 2));
    float* gs     = (float*)(ws + alloc((size_t)64 * L_SEQ * 4));
    float* bs     = (float*)(ws + alloc((size_t)64 * L_SEQ * 4));
    u16*   WoutT  = (u16*)(ws + alloc((size_t)HID * 2048 * 2));
    u16*   WbaTb  = (u16*)(ws + alloc((size_t)32 * HID * 2));
    u16*   Tbuf   = (u16*)(ws + alloc((size_t)1024 * 4096 * 2));
    u16*   Pbuf   = (u16*)(ws + alloc((size_t)1024 * 4096 * 2));
    u16*   wbq    = (u16*)(ws + alloc((size_t)1024 * 8192 * 2));
    u16*   qlq    = (u16*)(ws + alloc((size_t)1024 * 8192 * 2));
    u16*   kdq    = (u16*)(ws + alloc((size_t)1024 * 8192 * 2));
    float* gamb   = (float*)(ws + alloc((size_t)1024 * 4));

    // 1. convert + transposes
    hipLaunchKernelGGL(f32_to_bf16, dim3(4096), dim3(256), 0, stream, hs, hsb);
    hipLaunchKernelGGL(transpose_f32_bf16, dim3(NQKVZ / 32, HID / 32), dim3(256), 0, stream,
                       Wqkvz, WqkvzT, HID, NQKVZ);
    hipLaunchKernelGGL(transpose_f32_bf16, dim3(2048 / 32, 2048 / 32), dim3(256), 0, stream,
                       Wout, WoutT, 2048, 2048);
    hipLaunchKernelGGL(transpose_f32_bf16, dim3(1, HID / 32), dim3(256), 0, stream,
                       Wba, WbaTb, HID, 32);

    // 2. GEMM1: qkvz = hs @ W_qkvz (r2 schedule, frozen)
    hipLaunchKernelGGL(gemm1_8ph, dim3(512), dim3(512), 0, stream,
                       hsb, WqkvzT, qkvz);

    // 3. ba (MFMA, 128 blocks, wave-split ring) -> g, beta
    hipLaunchKernelGGL(ba_gemm, dim3(128), dim3(256), 0, stream,
                       hsb, WbaTb, A_log, dtb, gs, bs);

    // 4. conv + l2norm -> q,k,v (bf16), vectorized + XCD-swizzled
    hipLaunchKernelGGL(conv_qkv, dim3(4096), dim3(256), 0, stream,
                       qkvz, convw, convb, qs, ks, vs);

    // 5a. chunk prep (parallel): T, P, wb, ql, kd, gam
    hipLaunchKernelGGL(gdn_prep, dim3(1024), dim3(256), 0, stream,
                       ks, qs, gs, bs, Tbuf, Pbuf, wbq, qlq, kdq, gamb);

    // 5b. chunk recurrence (MFMA, direct-global fragments, XCD-swizzled)
    hipLaunchKernelGGL(gdn_chunk, dim3(512), dim3(256), 0, stream,
                       vs, bs, Tbuf, Pbuf, wbq, qlq, kdq, gamb, os);

    // 6. gated RMS norm -> bf16 A2
    hipLaunchKernelGGL(gated_norm, dim3(4096 * NH), dim3(128), 0, stream,
                       os, qkvz, normw, A2);

    // 7. GEMM2: out = A2 @ W_out (256x128 2-phase counted-vmcnt)
    hipLaunchKernelGGL(gemm2_2ph, dim3(256), dim3(512), 0, stream,
                       A2, WoutT, (float*)d_out);
}

// Round 6
// 504.961 us; speedup vs baseline: 1.1870x; 1.1870x over previous
//
#include <hip/hip_runtime.h>

typedef unsigned short u16;
typedef unsigned int u32;
typedef short short8 __attribute__((ext_vector_type(8)));
typedef float float4v __attribute__((ext_vector_type(4)));

#define L_SEQ 1024
#define NB 4
#define NH 16
#define DK 128
#define DV 128
#define HID 2048
#define NQKVZ 8192
#define CONV_DIM 6144
#define GDN_SCALE 0.08838834764831845f  // 128^-0.5

static __device__ __forceinline__ float bf2f(u16 u) {
    union { u32 i; float f; } x; x.i = ((u32)u) << 16; return x.f;
}
static __device__ __forceinline__ u16 f2bf(float f) {
    union { float f; u32 u; } x; x.f = f;
    u32 r = x.u + 0x7FFF + ((x.u >> 16) & 1);
    return (u16)(r >> 16);
}

union FragU { short8 v; uint4 u; };

// async global->LDS, 16B per lane (lane-contiguous LDS dest required).
#define GLOAD_LDS16(g, l)                                        \
    __builtin_amdgcn_global_load_lds(                            \
        (const __attribute__((address_space(1))) void*)(g),      \
        (__attribute__((address_space(3))) void*)(l), 16, 0, 0)

// ---------------- fp32 -> bf16 elementwise convert ---------------------------
__global__ __launch_bounds__(256) void f32_to_bf16(
    const float* __restrict__ in, u16* __restrict__ out) {
    long i = ((long)blockIdx.x * 256 + threadIdx.x) * 8;
    float4 a = *(const float4*)(in + i);
    float4 b = *(const float4*)(in + i + 4);
    u16 tmp[8];
    tmp[0] = f2bf(a.x); tmp[1] = f2bf(a.y); tmp[2] = f2bf(a.z); tmp[3] = f2bf(a.w);
    tmp[4] = f2bf(b.x); tmp[5] = f2bf(b.y); tmp[6] = f2bf(b.z); tmp[7] = f2bf(b.w);
    *(uint4*)(out + i) = *(const uint4*)tmp;
}

// ---------------- transpose fp32 (RxC) -> bf16 (CxR) -------------------------
__global__ __launch_bounds__(256) void transpose_f32_bf16(
    const float* __restrict__ in, u16* __restrict__ out, int R, int C) {
    __shared__ float tile[32][33];
    int bx = blockIdx.x, by = blockIdx.y;
    int c = threadIdx.x & 31;
    int r0 = threadIdx.x >> 5;
#pragma unroll
    for (int i = 0; i < 4; i++) {
        int r = r0 + i * 8;
        tile[r][c] = in[(long)(by * 32 + r) * C + bx * 32 + c];
    }
    __syncthreads();
#pragma unroll
    for (int i = 0; i < 4; i++) {
        int r = r0 + i * 8;
        out[(long)(bx * 32 + r) * R + by * 32 + c] = f2bf(tile[c][r]);
    }
}

// ---------------- conv_w [6144][4] -> convwT [4][6144] (fp32) ----------------
__global__ __launch_bounds__(256) void convw_transpose(
    const float* __restrict__ w, float* __restrict__ wT) {
    int c = blockIdx.x * 256 + threadIdx.x;
    float4 v = *(const float4*)(w + c * 4);
    wT[0 * CONV_DIM + c] = v.x;
    wT[1 * CONV_DIM + c] = v.y;
    wT[2 * CONV_DIM + c] = v.z;
    wT[3 * CONV_DIM + c] = v.w;
}

// ---------------- GEMM (m97 structure): C = A * BT^T, bf16 in, OutT out ------
#define BM 128
#define BN 128
#define BKK 32

static __device__ __forceinline__ void store_out(u16* p, float v)  { *p = f2bf(v); }
static __device__ __forceinline__ void store_out(float* p, float v){ *p = v; }

template <typename OutT>
__global__ __launch_bounds__(256) void gemm_abT(
    const u16* __restrict__ A, const u16* __restrict__ BT,
    OutT* __restrict__ C, int M, int N, int K) {
    __shared__ u16 As[BM * BKK];
    __shared__ u16 Bs[BN * BKK];
    int t = threadIdx.x;
    int lane = t & 63;
    int w = t >> 6;
    int wm = (w & 1) * 64;
    int wn = (w >> 1) * 64;
    int l15 = lane & 15;
    int quad = lane >> 4;
    long blockM = (long)blockIdx.y * BM;
    long blockN = (long)blockIdx.x * BN;

    float4v acc[4][4];
#pragma unroll
    for (int i = 0; i < 4; i++)
#pragma unroll
        for (int j = 0; j < 4; j++) acc[i][j] = (float4v){0.f, 0.f, 0.f, 0.f};

    const u16* Ab = A + blockM * K;
    const u16* Bb = BT + blockN * K;

    const int r0 = t >> 2,         c0 = (t & 3) * 8;
    const int r1 = (t + 256) >> 2, c1 = ((t + 256) & 3) * 8;
    u16* As0 = As + t * 8;         u16* As1 = As + (t + 256) * 8;
    u16* Bs0 = Bs + t * 8;         u16* Bs1 = Bs + (t + 256) * 8;
    const u16* Ag0 = Ab + (long)r0 * K + c0;
    const u16* Ag1 = Ab + (long)r1 * K + c1;
    const u16* Bg0 = Bb + (long)r0 * K + c0;
    const u16* Bg1 = Bb + (long)r1 * K + c1;

    for (int k0 = 0; k0 < K; k0 += BKK) {
        __syncthreads();
        GLOAD_LDS16(Ag0 + k0, As0);
        GLOAD_LDS16(Ag1 + k0, As1);
        GLOAD_LDS16(Bg0 + k0, Bs0);
        GLOAD_LDS16(Bg1 + k0, Bs1);
        __syncthreads();

        FragU fa[4], fb[4];
#pragma unroll
        for (int i = 0; i < 4; i++) {
            fa[i].u = *(const uint4*)(As + (wm + i * 16 + l15) * BKK + quad * 8);
            fb[i].u = *(const uint4*)(Bs + (wn + i * 16 + l15) * BKK + quad * 8);
        }
#pragma unroll
        for (int i = 0; i < 4; i++)
#pragma unroll
            for (int j = 0; j < 4; j++)
                acc[i][j] = __builtin_amdgcn_mfma_f32_16x16x32_bf16(
                    fa[i].v, fb[j].v, acc[i][j], 0, 0, 0);
    }

#pragma unroll
    for (int i = 0; i < 4; i++) {
        long mrow = blockM + wm + i * 16 + quad * 4;
#pragma unroll
        for (int j = 0; j < 4; j++) {
            long col = blockN + wn + j * 16 + l15;
#pragma unroll
            for (int r = 0; r < 4; r++) {
                store_out(&C[(mrow + r) * N + col], acc[i][j][r]);
            }
        }
    }
}

// ---------------- GEMM1: 256x256 tile, BK=64, m201-style 4-phase groups ------
// (r2 schedule, measured 130 us / MfmaUtil 47.6 — FROZEN)
#define G1_LDSU 32768  // u16 per dbuf (64 KB)

__global__ __launch_bounds__(512, 2) void gemm1_8ph(
    const u16* __restrict__ A, const u16* __restrict__ BT,
    u16* __restrict__ C) {
    const int K = HID, N = NQKVZ;
    __shared__ __align__(16) u16 lds[2 * G1_LDSU];  // 128 KB

    int t = threadIdx.x;
    int lane = t & 63, w = t >> 6, l15 = lane & 15, quad = lane >> 4;
    int wm = w & 1, wn = w >> 1;

    int orig = blockIdx.x;
    int wg = (orig & 7) * 64 + (orig >> 3);
    int p = wg >> 6, q = wg & 63;
    long blockM = (long)((p >> 2) * 8 + (q >> 3)) * 256;  // 0..15
    long blockN = (long)((p & 3) * 8 + (q & 7)) * 256;    // 0..31

    int srow = t >> 3;
    int scol = ((t & 7) ^ (srow & 7)) * 8;
    const u16* Ast = A + (blockM + srow) * (long)K + scol;
    const u16* Bst = BT + (blockN + srow) * (long)K + scol;

#define STA(db, qq, T) GLOAD_LDS16(Ast + (long)(qq) * 64 * K + (T) * 64,      \
                                   lds + (db) * G1_LDSU + (qq) * 4096 + t * 8)
#define STB(db, qq, T) GLOAD_LDS16(Bst + (long)(qq) * 64 * K + (T) * 64,      \
                                   lds + (db) * G1_LDSU + 16384 + (qq) * 4096 + t * 8)

    const int rowA0 = (wm * 128 + l15) * 64;
    const int rowB0 = 16384 + (wn * 64 + l15) * 64;
    const int cs0 = ((quad) ^ (l15 & 7)) * 8;        // kk=0 chunk
    const int cs1 = ((4 + quad) ^ (l15 & 7)) * 8;    // kk=1 chunk

    float4v acc[8][4];
#pragma unroll
    for (int mi = 0; mi < 8; mi++)
#pragma unroll
        for (int nj = 0; nj < 4; nj++) acc[mi][nj] = (float4v){0.f, 0.f, 0.f, 0.f};

    STA(0, 0, 0); STA(0, 1, 0); STA(0, 2, 0); STA(0, 3, 0);
    STB(0, 0, 0); STB(0, 1, 0); STB(0, 2, 0); STB(0, 3, 0);
    STA(1, 0, 1); STA(1, 2, 1);
    asm volatile("s_waitcnt vmcnt(2)" ::: "memory");
    __builtin_amdgcn_s_barrier();

    FragU bA[4][2], bB0[2][2], bB1[2][2];

    for (int g = 0; g < 32; ++g) {
        const int c = g & 1, db = c ^ 1;
        const u16* sb = lds + c * G1_LDSU;

        // ---- ph1 (mh0,nh0): 8 A-reads + 4 B-reads; stage T(g+1).Aq1,Aq3 ----
#pragma unroll
        for (int i = 0; i < 4; i++) {
            bA[i][0].u = *(const uint4*)(sb + rowA0 + i * 1024 + cs0);
            bA[i][1].u = *(const uint4*)(sb + rowA0 + i * 1024 + cs1);
        }
#pragma unroll
        for (int j = 0; j < 2; j++) {
            bB0[j][0].u = *(const uint4*)(sb + rowB0 + j * 1024 + cs0);
            bB0[j][1].u = *(const uint4*)(sb + rowB0 + j * 1024 + cs1);
        }
        if (g + 1 < 32) { STA(db, 1, g + 1); STA(db, 3, g + 1); }
        __builtin_amdgcn_s_barrier();
        asm volatile("s_waitcnt lgkmcnt(0)" ::: "memory");
        __builtin_amdgcn_s_setprio(1);
#pragma unroll
        for (int i = 0; i < 4; i++)
#pragma unroll
            for (int j = 0; j < 2; j++) {
                acc[i][j] = __builtin_amdgcn_mfma_f32_16x16x32_bf16(
                    bA[i][0].v, bB0[j][0].v, acc[i][j], 0, 0, 0);
                acc[i][j] = __builtin_amdgcn_mfma_f32_16x16x32_bf16(
                    bA[i][1].v, bB0[j][1].v, acc[i][j], 0, 0, 0);
            }
        __builtin_amdgcn_s_setprio(0);

        // ---- ph2 (mh0,nh1): 4 B-reads; stage T(g+1).Bq0,Bq1 ----
#pragma unroll
        for (int j = 0; j < 2; j++) {
            bB1[j][0].u = *(const uint4*)(sb + rowB0 + (2 + j) * 1024 + cs0);
            bB1[j][1].u = *(const uint4*)(sb + rowB0 + (2 + j) * 1024 + cs1);
        }
        if (g + 1 < 32) { STB(db, 0, g + 1); STB(db, 1, g + 1); }
        __builtin_amdgcn_s_barrier();
        asm volatile("s_waitcnt lgkmcnt(0)" ::: "memory");
        __builtin_amdgcn_s_setprio(1);
#pragma unroll
        for (int i = 0; i < 4; i++)
#pragma unroll
            for (int j = 0; j < 2; j++) {
                acc[i][2 + j] = __builtin_amdgcn_mfma_f32_16x16x32_bf16(
                    bA[i][0].v, bB1[j][0].v, acc[i][2 + j], 0, 0, 0);
                acc[i][2 + j] = __builtin_amdgcn_mfma_f32_16x16x32_bf16(
                    bA[i][1].v, bB1[j][1].v, acc[i][2 + j], 0, 0, 0);
            }
        __builtin_amdgcn_s_setprio(0);

        // ---- ph3 (mh1,nh0): 8 A-reads; stage T(g+1).Bq2,Bq3 ----
#pragma unroll
        for (int i = 0; i < 4; i++) {
            bA[i][0].u = *(const uint4*)(sb + rowA0 + (4 + i) * 1024 + cs0);
            bA[i][1].u = *(const uint4*)(sb + rowA0 + (4 + i) * 1024 + cs1);
        }
        if (g + 1 < 32) { STB(db, 2, g + 1); STB(db, 3, g + 1); }
        __builtin_amdgcn_s_barrier();
        asm volatile("s_waitcnt lgkmcnt(0)" ::: "memory");
        __builtin_amdgcn_s_setprio(1);
#pragma unroll
        for (int i = 0; i < 4; i++)
#pragma unroll
            for (int j = 0; j < 2; j++) {
                acc[4 + i][j] = __builtin_amdgcn_mfma_f32_16x16x32_bf16(
                    bA[i][0].v, bB0[j][0].v, acc[4 + i][j], 0, 0, 0);
                acc[4 + i][j] = __builtin_amdgcn_mfma_f32_16x16x32_bf16(
                    bA[i][1].v, bB0[j][1].v, acc[4 + i][j], 0, 0, 0);
            }
        __builtin_amdgcn_s_setprio(0);

        // ---- ph4 (mh1,nh1): 0 reads; stage T(g+2).Aq0,Aq2 into CURRENT dbuf
        if (g + 2 < 32) { STA(c, 0, g + 2); STA(c, 2, g + 2); }
        __builtin_amdgcn_s_barrier();
        __builtin_amdgcn_s_setprio(1);
#pragma unroll
        for (int i = 0; i < 4; i++)
#pragma unroll
            for (int j = 0; j < 2; j++) {
                acc[4 + i][2 + j] = __builtin_amdgcn_mfma_f32_16x16x32_bf16(
                    bA[i][0].v, bB1[j][0].v, acc[4 + i][2 + j], 0, 0, 0);
                acc[4 + i][2 + j] = __builtin_amdgcn_mfma_f32_16x16x32_bf16(
                    bA[i][1].v, bB1[j][1].v, acc[4 + i][2 + j], 0, 0, 0);
            }
        __builtin_amdgcn_s_setprio(0);

        if (g < 30)       { asm volatile("s_waitcnt vmcnt(2)" ::: "memory"); }
        else if (g == 30) { asm volatile("s_waitcnt vmcnt(0)" ::: "memory"); }
        __builtin_amdgcn_s_barrier();
    }

#pragma unroll
    for (int mi = 0; mi < 8; mi++) {
        long row0 = blockM + wm * 128 + mi * 16 + quad * 4;
#pragma unroll
        for (int nj = 0; nj < 4; nj++) {
            long col = blockN + wn * 64 + nj * 16 + l15;
#pragma unroll
            for (int r = 0; r < 4; r++)
                C[(row0 + r) * N + col] = f2bf(acc[mi][nj][r]);
        }
    }
#undef STA
#undef STB
}

// ---------------- GEMM2: 256x128 tile, BK=64, 2-phase, counted vmcnt ---------
#define G2_LDSU 24576  // u16 per dbuf (48 KB)

__global__ __launch_bounds__(512) void gemm2_2ph(
    const u16* __restrict__ A, const u16* __restrict__ BT,
    float* __restrict__ C) {
    const int K = HID, N = 2048;
    __shared__ __align__(16) u16 lds[2 * G2_LDSU];  // 96 KB

    int t = threadIdx.x;
    int lane = t & 63, w = t >> 6, l15 = lane & 15, quad = lane >> 4;
    int wm = w & 1, wn = w >> 1;

    int orig = blockIdx.x;
    int x = orig & 7, q = orig >> 3;           // q in 0..31
    long blockM = (long)((x >> 2) * 8 + (q >> 2)) * 256;   // 0..15
    long blockN = (long)((x & 3) * 4 + (q & 3)) * 128;     // 0..15

    int srow = t >> 3;
    int scol = ((t & 7) ^ (srow & 7)) * 8;
    const u16* Ast = A + (blockM + srow) * (long)K + scol;
    const u16* Bst = BT + (blockN + srow) * (long)K + scol;

#define STA2(db, qq, T) GLOAD_LDS16(Ast + (long)(qq) * 64 * K + (T) * 64,     \
                                    lds + (db) * G2_LDSU + (qq) * 4096 + t * 8)
#define STB2(db, hh, T) GLOAD_LDS16(Bst + (long)(hh) * 64 * K + (T) * 64,     \
                                    lds + (db) * G2_LDSU + 16384 + (hh) * 4096 + t * 8)

    const int cs0 = ((quad) ^ (l15 & 7)) * 8;
    const int cs1 = ((4 + quad) ^ (l15 & 7)) * 8;
    int offA[8], offB[2];
#pragma unroll
    for (int mi = 0; mi < 8; mi++)
        offA[mi] = (wm * 2 + (mi >> 2)) * 4096 + (((mi & 3) * 16 + l15)) * 64;
#pragma unroll
    for (int nj = 0; nj < 2; nj++)
        offB[nj] = 16384 + (wn >> 1) * 4096 + ((wn & 1) * 32 + nj * 16 + l15) * 64;

    float4v acc[8][2];
#pragma unroll
    for (int mi = 0; mi < 8; mi++)
#pragma unroll
        for (int nj = 0; nj < 2; nj++) acc[mi][nj] = (float4v){0.f, 0.f, 0.f, 0.f};

    STA2(0, 0, 0); STA2(0, 2, 0); STB2(0, 0, 0); STB2(0, 1, 0);
    STA2(0, 1, 0); STA2(0, 3, 0);
    STA2(1, 0, 1); STA2(1, 2, 1); STB2(1, 0, 1); STB2(1, 1, 1);
    asm volatile("s_waitcnt vmcnt(6)" ::: "memory");
    __builtin_amdgcn_s_barrier();

    FragU fA[4][2], fB[2][2];

    for (int g = 0; g < 32; ++g) {
        const int c = g & 1, db = c ^ 1;
        const u16* sb = lds + c * G2_LDSU;

        // ---- ph1 (mh0): reads A0-3 (8) + B (4); stage A13(g+1) -> db ----
#pragma unroll
        for (int i = 0; i < 4; i++) {
            fA[i][0].u = *(const uint4*)(sb + offA[i] + cs0);
            fA[i][1].u = *(const uint4*)(sb + offA[i] + cs1);
        }
#pragma unroll
        for (int j = 0; j < 2; j++) {
            fB[j][0].u = *(const uint4*)(sb + offB[j] + cs0);
            fB[j][1].u = *(const uint4*)(sb + offB[j] + cs1);
        }
        if (g < 31) { STA2(db, 1, g + 1); STA2(db, 3, g + 1); }
        asm volatile("s_waitcnt lgkmcnt(8)" ::: "memory");
        __builtin_amdgcn_s_barrier();
        __builtin_amdgcn_s_setprio(1);
#pragma unroll
        for (int i = 0; i < 4; i++)
#pragma unroll
            for (int j = 0; j < 2; j++) {
                acc[i][j] = __builtin_amdgcn_mfma_f32_16x16x32_bf16(
                    fA[i][0].v, fB[j][0].v, acc[i][j], 0, 0, 0);
                acc[i][j] = __builtin_amdgcn_mfma_f32_16x16x32_bf16(
                    fA[i][1].v, fB[j][1].v, acc[i][j], 0, 0, 0);
            }
        __builtin_amdgcn_s_setprio(0);

        // ---- ph2 (mh1): W2 wait; reads A4-7; stage A02+B(g+2) -> cur ----
        if (g < 31) { asm volatile("s_waitcnt vmcnt(6)" ::: "memory"); }
        else        { asm volatile("s_waitcnt vmcnt(0)" ::: "memory"); }
        __builtin_amdgcn_s_barrier();
        if (g < 30) { STA2(c, 0, g + 2); STA2(c, 2, g + 2);
                      STB2(c, 0, g + 2); STB2(c, 1, g + 2); }
#pragma unroll
        for (int i = 0; i < 4; i++) {
            fA[i][0].u = *(const uint4*)(sb + offA[4 + i] + cs0);
            fA[i][1].u = *(const uint4*)(sb + offA[4 + i] + cs1);
        }
        __builtin_amdgcn_s_setprio(1);
#pragma unroll
        for (int i = 0; i < 4; i++)
#pragma unroll
            for (int j = 0; j < 2; j++) {
                acc[4 + i][j] = __builtin_amdgcn_mfma_f32_16x16x32_bf16(
                    fA[i][0].v, fB[j][0].v, acc[4 + i][j], 0, 0, 0);
                acc[4 + i][j] = __builtin_amdgcn_mfma_f32_16x16x32_bf16(
                    fA[i][1].v, fB[j][1].v, acc[4 + i][j], 0, 0, 0);
            }
        __builtin_amdgcn_s_setprio(0);

        if (g < 30)       { asm volatile("s_waitcnt vmcnt(6)" ::: "memory"); }
        else if (g == 30) { asm volatile("s_waitcnt vmcnt(2)" ::: "memory"); }
        if (g < 31) __builtin_amdgcn_s_barrier();
    }

#pragma unroll
    for (int mi = 0; mi < 8; mi++) {
        long row0 = blockM + wm * 128 + mi * 16 + quad * 4;
#pragma unroll
        for (int nj = 0; nj < 2; nj++) {
            long col = blockN + wn * 32 + nj * 16 + l15;
#pragma unroll
            for (int r = 0; r < 4; r++)
                C[(row0 + r) * N + col] = acc[mi][nj][r];
        }
    }
#undef STA2
#undef STB2
}

// ---------------- ba as MFMA GEMM, 128 blocks, wave-split staging ------------
__global__ __launch_bounds__(256) void ba_gemm(
    const u16* __restrict__ hsb, const u16* __restrict__ WbaTb,
    const float* __restrict__ A_log, const float* __restrict__ dtb,
    float* __restrict__ gout, float* __restrict__ bout) {
    __shared__ u16 As[2][32 * 32];
    __shared__ u16 Bs[2][32 * 32];
    int t = threadIdx.x;
    int lane = t & 63, w = t >> 6, l15 = lane & 15, quad = lane >> 4;
    long blockM = (long)blockIdx.x * 32;

    float4v acc = (float4v){0.f, 0.f, 0.f, 0.f};

    int sidx = t & 127;
    const u16* Sg = (t < 128)
        ? hsb + (blockM + (sidx >> 2)) * (long)HID + (sidx & 3) * 8
        : WbaTb + (long)(sidx >> 2) * HID + (sidx & 3) * 8;
    u16* Sl0 = (t < 128) ? As[0] + sidx * 8 : Bs[0] + sidx * 8;
    u16* Sl1 = (t < 128) ? As[1] + sidx * 8 : Bs[1] + sidx * 8;

    GLOAD_LDS16(Sg + 0, Sl0);
    GLOAD_LDS16(Sg + 32, Sl1);

    const int wr = (w >> 1) * 16, wc = (w & 1) * 16;

    for (int k0 = 0; k0 < HID; k0 += 32) {
        int buf = (k0 >> 5) & 1;
        if (k0 < HID - 64) { asm volatile("s_waitcnt vmcnt(1)" ::: "memory"); }
        else               { asm volatile("s_waitcnt vmcnt(0)" ::: "memory"); }
        __builtin_amdgcn_s_barrier();
        FragU fa, fb;
        fa.u = *(const uint4*)(As[buf] + (wr + l15) * 32 + quad * 8);
        fb.u = *(const uint4*)(Bs[buf] + (wc + l15) * 32 + quad * 8);
        asm volatile("s_waitcnt lgkmcnt(0)" ::: "memory");
        __builtin_amdgcn_sched_barrier(0);
        __builtin_amdgcn_s_barrier();     // all reads done before overwrite
        if (k0 + 64 < HID) GLOAD_LDS16(Sg + k0 + 64, buf ? Sl1 : Sl0);
        acc = __builtin_amdgcn_mfma_f32_16x16x32_bf16(fa.v, fb.v, acc, 0, 0, 0);
    }

    {
        int n = wc + l15;
#pragma unroll
        for (int r = 0; r < 4; r++) {
            long m = blockM + wr + quad * 4 + r;
            int b = (int)(m >> 10), l = (int)(m & 1023);
            float v = acc[r];
            if (n < 16) {
                bout[((long)(b * NH + n)) * L_SEQ + l] = 1.f / (1.f + expf(-v));
            } else {
                int h = n - 16;
                float x = v + dtb[h];
                float sp = (x > 20.f) ? x : log1pf(expf(x));
                gout[((long)(b * NH + h)) * L_SEQ + l] = -expf(A_log[h]) * sp;
            }
        }
    }
}

// ---------------- conv(KS=4) + l2norm(q,k) + split v -> bf16 (v3) ------------
// LDS-free: thread t owns 8 consecutive channels (one head slice); the
// 16 threads of a head are CONTIGUOUS LANES in one wave, so the 128-channel
// l2norm reduce is 4 shfl_xor steps. Weights read from convwT [4][6144]
// (coalesced 32B/lane). Zero LDS, zero barriers, zero bank conflicts.
__global__ __launch_bounds__(256) void conv_qkv(
    const u16* __restrict__ qkvz, const float* __restrict__ wT,
    const float* __restrict__ conv_b,
    u16* __restrict__ qs, u16* __restrict__ ks, u16* __restrict__ vs) {
    // XCD swizzle: consecutive bl (sharing 3 of 4 qkvz rows) on same XCD.
    int orig = blockIdx.x;
    int bl = ((orig & 7) << 9) + (orig >> 3);   // 4096 = 8 x 512, bijective
    int b = bl >> 10, l = bl & 1023;
    int t = threadIdx.x;
    const int ok3 = (l >= 3), ok2 = (l >= 2), ok1 = (l >= 1);
    const int h = t >> 4;            // head slice within pass (0..15)
    const int d = (t & 15) * 8;      // dim offset within head

#pragma unroll
    for (int pass = 0; pass < 3; pass++) {
        int c = pass * 2048 + t * 8;
        long rowbase = (long)(b * L_SEQ + l) * NQKVZ + c;
        uint4 x0 = *(const uint4*)(qkvz + rowbase);
        uint4 x1 = ok1 ? *(const uint4*)(qkvz + rowbase - 1L * NQKVZ) : (uint4){0, 0, 0, 0};
        uint4 x2 = ok2 ? *(const uint4*)(qkvz + rowbase - 2L * NQKVZ) : (uint4){0, 0, 0, 0};
        uint4 x3 = ok3 ? *(const uint4*)(qkvz + rowbase - 3L * NQKVZ) : (uint4){0, 0, 0, 0};
        // wT plane k multiplies row l-3+k: plane0 -> x3 ... plane3 -> x0
        float w3[8], w2[8], w1[8], w0[8], bb[8];
        *(float4*)&w3[0] = *(const float4*)(wT + 0 * CONV_DIM + c);
        *(float4*)&w3[4] = *(const float4*)(wT + 0 * CONV_DIM + c + 4);
        *(float4*)&w2[0] = *(const float4*)(wT + 1 * CONV_DIM + c);
        *(float4*)&w2[4] = *(const float4*)(wT + 1 * CONV_DIM + c + 4);
        *(float4*)&w1[0] = *(const float4*)(wT + 2 * CONV_DIM + c);
        *(float4*)&w1[4] = *(const float4*)(wT + 2 * CONV_DIM + c + 4);
        *(float4*)&w0[0] = *(const float4*)(wT + 3 * CONV_DIM + c);
        *(float4*)&w0[4] = *(const float4*)(wT + 3 * CONV_DIM + c + 4);
        *(float4*)&bb[0] = *(const float4*)(conv_b + c);
        *(float4*)&bb[4] = *(const float4*)(conv_b + c + 4);
        const u16* p0 = (const u16*)&x0;
        const u16* p1 = (const u16*)&x1;
        const u16* p2 = (const u16*)&x2;
        const u16* p3 = (const u16*)&x3;
        float v[8];
#pragma unroll
        for (int j = 0; j < 8; j++) {
            float a = bb[j] + bf2f(p0[j]) * w0[j];
            if (ok1) a += bf2f(p1[j]) * w1[j];
            if (ok2) a += bf2f(p2[j]) * w2[j];
            if (ok3) a += bf2f(p3[j]) * w3[j];
            v[j] = a;
        }
        u16 outv[8];
        if (pass < 2) {
            float s = 0.f;
#pragma unroll
            for (int j = 0; j < 8; j++) s += v[j] * v[j];
            s += __shfl_xor(s, 1);
            s += __shfl_xor(s, 2);
            s += __shfl_xor(s, 4);
            s += __shfl_xor(s, 8);
            float r = rsqrtf(s + 1e-6f);
#pragma unroll
            for (int j = 0; j < 8; j++) outv[j] = f2bf(v[j] * r);
            u16* dst = (pass == 0) ? qs : ks;
            *(uint4*)&dst[(((long)(b * NH + h)) * L_SEQ + l) * DK + d] = *(const uint4*)outv;
        } else {
#pragma unroll
            for (int j = 0; j < 8; j++) outv[j] = f2bf(v[j]);
            *(uint4*)&vs[(((long)(b * NH + h)) * L_SEQ + l) * DV + d] = *(const uint4*)outv;
        }
    }
}

// ---------------- gdn_prep v2: per-chunk T, P, wb, ql, kd, gam ---------------
__global__ __launch_bounds__(256) void gdn_prep(
    const u16* __restrict__ ks_g, const u16* __restrict__ qs_g,
    const float* __restrict__ g_g, const float* __restrict__ b_g,
    u16* __restrict__ Tbuf, u16* __restrict__ Pbuf,
    u16* __restrict__ wbq, u16* __restrict__ qlq, u16* __restrict__ kdq,
    float* __restrict__ gam_g) {
    int cid = blockIdx.x;
    int bh = cid >> 4;
    int ch = cid & 15;
    long rowbase = (long)bh * L_SEQ + ch * 64;
    int t = threadIdx.x;
    int lane = t & 63, w = t >> 6, l15 = lane & 15, quad = lane >> 4;

    __shared__ u16 Kl[64 * 136];
    __shared__ u16 Ql[64 * 136];
    __shared__ float Am[64 * 66];
    __shared__ float Tm[64 * 66];
    __shared__ float Tt[32 * 33];
    __shared__ float Gs[64], lamL[64], betaL[64], dlL[64];

    {   // stage K,Q rows bf16 -> padded LDS; stage g, beta
        int row = t >> 2, seg = (t & 3) * 32;
        const u16* ksrc = ks_g + (rowbase + row) * DK + seg;
        const u16* qsrc = qs_g + (rowbase + row) * DK + seg;
        *(uint4*)&Kl[row * 136 + seg]      = *(const uint4*)ksrc;
        *(uint4*)&Kl[row * 136 + seg + 8]  = *(const uint4*)(ksrc + 8);
        *(uint4*)&Kl[row * 136 + seg + 16] = *(const uint4*)(ksrc + 16);
        *(uint4*)&Kl[row * 136 + seg + 24] = *(const uint4*)(ksrc + 24);
        *(uint4*)&Ql[row * 136 + seg]      = *(const uint4*)qsrc;
        *(uint4*)&Ql[row * 136 + seg + 8]  = *(const uint4*)(qsrc + 8);
        *(uint4*)&Ql[row * 136 + seg + 16] = *(const uint4*)(qsrc + 16);
        *(uint4*)&Ql[row * 136 + seg + 24] = *(const uint4*)(qsrc + 24);
        if (t < 64) Gs[t] = g_g[rowbase + t];
        else if (t < 128) betaL[t - 64] = b_g[rowbase + t - 64];
    }
    __syncthreads();
    if (t < 64) {   // inclusive prefix scan (Kogge-Stone, wave 0)
        float gv = Gs[t];
#pragma unroll
        for (int off = 1; off < 64; off <<= 1) {
            float n = __shfl_up(gv, off);
            if (lane >= off) gv += n;
        }
        Gs[t] = gv;
    }
    __syncthreads();
    if (t < 64) {
        float G63 = Gs[63];
        float lm = expf(Gs[t]);
        lamL[t] = lm;
        dlL[t] = expf(G63 - Gs[t]);
        if (t == 0) gam_g[cid] = expf(G63);
    }
    // MFMA: KK^T and QK^T (wave w = row-stripe w*16)
    float4v accKK[4], accQK[4];
#pragma unroll
    for (int tj = 0; tj < 4; tj++) {
        accKK[tj] = (float4v){0.f, 0.f, 0.f, 0.f};
        accQK[tj] = (float4v){0.f, 0.f, 0.f, 0.f};
    }
#pragma unroll
    for (int k0 = 0; k0 < 128; k0 += 32) {
        FragU ka, qa;
        ka.u = *(const uint4*)&Kl[(w * 16 + l15) * 136 + k0 + quad * 8];
        qa.u = *(const uint4*)&Ql[(w * 16 + l15) * 136 + k0 + quad * 8];
#pragma unroll
        for (int tj = 0; tj < 4; tj++) {
            FragU kb;
            kb.u = *(const uint4*)&Kl[(tj * 16 + l15) * 136 + k0 + quad * 8];
            accKK[tj] = __builtin_amdgcn_mfma_f32_16x16x32_bf16(ka.v, kb.v, accKK[tj], 0, 0, 0);
            accQK[tj] = __builtin_amdgcn_mfma_f32_16x16x32_bf16(qa.v, kb.v, accQK[tj], 0, 0, 0);
        }
    }
    __syncthreads();   // lamL/betaL/dlL visible
    // mask + scale; Am -> LDS fp32, P -> global bf16
#pragma unroll
    for (int tj = 0; tj < 4; tj++) {
#pragma unroll
        for (int r = 0; r < 4; r++) {
            int ti_ = w * 16 + quad * 4 + r;
            int j = tj * 16 + l15;
            float e = (j <= ti_) ? expf(Gs[ti_] - Gs[j]) : 0.f;
            Am[ti_ * 66 + j] = (j < ti_) ? betaL[ti_] * e * accKK[tj][r] : 0.f;
            Pbuf[(long)cid * 4096 + ti_ * 64 + j] =
                (j <= ti_) ? f2bf(GDN_SCALE * e * accQK[tj][r]) : (u16)0;
        }
    }
    // wbq, qlq (row-major [64][128])
    {
        int row = t >> 2, seg = (t & 3) * 32;
        float sw = -betaL[row] * lamL[row];
        float sq = GDN_SCALE * lamL[row];
#pragma unroll
        for (int c0 = 0; c0 < 32; c0 += 8) {
            u16 wt[8], qt2[8];
#pragma unroll
            for (int j2 = 0; j2 < 8; j2++) {
                wt[j2]  = f2bf(sw * bf2f(Kl[row * 136 + seg + c0 + j2]));
                qt2[j2] = f2bf(sq * bf2f(Ql[row * 136 + seg + c0 + j2]));
            }
            *(uint4*)&wbq[(long)cid * 8192 + row * 128 + seg + c0] = *(uint4*)wt;
            *(uint4*)&qlq[(long)cid * 8192 + row * 128 + seg + c0] = *(uint4*)qt2;
        }
    }
    // kdq (transposed [128 k][64 t]) — all 256 threads
    {
        int k = t & 127, t0b = (t >> 7) * 32;
#pragma unroll
        for (int t0 = 0; t0 < 32; t0 += 8) {
            u16 tmp[8];
#pragma unroll
            for (int j2 = 0; j2 < 8; j2++)
                tmp[j2] = f2bf(dlL[t0b + t0 + j2] * bf2f(Kl[(t0b + t0 + j2) * 136 + k]));
            *(uint4*)&kdq[(long)cid * 8192 + k * 64 + t0b + t0] = *(uint4*)tmp;
        }
    }
    __syncthreads();
    // fwd-subst: T11 (lanes 0-31 of wave 0), T22 (lanes 0-31 of wave 1), zero T12
    if (t < 32) {
        int c = t;
        for (int i = 0; i < 32; i++) {
            float s = (i == c) ? 1.f : 0.f;
            for (int j = 0; j < i; j++) s -= Am[i * 66 + j] * Tm[j * 66 + c];
            Tm[i * 66 + c] = s;
        }
    } else if (t >= 64 && t < 96) {
        int c = 32 + (t - 64);
        for (int i = 32; i < 64; i++) {
            float s = (i == c) ? 1.f : 0.f;
            for (int j = 32; j < i; j++) s -= Am[i * 66 + j] * Tm[j * 66 + c];
            Tm[i * 66 + c] = s;
        }
    } else if (t >= 128 && t < 192) {
        int idx = t - 128;
        for (int kk = 0; kk < 16; kk++) {
            int e = idx * 16 + kk;
            Tm[(e >> 5) * 66 + 32 + (e & 31)] = 0.f;
        }
    }
    __syncthreads();
    {   // Tt = A21 * T11  (32x32, 4 elems/thread)
        int e0 = t * 4;
#pragma unroll
        for (int kk = 0; kk < 4; kk++) {
            int e = e0 + kk; int i = e >> 5, c = e & 31;
            float s = 0.f;
            for (int j = 0; j < 32; j++) s += Am[(32 + i) * 66 + j] * Tm[j * 66 + c];
            Tt[i * 33 + c] = s;
        }
    }
    __syncthreads();
    {   // T21 = -T22 * Tt
        int e0 = t * 4;
#pragma unroll
        for (int kk = 0; kk < 4; kk++) {
            int e = e0 + kk; int i = e >> 5, c = e & 31;
            float s = 0.f;
            for (int j = 0; j < 32; j++) s -= Tm[(32 + i) * 66 + 32 + j] * Tt[j * 33 + c];
            Tm[(32 + i) * 66 + c] = s;
        }
    }
    __syncthreads();
    {   // T -> global bf16
        int row = t >> 2, c0 = (t & 3) * 16;
        u16 tmp[16];
#pragma unroll
        for (int i = 0; i < 16; i++) tmp[i] = f2bf(Tm[row * 66 + c0 + i]);
        *(uint4*)&Tbuf[(long)cid * 4096 + row * 64 + c0]     = *(uint4*)tmp;
        *(uint4*)&Tbuf[(long)cid * 4096 + row * 64 + c0 + 8] = *(uint4*)(tmp + 8);
    }
}

// ---------------- gdn_chunk v3: direct-global fragments, 512 blocks ----------
__global__ __launch_bounds__(256) void gdn_chunk(
    const u16* __restrict__ vs_g, const float* __restrict__ b_g,
    const u16* __restrict__ Tq, const u16* __restrict__ Pq,
    const u16* __restrict__ wbq, const u16* __restrict__ qlq,
    const u16* __restrict__ kdq, const float* __restrict__ gam_g,
    float* __restrict__ o_g) {
    int orig = blockIdx.x;
    int bid = ((orig & 7) << 6) + (orig >> 3);   // 512 = 8 x 64, bijective
    int dc = bid & 7;
    int bh = bid >> 3;
    int b = bh >> 4, h = bh & 15;
    int t = threadIdx.x;
    int lane = t & 63, w = t >> 6, l15 = lane & 15, quad = lane >> 4;

    __shared__ u16 s0h[16 * 136], s0l[16 * 136];   // S0^T [v][k] hi/lo
    __shared__ float vO[64 * 20];                  // vb / O, [t][v]
    __shared__ u16 rhsT[16 * 72], DT[16 * 72];     // [v][t]

    float4v S0r[2];
    S0r[0] = (float4v){0.f, 0.f, 0.f, 0.f};
    S0r[1] = (float4v){0.f, 0.f, 0.f, 0.f};

    const int orow = t >> 2, oseg = (t & 3) * 4;   // 64 rows x 16 cols

    for (int ch = 0; ch < 16; ch++) {
        int cid = bh * 16 + ch;
        long rowbase = (long)bh * L_SEQ + ch * 64;
        float gam = gam_g[cid];

        const u16* wbp = wbq + (long)cid * 8192 + (w * 16 + l15) * 128 + quad * 8;
        uint4 wbf0 = *(const uint4*)(wbp);
        uint4 wbf1 = *(const uint4*)(wbp + 32);
        uint4 wbf2 = *(const uint4*)(wbp + 64);
        uint4 wbf3 = *(const uint4*)(wbp + 96);

        // ---- phase a: store prev O, load vb, split S0 ----
        if (ch > 0) {
            float4 a = *(const float4*)&vO[orow * 20 + oseg];
            float* d2 = o_g + (((long)b * L_SEQ + (ch - 1) * 64 + orow) * 16 + h) * 128L
                        + dc * 16 + oseg;
            *(float4*)d2 = a;
        }
        {
            float beta = b_g[rowbase + orow];
            uint2 vv = *(const uint2*)(vs_g + (rowbase + orow) * DV + dc * 16 + oseg);
            const u16* vp = (const u16*)&vv;
#pragma unroll
            for (int j2 = 0; j2 < 4; j2++)
                vO[orow * 20 + oseg + j2] = beta * bf2f(vp[j2]);
        }
#pragma unroll
        for (int ktl = 0; ktl < 2; ktl++) {
            int kc = (2 * w + ktl) * 16 + l15;
#pragma unroll
            for (int r = 0; r < 4; r++) {
                float x = S0r[ktl][r];
                u16 hi = f2bf(x);
                float lo = x - bf2f(hi);
                s0h[(quad * 4 + r) * 136 + kc] = hi;
                s0l[(quad * 4 + r) * 136 + kc] = f2bf(lo);
            }
        }
        __syncthreads();

        // ---- phase b: RHS[t][v] = vb + wb*(S0h+S0l) -> rhsT ----
        const u16* Tp = Tq + (long)cid * 4096 + (w * 16 + l15) * 64 + quad * 8;
        uint4 Tf0 = *(const uint4*)(Tp);
        uint4 Tf1 = *(const uint4*)(Tp + 32);
        {
            float4v acc;
#pragma unroll
            for (int r = 0; r < 4; r++)
                acc[r] = vO[(w * 16 + quad * 4 + r) * 20 + l15];
            uint4 wbf[4] = {wbf0, wbf1, wbf2, wbf3};
#pragma unroll
            for (int k0 = 0; k0 < 4; k0++) {
                FragU a, bh_, bl_;
                a.u = wbf[k0];
                bh_.u = *(const uint4*)&s0h[l15 * 136 + k0 * 32 + quad * 8];
                acc = __builtin_amdgcn_mfma_f32_16x16x32_bf16(a.v, bh_.v, acc, 0, 0, 0);
                bl_.u = *(const uint4*)&s0l[l15 * 136 + k0 * 32 + quad * 8];
                acc = __builtin_amdgcn_mfma_f32_16x16x32_bf16(a.v, bl_.v, acc, 0, 0, 0);
            }
            u16 tmp[4] = {f2bf(acc[0]), f2bf(acc[1]), f2bf(acc[2]), f2bf(acc[3])};
            *(uint2*)&rhsT[l15 * 72 + w * 16 + quad * 4] = *(uint2*)tmp;
        }
        __syncthreads();

        // ---- phase c: D = T*RHS -> DT ----
        const u16* qlp = qlq + (long)cid * 8192 + (w * 16 + l15) * 128 + quad * 8;
        uint4 qlf0 = *(const uint4*)(qlp);
        uint4 qlf1 = *(const uint4*)(qlp + 32);
        uint4 qlf2 = *(const uint4*)(qlp + 64);
        uint4 qlf3 = *(const uint4*)(qlp + 96);
        const u16* Pp = Pq + (long)cid * 4096 + (w * 16 + l15) * 64 + quad * 8;
        uint4 Pf0 = *(const uint4*)(Pp);
        uint4 Pf1 = *(const uint4*)(Pp + 32);
        {
            float4v acc = (float4v){0.f, 0.f, 0.f, 0.f};
            uint4 Tf[2] = {Tf0, Tf1};
#pragma unroll
            for (int k0 = 0; k0 < 2; k0++) {
                FragU a, b_;
                a.u = Tf[k0];
                b_.u = *(const uint4*)&rhsT[l15 * 72 + k0 * 32 + quad * 8];
                acc = __builtin_amdgcn_mfma_f32_16x16x32_bf16(a.v, b_.v, acc, 0, 0, 0);
            }
            u16 tmp[4] = {f2bf(acc[0]), f2bf(acc[1]), f2bf(acc[2]), f2bf(acc[3])};
            *(uint2*)&DT[l15 * 72 + w * 16 + quad * 4] = *(uint2*)tmp;
        }
        __syncthreads();

        // ---- phase d: O = ql*S0 + P*D ; S0 = gam*S0 + kd^T D ----
        uint4 kdf[2][2];
#pragma unroll
        for (int ktl = 0; ktl < 2; ktl++) {
            const u16* kdp = kdq + (long)cid * 8192 + ((2 * w + ktl) * 16 + l15) * 64 + quad * 8;
            kdf[ktl][0] = *(const uint4*)(kdp);
            kdf[ktl][1] = *(const uint4*)(kdp + 32);
        }
        {
            float4v acc = (float4v){0.f, 0.f, 0.f, 0.f};
            uint4 qlf[4] = {qlf0, qlf1, qlf2, qlf3};
#pragma unroll
            for (int k0 = 0; k0 < 4; k0++) {
                FragU a, bh_, bl_;
                a.u = qlf[k0];
                bh_.u = *(const uint4*)&s0h[l15 * 136 + k0 * 32 + quad * 8];
                acc = __builtin_amdgcn_mfma_f32_16x16x32_bf16(a.v, bh_.v, acc, 0, 0, 0);
                bl_.u = *(const uint4*)&s0l[l15 * 136 + k0 * 32 + quad * 8];
                acc = __builtin_amdgcn_mfma_f32_16x16x32_bf16(a.v, bl_.v, acc, 0, 0, 0);
            }
            uint4 Pf[2] = {Pf0, Pf1};
#pragma unroll
            for (int k0 = 0; k0 < 2; k0++) {
                FragU a, b_;
                a.u = Pf[k0];
                b_.u = *(const uint4*)&DT[l15 * 72 + k0 * 32 + quad * 8];
                acc = __builtin_amdgcn_mfma_f32_16x16x32_bf16(a.v, b_.v, acc, 0, 0, 0);
            }
#pragma unroll
            for (int r = 0; r < 4; r++)
                vO[(w * 16 + quad * 4 + r) * 20 + l15] = acc[r];
        }
#pragma unroll
        for (int ktl = 0; ktl < 2; ktl++) {
            float4v acc = S0r[ktl];
#pragma unroll
            for (int r = 0; r < 4; r++) acc[r] *= gam;
#pragma unroll
            for (int t0 = 0; t0 < 2; t0++) {
                FragU a, b_;
                a.u = *(const uint4*)&DT[l15 * 72 + t0 * 32 + quad * 8];
                b_.u = kdf[ktl][t0];
                acc = __builtin_amdgcn_mfma_f32_16x16x32_bf16(a.v, b_.v, acc, 0, 0, 0);
            }
            S0r[ktl] = acc;
        }
        __syncthreads();
    }
    {
        float4 a = *(const float4*)&vO[orow * 20 + oseg];
        float* d2 = o_g + (((long)b * L_SEQ + 15 * 64 + orow) * 16 + h) * 128L
                    + dc * 16 + oseg;
        *(float4*)d2 = a;
    }
}

// ---------------- gated RMS norm -> bf16 A2 ----------------------------------
__global__ __launch_bounds__(128) void gated_norm(
    const float* __restrict__ o, const u16* __restrict__ qkvz,
    const float* __restrict__ norm_w, u16* __restrict__ A2) {
    int bid = blockIdx.x;  // (b*L+l)*16 + h
    int t = threadIdx.x;   // 0..127
    float ov = o[(long)bid * 128 + t];
    float s = ov * ov;
#pragma unroll
    for (int off = 32; off > 0; off >>= 1) s += __shfl_down(s, off);
    __shared__ float ws2[2];
    if ((t & 63) == 0) ws2[t >> 6] = s;
    __syncthreads();
    float tot = ws2[0] + ws2[1];
    float rinv = rsqrtf(tot * (1.f / 128.f) + 1e-6f);
    int bl = bid >> 4, h = bid & 15;
    float z = bf2f(qkvz[(long)bl * NQKVZ + CONV_DIM + h * 128 + t]);
    float sig = 1.f / (1.f + expf(-z));
    float val = ov * rinv * norm_w[t] * sig;
    A2[(long)bl * 2048 + h * 128 + t] = f2bf(val);
}

// ---------------- host-side launcher -----------------------------------------
extern "C" void kernel_launch(void* const* d_in, const int* in_sizes, int n_in,
                              void* d_out, int out_size, void* d_ws, size_t ws_size,
                              hipStream_t stream) {
    const float* hs    = (const float*)d_in[0];
    const float* Wqkvz = (const float*)d_in[1];
    const float* Wba   = (const float*)d_in[2];
    const float* convw = (const float*)d_in[3];
    const float* convb = (const float*)d_in[4];
    const float* A_log = (const float*)d_in[5];
    const float* dtb   = (const float*)d_in[6];
    const float* normw = (const float*)d_in[7];
    const float* Wout  = (const float*)d_in[8];

    char* ws = (char*)d_ws;
    size_t off = 0;
    auto alloc = [&](size_t bytes) {
        size_t o = off;
        off = (off + bytes + 255) & ~(size_t)255;
        return o;
    };
    // region0: WqkvzT (bf16) — dead after GEMM1, reused for os (fp32)
    size_t r0 = alloc((size_t)NQKVZ * HID * 2);
    // region1: hs_bf16 — kept through ba_gemm; A2 aliases after
    size_t r1 = alloc((size_t)4096 * HID * 2);
    u16*   WqkvzT = (u16*)(ws + r0);
    float* os     = (float*)(ws + r0);
    u16*   hsb    = (u16*)(ws + r1);
    u16*   A2     = (u16*)(ws + r1);   // written by gated_norm after ba_gemm done
    u16*   qkvz   = (u16*)(ws + alloc((size_t)4096 * NQKVZ * 2));
    u16*   qs     = (u16*)(ws + alloc((size_t)64 * L_SEQ * DK * 2));
    u16*   ks     = (u16*)(ws + alloc((size_t)64 * L_SEQ * DK * 2));
    u16*   vs     = (u16*)(ws + alloc((size_t)64 * L_SEQ * DV * 2));
    float* gs     = (float*)(ws + alloc((size_t)64 * L_SEQ * 4));
    float* bs     = (float*)(ws + alloc((size_t)64 * L_SEQ * 4));
    u16*   WoutT  = (u16*)(ws + alloc((size_t)HID * 2048 * 2));
    u16*   WbaTb  = (u16*)(ws + alloc((size_t)32 * HID * 2));
    u16*   Tbuf   = (u16*)(ws + alloc((size_t)1024 * 4096 * 2));
    u16*   Pbuf   = (u16*)(ws + alloc((size_t)1024 * 4096 * 2));
    u16*   wbq    = (u16*)(ws + alloc((size_t)1024 * 8192 * 2));
    u16*   qlq    = (u16*)(ws + alloc((size_t)1024 * 8192 * 2));
    u16*   kdq    = (u16*)(ws + alloc((size_t)1024 * 8192 * 2));
    float* gamb   = (float*)(ws + alloc((size_t)1024 * 4));
    float* convwT = (float*)(ws + alloc((size_t)4 * CONV_DIM * 4));

    // 1. convert + transposes
    hipLaunchKernelGGL(f32_to_bf16, dim3(4096), dim3(256), 0, stream, hs, hsb);
    hipLaunchKernelGGL(transpose_f32_bf16, dim3(NQKVZ / 32, HID / 32), dim3(256), 0, stream,
                       Wqkvz, WqkvzT, HID, NQKVZ);
    hipLaunchKernelGGL(transpose_f32_bf16, dim3(2048 / 32, 2048 / 32), dim3(256), 0, stream,
                       Wout, WoutT, 2048, 2048);
    hipLaunchKernelGGL(transpose_f32_bf16, dim3(1, HID / 32), dim3(256), 0, stream,
                       Wba, WbaTb, HID, 32);
    hipLaunchKernelGGL(convw_transpose, dim3(CONV_DIM / 256), dim3(256), 0, stream,
                       convw, convwT);

    // 2. GEMM1: qkvz = hs @ W_qkvz (r2 schedule, frozen)
    hipLaunchKernelGGL(gemm1_8ph, dim3(512), dim3(512), 0, stream,
                       hsb, WqkvzT, qkvz);

    // 3. ba (MFMA, 128 blocks, wave-split ring) -> g, beta
    hipLaunchKernelGGL(ba_gemm, dim3(128), dim3(256), 0, stream,
                       hsb, WbaTb, A_log, dtb, gs, bs);

    // 4. conv + l2norm -> q,k,v (bf16), LDS-free shfl-reduce + XCD-swizzled
    hipLaunchKernelGGL(conv_qkv, dim3(4096), dim3(256), 0, stream,
                       qkvz, convwT, convb, qs, ks, vs);

    // 5a. chunk prep (parallel): T, P, wb, ql, kd, gam
    hipLaunchKernelGGL(gdn_prep, dim3(1024), dim3(256), 0, stream,
                       ks, qs, gs, bs, Tbuf, Pbuf, wbq, qlq, kdq, gamb);

    // 5b. chunk recurrence (MFMA, direct-global fragments, XCD-swizzled)
    hipLaunchKernelGGL(gdn_chunk, dim3(512), dim3(256), 0, stream,
                       vs, bs, Tbuf, Pbuf, wbq, qlq, kdq, gamb, os);

    // 6. gated RMS norm -> bf16 A2
    hipLaunchKernelGGL(gated_norm, dim3(4096 * NH), dim3(128), 0, stream,
                       os, qkvz, normw, A2);

    // 7. GEMM2: out = A2 @ W_out (256x128 2-phase counted-vmcnt)
    hipLaunchKernelGGL(gemm2_2ph, dim3(256), dim3(512), 0, stream,
                       A2, WoutT, (float*)d_out);
}

// Round 7
// 503.826 us; speedup vs baseline: 1.1897x; 1.0023x over previous
//
#include <hip/hip_runtime.h>

typedef unsigned short u16;
typedef unsigned int u32;
typedef short short8 __attribute__((ext_vector_type(8)));
typedef float float4v __attribute__((ext_vector_type(4)));

#define L_SEQ 1024
#define NB 4
#define NH 16
#define DK 128
#define DV 128
#define HID 2048
#define NQKVZ 8192
#define CONV_DIM 6144
#define GDN_SCALE 0.08838834764831845f  // 128^-0.5

static __device__ __forceinline__ float bf2f(u16 u) {
    union { u32 i; float f; } x; x.i = ((u32)u) << 16; return x.f;
}
static __device__ __forceinline__ u16 f2bf(float f) {
    union { float f; u32 u; } x; x.f = f;
    u32 r = x.u + 0x7FFF + ((x.u >> 16) & 1);
    return (u16)(r >> 16);
}

union FragU { short8 v; uint4 u; };

// async global->LDS, 16B per lane (lane-contiguous LDS dest required).
#define GLOAD_LDS16(g, l)                                        \
    __builtin_amdgcn_global_load_lds(                            \
        (const __attribute__((address_space(1))) void*)(g),      \
        (__attribute__((address_space(3))) void*)(l), 16, 0, 0)

// ---------------- fp32 -> bf16 elementwise convert ---------------------------
__global__ __launch_bounds__(256) void f32_to_bf16(
    const float* __restrict__ in, u16* __restrict__ out) {
    long i = ((long)blockIdx.x * 256 + threadIdx.x) * 8;
    float4 a = *(const float4*)(in + i);
    float4 b = *(const float4*)(in + i + 4);
    u16 tmp[8];
    tmp[0] = f2bf(a.x); tmp[1] = f2bf(a.y); tmp[2] = f2bf(a.z); tmp[3] = f2bf(a.w);
    tmp[4] = f2bf(b.x); tmp[5] = f2bf(b.y); tmp[6] = f2bf(b.z); tmp[7] = f2bf(b.w);
    *(uint4*)(out + i) = *(const uint4*)tmp;
}

// ---------------- transpose fp32 (RxC) -> bf16 (CxR) -------------------------
__global__ __launch_bounds__(256) void transpose_f32_bf16(
    const float* __restrict__ in, u16* __restrict__ out, int R, int C) {
    __shared__ float tile[32][33];
    int bx = blockIdx.x, by = blockIdx.y;
    int c = threadIdx.x & 31;
    int r0 = threadIdx.x >> 5;
#pragma unroll
    for (int i = 0; i < 4; i++) {
        int r = r0 + i * 8;
        tile[r][c] = in[(long)(by * 32 + r) * C + bx * 32 + c];
    }
    __syncthreads();
#pragma unroll
    for (int i = 0; i < 4; i++) {
        int r = r0 + i * 8;
        out[(long)(bx * 32 + r) * R + by * 32 + c] = f2bf(tile[c][r]);
    }
}

// ---------------- conv_w [6144][4] -> convwT [4][6144] (fp32) ----------------
__global__ __launch_bounds__(256) void convw_transpose(
    const float* __restrict__ w, float* __restrict__ wT) {
    int c = blockIdx.x * 256 + threadIdx.x;
    float4 v = *(const float4*)(w + c * 4);
    wT[0 * CONV_DIM + c] = v.x;
    wT[1 * CONV_DIM + c] = v.y;
    wT[2 * CONV_DIM + c] = v.z;
    wT[3 * CONV_DIM + c] = v.w;
}

// ---------------- GEMM (m97 structure): C = A * BT^T, bf16 in, OutT out ------
#define BM 128
#define BN 128
#define BKK 32

static __device__ __forceinline__ void store_out(u16* p, float v)  { *p = f2bf(v); }
static __device__ __forceinline__ void store_out(float* p, float v){ *p = v; }

template <typename OutT>
__global__ __launch_bounds__(256) void gemm_abT(
    const u16* __restrict__ A, const u16* __restrict__ BT,
    OutT* __restrict__ C, int M, int N, int K) {
    __shared__ u16 As[BM * BKK];
    __shared__ u16 Bs[BN * BKK];
    int t = threadIdx.x;
    int lane = t & 63;
    int w = t >> 6;
    int wm = (w & 1) * 64;
    int wn = (w >> 1) * 64;
    int l15 = lane & 15;
    int quad = lane >> 4;
    long blockM = (long)blockIdx.y * BM;
    long blockN = (long)blockIdx.x * BN;

    float4v acc[4][4];
#pragma unroll
    for (int i = 0; i < 4; i++)
#pragma unroll
        for (int j = 0; j < 4; j++) acc[i][j] = (float4v){0.f, 0.f, 0.f, 0.f};

    const u16* Ab = A + blockM * K;
    const u16* Bb = BT + blockN * K;

    const int r0 = t >> 2,         c0 = (t & 3) * 8;
    const int r1 = (t + 256) >> 2, c1 = ((t + 256) & 3) * 8;
    u16* As0 = As + t * 8;         u16* As1 = As + (t + 256) * 8;
    u16* Bs0 = Bs + t * 8;         u16* Bs1 = Bs + (t + 256) * 8;
    const u16* Ag0 = Ab + (long)r0 * K + c0;
    const u16* Ag1 = Ab + (long)r1 * K + c1;
    const u16* Bg0 = Bb + (long)r0 * K + c0;
    const u16* Bg1 = Bb + (long)r1 * K + c1;

    for (int k0 = 0; k0 < K; k0 += BKK) {
        __syncthreads();
        GLOAD_LDS16(Ag0 + k0, As0);
        GLOAD_LDS16(Ag1 + k0, As1);
        GLOAD_LDS16(Bg0 + k0, Bs0);
        GLOAD_LDS16(Bg1 + k0, Bs1);
        __syncthreads();

        FragU fa[4], fb[4];
#pragma unroll
        for (int i = 0; i < 4; i++) {
            fa[i].u = *(const uint4*)(As + (wm + i * 16 + l15) * BKK + quad * 8);
            fb[i].u = *(const uint4*)(Bs + (wn + i * 16 + l15) * BKK + quad * 8);
        }
#pragma unroll
        for (int i = 0; i < 4; i++)
#pragma unroll
            for (int j = 0; j < 4; j++)
                acc[i][j] = __builtin_amdgcn_mfma_f32_16x16x32_bf16(
                    fa[i].v, fb[j].v, acc[i][j], 0, 0, 0);
    }

#pragma unroll
    for (int i = 0; i < 4; i++) {
        long mrow = blockM + wm + i * 16 + quad * 4;
#pragma unroll
        for (int j = 0; j < 4; j++) {
            long col = blockN + wn + j * 16 + l15;
#pragma unroll
            for (int r = 0; r < 4; r++) {
                store_out(&C[(mrow + r) * N + col], acc[i][j][r]);
            }
        }
    }
}

// ---------------- GEMM1: 256x256 tile, BK=64, 4-phase, deep prefetch ---------
// r7 delta vs r2 (measured-best): SAME barrier/rendezvous skeleton, only
// stage placement + wait count move. Prefetch depth = 1 full tile:
//   ph1 -> A13(g+1) into db (db.A13 died g-1.ph3; 3 barriers)
//   ph2 -> (no stage)
//   ph3 -> A02(g+2) into c  (c.A02 died ph1; 2 barriers)
//   ph4 -> B(g+2) x4 into c (c.B died ph2; 2 barriers)
// Group-end wait vmcnt(6) covers only g+2's loads; everything g+1 needs
// has 3-5 phases of cover (r2's B23 had 1 phase -> the stall).
#define G1_LDSU 32768  // u16 per dbuf (64 KB)

__global__ __launch_bounds__(512, 2) void gemm1_8ph(
    const u16* __restrict__ A, const u16* __restrict__ BT,
    u16* __restrict__ C) {
    const int K = HID, N = NQKVZ;
    __shared__ __align__(16) u16 lds[2 * G1_LDSU];  // 128 KB

    int t = threadIdx.x;
    int lane = t & 63, w = t >> 6, l15 = lane & 15, quad = lane >> 4;
    int wm = w & 1, wn = w >> 1;

    int orig = blockIdx.x;
    int wg = (orig & 7) * 64 + (orig >> 3);
    int p = wg >> 6, q = wg & 63;
    long blockM = (long)((p >> 2) * 8 + (q >> 3)) * 256;  // 0..15
    long blockN = (long)((p & 3) * 8 + (q & 7)) * 256;    // 0..31

    int srow = t >> 3;
    int scol = ((t & 7) ^ (srow & 7)) * 8;
    const u16* Ast = A + (blockM + srow) * (long)K + scol;
    const u16* Bst = BT + (blockN + srow) * (long)K + scol;

#define STA(db, qq, T) GLOAD_LDS16(Ast + (long)(qq) * 64 * K + (T) * 64,      \
                                   lds + (db) * G1_LDSU + (qq) * 4096 + t * 8)
#define STB(db, qq, T) GLOAD_LDS16(Bst + (long)(qq) * 64 * K + (T) * 64,      \
                                   lds + (db) * G1_LDSU + 16384 + (qq) * 4096 + t * 8)

    const int rowA0 = (wm * 128 + l15) * 64;
    const int rowB0 = 16384 + (wn * 64 + l15) * 64;
    const int cs0 = ((quad) ^ (l15 & 7)) * 8;        // kk=0 chunk
    const int cs1 = ((4 + quad) ^ (l15 & 7)) * 8;    // kk=1 chunk

    float4v acc[8][4];
#pragma unroll
    for (int mi = 0; mi < 8; mi++)
#pragma unroll
        for (int nj = 0; nj < 4; nj++) acc[mi][nj] = (float4v){0.f, 0.f, 0.f, 0.f};

    // prologue: T0 complete (8); T1 A02+B (6). Drain to T0 -> vmcnt(6).
    STA(0, 0, 0); STA(0, 1, 0); STA(0, 2, 0); STA(0, 3, 0);
    STB(0, 0, 0); STB(0, 1, 0); STB(0, 2, 0); STB(0, 3, 0);
    STA(1, 0, 1); STA(1, 2, 1);
    STB(1, 0, 1); STB(1, 1, 1); STB(1, 2, 1); STB(1, 3, 1);
    asm volatile("s_waitcnt vmcnt(6)" ::: "memory");
    __builtin_amdgcn_s_barrier();

    FragU bA[4][2], bB0[2][2], bB1[2][2];

    for (int g = 0; g < 32; ++g) {
        const int c = g & 1, db = c ^ 1;
        const u16* sb = lds + c * G1_LDSU;

        // ---- ph1 (mh0,nh0): 8 A-reads + 4 B-reads; stage A13(g+1) -> db ----
#pragma unroll
        for (int i = 0; i < 4; i++) {
            bA[i][0].u = *(const uint4*)(sb + rowA0 + i * 1024 + cs0);
            bA[i][1].u = *(const uint4*)(sb + rowA0 + i * 1024 + cs1);
        }
#pragma unroll
        for (int j = 0; j < 2; j++) {
            bB0[j][0].u = *(const uint4*)(sb + rowB0 + j * 1024 + cs0);
            bB0[j][1].u = *(const uint4*)(sb + rowB0 + j * 1024 + cs1);
        }
        if (g + 1 < 32) { STA(db, 1, g + 1); STA(db, 3, g + 1); }
        __builtin_amdgcn_s_barrier();
        asm volatile("s_waitcnt lgkmcnt(0)" ::: "memory");
        __builtin_amdgcn_s_setprio(1);
#pragma unroll
        for (int i = 0; i < 4; i++)
#pragma unroll
            for (int j = 0; j < 2; j++) {
                acc[i][j] = __builtin_amdgcn_mfma_f32_16x16x32_bf16(
                    bA[i][0].v, bB0[j][0].v, acc[i][j], 0, 0, 0);
                acc[i][j] = __builtin_amdgcn_mfma_f32_16x16x32_bf16(
                    bA[i][1].v, bB0[j][1].v, acc[i][j], 0, 0, 0);
            }
        __builtin_amdgcn_s_setprio(0);

        // ---- ph2 (mh0,nh1): 4 B-reads; no stage ----
#pragma unroll
        for (int j = 0; j < 2; j++) {
            bB1[j][0].u = *(const uint4*)(sb + rowB0 + (2 + j) * 1024 + cs0);
            bB1[j][1].u = *(const uint4*)(sb + rowB0 + (2 + j) * 1024 + cs1);
        }
        __builtin_amdgcn_s_barrier();
        asm volatile("s_waitcnt lgkmcnt(0)" ::: "memory");
        __builtin_amdgcn_s_setprio(1);
#pragma unroll
        for (int i = 0; i < 4; i++)
#pragma unroll
            for (int j = 0; j < 2; j++) {
                acc[i][2 + j] = __builtin_amdgcn_mfma_f32_16x16x32_bf16(
                    bA[i][0].v, bB1[j][0].v, acc[i][2 + j], 0, 0, 0);
                acc[i][2 + j] = __builtin_amdgcn_mfma_f32_16x16x32_bf16(
                    bA[i][1].v, bB1[j][1].v, acc[i][2 + j], 0, 0, 0);
            }
        __builtin_amdgcn_s_setprio(0);

        // ---- ph3 (mh1,nh0): 8 A-reads; stage A02(g+2) -> c (dead ph1) ----
#pragma unroll
        for (int i = 0; i < 4; i++) {
            bA[i][0].u = *(const uint4*)(sb + rowA0 + (4 + i) * 1024 + cs0);
            bA[i][1].u = *(const uint4*)(sb + rowA0 + (4 + i) * 1024 + cs1);
        }
        if (g + 2 < 32) { STA(c, 0, g + 2); STA(c, 2, g + 2); }
        __builtin_amdgcn_s_barrier();
        asm volatile("s_waitcnt lgkmcnt(0)" ::: "memory");
        __builtin_amdgcn_s_setprio(1);
#pragma unroll
        for (int i = 0; i < 4; i++)
#pragma unroll
            for (int j = 0; j < 2; j++) {
                acc[4 + i][j] = __builtin_amdgcn_mfma_f32_16x16x32_bf16(
                    bA[i][0].v, bB0[j][0].v, acc[4 + i][j], 0, 0, 0);
                acc[4 + i][j] = __builtin_amdgcn_mfma_f32_16x16x32_bf16(
                    bA[i][1].v, bB0[j][1].v, acc[4 + i][j], 0, 0, 0);
            }
        __builtin_amdgcn_s_setprio(0);

        // ---- ph4 (mh1,nh1): 0 reads; stage B(g+2) x4 -> c (dead ph2) ----
        if (g + 2 < 32) { STB(c, 0, g + 2); STB(c, 1, g + 2);
                          STB(c, 2, g + 2); STB(c, 3, g + 2); }
        __builtin_amdgcn_s_barrier();
        __builtin_amdgcn_s_setprio(1);
#pragma unroll
        for (int i = 0; i < 4; i++)
#pragma unroll
            for (int j = 0; j < 2; j++) {
                acc[4 + i][2 + j] = __builtin_amdgcn_mfma_f32_16x16x32_bf16(
                    bA[i][0].v, bB1[j][0].v, acc[4 + i][2 + j], 0, 0, 0);
                acc[4 + i][2 + j] = __builtin_amdgcn_mfma_f32_16x16x32_bf16(
                    bA[i][1].v, bB1[j][1].v, acc[4 + i][2 + j], 0, 0, 0);
            }
        __builtin_amdgcn_s_setprio(0);

        // group end: only g+2's 6 loads may remain in flight
        if (g < 30)       { asm volatile("s_waitcnt vmcnt(6)" ::: "memory"); }
        else if (g == 30) { asm volatile("s_waitcnt vmcnt(0)" ::: "memory"); }
        __builtin_amdgcn_s_barrier();
    }

#pragma unroll
    for (int mi = 0; mi < 8; mi++) {
        long row0 = blockM + wm * 128 + mi * 16 + quad * 4;
#pragma unroll
        for (int nj = 0; nj < 4; nj++) {
            long col = blockN + wn * 64 + nj * 16 + l15;
#pragma unroll
            for (int r = 0; r < 4; r++)
                C[(row0 + r) * N + col] = f2bf(acc[mi][nj][r]);
        }
    }
#undef STA
#undef STB
}

// ---------------- GEMM2: 256x128 tile, BK=64, 2-phase, counted vmcnt ---------
#define G2_LDSU 24576  // u16 per dbuf (48 KB)

__global__ __launch_bounds__(512) void gemm2_2ph(
    const u16* __restrict__ A, const u16* __restrict__ BT,
    float* __restrict__ C) {
    const int K = HID, N = 2048;
    __shared__ __align__(16) u16 lds[2 * G2_LDSU];  // 96 KB

    int t = threadIdx.x;
    int lane = t & 63, w = t >> 6, l15 = lane & 15, quad = lane >> 4;
    int wm = w & 1, wn = w >> 1;

    int orig = blockIdx.x;
    int x = orig & 7, q = orig >> 3;           // q in 0..31
    long blockM = (long)((x >> 2) * 8 + (q >> 2)) * 256;   // 0..15
    long blockN = (long)((x & 3) * 4 + (q & 3)) * 128;     // 0..15

    int srow = t >> 3;
    int scol = ((t & 7) ^ (srow & 7)) * 8;
    const u16* Ast = A + (blockM + srow) * (long)K + scol;
    const u16* Bst = BT + (blockN + srow) * (long)K + scol;

#define STA2(db, qq, T) GLOAD_LDS16(Ast + (long)(qq) * 64 * K + (T) * 64,     \
                                    lds + (db) * G2_LDSU + (qq) * 4096 + t * 8)
#define STB2(db, hh, T) GLOAD_LDS16(Bst + (long)(hh) * 64 * K + (T) * 64,     \
                                    lds + (db) * G2_LDSU + 16384 + (hh) * 4096 + t * 8)

    const int cs0 = ((quad) ^ (l15 & 7)) * 8;
    const int cs1 = ((4 + quad) ^ (l15 & 7)) * 8;
    int offA[8], offB[2];
#pragma unroll
    for (int mi = 0; mi < 8; mi++)
        offA[mi] = (wm * 2 + (mi >> 2)) * 4096 + (((mi & 3) * 16 + l15)) * 64;
#pragma unroll
    for (int nj = 0; nj < 2; nj++)
        offB[nj] = 16384 + (wn >> 1) * 4096 + ((wn & 1) * 32 + nj * 16 + l15) * 64;

    float4v acc[8][2];
#pragma unroll
    for (int mi = 0; mi < 8; mi++)
#pragma unroll
        for (int nj = 0; nj < 2; nj++) acc[mi][nj] = (float4v){0.f, 0.f, 0.f, 0.f};

    STA2(0, 0, 0); STA2(0, 2, 0); STB2(0, 0, 0); STB2(0, 1, 0);
    STA2(0, 1, 0); STA2(0, 3, 0);
    STA2(1, 0, 1); STA2(1, 2, 1); STB2(1, 0, 1); STB2(1, 1, 1);
    asm volatile("s_waitcnt vmcnt(6)" ::: "memory");
    __builtin_amdgcn_s_barrier();

    FragU fA[4][2], fB[2][2];

    for (int g = 0; g < 32; ++g) {
        const int c = g & 1, db = c ^ 1;
        const u16* sb = lds + c * G2_LDSU;

        // ---- ph1 (mh0): reads A0-3 (8) + B (4); stage A13(g+1) -> db ----
#pragma unroll
        for (int i = 0; i < 4; i++) {
            fA[i][0].u = *(const uint4*)(sb + offA[i] + cs0);
            fA[i][1].u = *(const uint4*)(sb + offA[i] + cs1);
        }
#pragma unroll
        for (int j = 0; j < 2; j++) {
            fB[j][0].u = *(const uint4*)(sb + offB[j] + cs0);
            fB[j][1].u = *(const uint4*)(sb + offB[j] + cs1);
        }
        if (g < 31) { STA2(db, 1, g + 1); STA2(db, 3, g + 1); }
        asm volatile("s_waitcnt lgkmcnt(8)" ::: "memory");
        __builtin_amdgcn_s_barrier();
        __builtin_amdgcn_s_setprio(1);
#pragma unroll
        for (int i = 0; i < 4; i++)
#pragma unroll
            for (int j = 0; j < 2; j++) {
                acc[i][j] = __builtin_amdgcn_mfma_f32_16x16x32_bf16(
                    fA[i][0].v, fB[j][0].v, acc[i][j], 0, 0, 0);
                acc[i][j] = __builtin_amdgcn_mfma_f32_16x16x32_bf16(
                    fA[i][1].v, fB[j][1].v, acc[i][j], 0, 0, 0);
            }
        __builtin_amdgcn_s_setprio(0);

        // ---- ph2 (mh1): W2 wait; reads A4-7; stage A02+B(g+2) -> cur ----
        if (g < 31) { asm volatile("s_waitcnt vmcnt(6)" ::: "memory"); }
        else        { asm volatile("s_waitcnt vmcnt(0)" ::: "memory"); }
        __builtin_amdgcn_s_barrier();
        if (g < 30) { STA2(c, 0, g + 2); STA2(c, 2, g + 2);
                      STB2(c, 0, g + 2); STB2(c, 1, g + 2); }
#pragma unroll
        for (int i = 0; i < 4; i++) {
            fA[i][0].u = *(const uint4*)(sb + offA[4 + i] + cs0);
            fA[i][1].u = *(const uint4*)(sb + offA[4 + i] + cs1);
        }
        __builtin_amdgcn_s_setprio(1);
#pragma unroll
        for (int i = 0; i < 4; i++)
#pragma unroll
            for (int j = 0; j < 2; j++) {
                acc[4 + i][j] = __builtin_amdgcn_mfma_f32_16x16x32_bf16(
                    fA[i][0].v, fB[j][0].v, acc[4 + i][j], 0, 0, 0);
                acc[4 + i][j] = __builtin_amdgcn_mfma_f32_16x16x32_bf16(
                    fA[i][1].v, fB[j][1].v, acc[4 + i][j], 0, 0, 0);
            }
        __builtin_amdgcn_s_setprio(0);

        if (g < 30)       { asm volatile("s_waitcnt vmcnt(6)" ::: "memory"); }
        else if (g == 30) { asm volatile("s_waitcnt vmcnt(2)" ::: "memory"); }
        if (g < 31) __builtin_amdgcn_s_barrier();
    }

#pragma unroll
    for (int mi = 0; mi < 8; mi++) {
        long row0 = blockM + wm * 128 + mi * 16 + quad * 4;
#pragma unroll
        for (int nj = 0; nj < 2; nj++) {
            long col = blockN + wn * 32 + nj * 16 + l15;
#pragma unroll
            for (int r = 0; r < 4; r++)
                C[(row0 + r) * N + col] = acc[mi][nj][r];
        }
    }
#undef STA2
#undef STB2
}

// ---------------- ba as MFMA GEMM, 128 blocks, wave-split staging ------------
__global__ __launch_bounds__(256) void ba_gemm(
    const u16* __restrict__ hsb, const u16* __restrict__ WbaTb,
    const float* __restrict__ A_log, const float* __restrict__ dtb,
    float* __restrict__ gout, float* __restrict__ bout) {
    __shared__ u16 As[2][32 * 32];
    __shared__ u16 Bs[2][32 * 32];
    int t = threadIdx.x;
    int lane = t & 63, w = t >> 6, l15 = lane & 15, quad = lane >> 4;
    long blockM = (long)blockIdx.x * 32;

    float4v acc = (float4v){0.f, 0.f, 0.f, 0.f};

    int sidx = t & 127;
    const u16* Sg = (t < 128)
        ? hsb + (blockM + (sidx >> 2)) * (long)HID + (sidx & 3) * 8
        : WbaTb + (long)(sidx >> 2) * HID + (sidx & 3) * 8;
    u16* Sl0 = (t < 128) ? As[0] + sidx * 8 : Bs[0] + sidx * 8;
    u16* Sl1 = (t < 128) ? As[1] + sidx * 8 : Bs[1] + sidx * 8;

    GLOAD_LDS16(Sg + 0, Sl0);
    GLOAD_LDS16(Sg + 32, Sl1);

    const int wr = (w >> 1) * 16, wc = (w & 1) * 16;

    for (int k0 = 0; k0 < HID; k0 += 32) {
        int buf = (k0 >> 5) & 1;
        if (k0 < HID - 64) { asm volatile("s_waitcnt vmcnt(1)" ::: "memory"); }
        else               { asm volatile("s_waitcnt vmcnt(0)" ::: "memory"); }
        __builtin_amdgcn_s_barrier();
        FragU fa, fb;
        fa.u = *(const uint4*)(As[buf] + (wr + l15) * 32 + quad * 8);
        fb.u = *(const uint4*)(Bs[buf] + (wc + l15) * 32 + quad * 8);
        asm volatile("s_waitcnt lgkmcnt(0)" ::: "memory");
        __builtin_amdgcn_sched_barrier(0);
        __builtin_amdgcn_s_barrier();     // all reads done before overwrite
        if (k0 + 64 < HID) GLOAD_LDS16(Sg + k0 + 64, buf ? Sl1 : Sl0);
        acc = __builtin_amdgcn_mfma_f32_16x16x32_bf16(fa.v, fb.v, acc, 0, 0, 0);
    }

    {
        int n = wc + l15;
#pragma unroll
        for (int r = 0; r < 4; r++) {
            long m = blockM + wr + quad * 4 + r;
            int b = (int)(m >> 10), l = (int)(m & 1023);
            float v = acc[r];
            if (n < 16) {
                bout[((long)(b * NH + n)) * L_SEQ + l] = 1.f / (1.f + expf(-v));
            } else {
                int h = n - 16;
                float x = v + dtb[h];
                float sp = (x > 20.f) ? x : log1pf(expf(x));
                gout[((long)(b * NH + h)) * L_SEQ + l] = -expf(A_log[h]) * sp;
            }
        }
    }
}

// ---------------- conv(KS=4) + l2norm(q,k) + split v -> bf16 (v3) ------------
// LDS-free: thread t owns 8 consecutive channels (one head slice); the
// 16 threads of a head are CONTIGUOUS LANES in one wave, so the 128-channel
// l2norm reduce is 4 shfl_xor steps. Weights read from convwT [4][6144]
// (coalesced 32B/lane). Zero LDS, zero barriers, zero bank conflicts.
__global__ __launch_bounds__(256) void conv_qkv(
    const u16* __restrict__ qkvz, const float* __restrict__ wT,
    const float* __restrict__ conv_b,
    u16* __restrict__ qs, u16* __restrict__ ks, u16* __restrict__ vs) {
    // XCD swizzle: consecutive bl (sharing 3 of 4 qkvz rows) on same XCD.
    int orig = blockIdx.x;
    int bl = ((orig & 7) << 9) + (orig >> 3);   // 4096 = 8 x 512, bijective
    int b = bl >> 10, l = bl & 1023;
    int t = threadIdx.x;
    const int ok3 = (l >= 3), ok2 = (l >= 2), ok1 = (l >= 1);
    const int h = t >> 4;            // head slice within pass (0..15)
    const int d = (t & 15) * 8;      // dim offset within head

#pragma unroll
    for (int pass = 0; pass < 3; pass++) {
        int c = pass * 2048 + t * 8;
        long rowbase = (long)(b * L_SEQ + l) * NQKVZ + c;
        uint4 x0 = *(const uint4*)(qkvz + rowbase);
        uint4 x1 = ok1 ? *(const uint4*)(qkvz + rowbase - 1L * NQKVZ) : (uint4){0, 0, 0, 0};
        uint4 x2 = ok2 ? *(const uint4*)(qkvz + rowbase - 2L * NQKVZ) : (uint4){0, 0, 0, 0};
        uint4 x3 = ok3 ? *(const uint4*)(qkvz + rowbase - 3L * NQKVZ) : (uint4){0, 0, 0, 0};
        // wT plane k multiplies row l-3+k: plane0 -> x3 ... plane3 -> x0
        float w3[8], w2[8], w1[8], w0[8], bb[8];
        *(float4*)&w3[0] = *(const float4*)(wT + 0 * CONV_DIM + c);
        *(float4*)&w3[4] = *(const float4*)(wT + 0 * CONV_DIM + c + 4);
        *(float4*)&w2[0] = *(const float4*)(wT + 1 * CONV_DIM + c);
        *(float4*)&w2[4] = *(const float4*)(wT + 1 * CONV_DIM + c + 4);
        *(float4*)&w1[0] = *(const float4*)(wT + 2 * CONV_DIM + c);
        *(float4*)&w1[4] = *(const float4*)(wT + 2 * CONV_DIM + c + 4);
        *(float4*)&w0[0] = *(const float4*)(wT + 3 * CONV_DIM + c);
        *(float4*)&w0[4] = *(const float4*)(wT + 3 * CONV_DIM + c + 4);
        *(float4*)&bb[0] = *(const float4*)(conv_b + c);
        *(float4*)&bb[4] = *(const float4*)(conv_b + c + 4);
        const u16* p0 = (const u16*)&x0;
        const u16* p1 = (const u16*)&x1;
        const u16* p2 = (const u16*)&x2;
        const u16* p3 = (const u16*)&x3;
        float v[8];
#pragma unroll
        for (int j = 0; j < 8; j++) {
            float a = bb[j] + bf2f(p0[j]) * w0[j];
            if (ok1) a += bf2f(p1[j]) * w1[j];
            if (ok2) a += bf2f(p2[j]) * w2[j];
            if (ok3) a += bf2f(p3[j]) * w3[j];
            v[j] = a;
        }
        u16 outv[8];
        if (pass < 2) {
            float s = 0.f;
#pragma unroll
            for (int j = 0; j < 8; j++) s += v[j] * v[j];
            s += __shfl_xor(s, 1);
            s += __shfl_xor(s, 2);
            s += __shfl_xor(s, 4);
            s += __shfl_xor(s, 8);
            float r = rsqrtf(s + 1e-6f);
#pragma unroll
            for (int j = 0; j < 8; j++) outv[j] = f2bf(v[j] * r);
            u16* dst = (pass == 0) ? qs : ks;
            *(uint4*)&dst[(((long)(b * NH + h)) * L_SEQ + l) * DK + d] = *(const uint4*)outv;
        } else {
#pragma unroll
            for (int j = 0; j < 8; j++) outv[j] = f2bf(v[j]);
            *(uint4*)&vs[(((long)(b * NH + h)) * L_SEQ + l) * DV + d] = *(const uint4*)outv;
        }
    }
}

// ---------------- gdn_prep v2: per-chunk T, P, wb, ql, kd, gam ---------------
__global__ __launch_bounds__(256) void gdn_prep(
    const u16* __restrict__ ks_g, const u16* __restrict__ qs_g,
    const float* __restrict__ g_g, const float* __restrict__ b_g,
    u16* __restrict__ Tbuf, u16* __restrict__ Pbuf,
    u16* __restrict__ wbq, u16* __restrict__ qlq, u16* __restrict__ kdq,
    float* __restrict__ gam_g) {
    int cid = blockIdx.x;
    int bh = cid >> 4;
    int ch = cid & 15;
    long rowbase = (long)bh * L_SEQ + ch * 64;
    int t = threadIdx.x;
    int lane = t & 63, w = t >> 6, l15 = lane & 15, quad = lane >> 4;

    __shared__ u16 Kl[64 * 136];
    __shared__ u16 Ql[64 * 136];
    __shared__ float Am[64 * 66];
    __shared__ float Tm[64 * 66];
    __shared__ float Tt[32 * 33];
    __shared__ float Gs[64], lamL[64], betaL[64], dlL[64];

    {   // stage K,Q rows bf16 -> padded LDS; stage g, beta
        int row = t >> 2, seg = (t & 3) * 32;
        const u16* ksrc = ks_g + (rowbase + row) * DK + seg;
        const u16* qsrc = qs_g + (rowbase + row) * DK + seg;
        *(uint4*)&Kl[row * 136 + seg]      = *(const uint4*)ksrc;
        *(uint4*)&Kl[row * 136 + seg + 8]  = *(const uint4*)(ksrc + 8);
        *(uint4*)&Kl[row * 136 + seg + 16] = *(const uint4*)(ksrc + 16);
        *(uint4*)&Kl[row * 136 + seg + 24] = *(const uint4*)(ksrc + 24);
        *(uint4*)&Ql[row * 136 + seg]      = *(const uint4*)qsrc;
        *(uint4*)&Ql[row * 136 + seg + 8]  = *(const uint4*)(qsrc + 8);
        *(uint4*)&Ql[row * 136 + seg + 16] = *(const uint4*)(qsrc + 16);
        *(uint4*)&Ql[row * 136 + seg + 24] = *(const uint4*)(qsrc + 24);
        if (t < 64) Gs[t] = g_g[rowbase + t];
        else if (t < 128) betaL[t - 64] = b_g[rowbase + t - 64];
    }
    __syncthreads();
    if (t < 64) {   // inclusive prefix scan (Kogge-Stone, wave 0)
        float gv = Gs[t];
#pragma unroll
        for (int off = 1; off < 64; off <<= 1) {
            float n = __shfl_up(gv, off);
            if (lane >= off) gv += n;
        }
        Gs[t] = gv;
    }
    __syncthreads();
    if (t < 64) {
        float G63 = Gs[63];
        float lm = expf(Gs[t]);
        lamL[t] = lm;
        dlL[t] = expf(G63 - Gs[t]);
        if (t == 0) gam_g[cid] = expf(G63);
    }
    // MFMA: KK^T and QK^T (wave w = row-stripe w*16)
    float4v accKK[4], accQK[4];
#pragma unroll
    for (int tj = 0; tj < 4; tj++) {
        accKK[tj] = (float4v){0.f, 0.f, 0.f, 0.f};
        accQK[tj] = (float4v){0.f, 0.f, 0.f, 0.f};
    }
#pragma unroll
    for (int k0 = 0; k0 < 128; k0 += 32) {
        FragU ka, qa;
        ka.u = *(const uint4*)&Kl[(w * 16 + l15) * 136 + k0 + quad * 8];
        qa.u = *(const uint4*)&Ql[(w * 16 + l15) * 136 + k0 + quad * 8];
#pragma unroll
        for (int tj = 0; tj < 4; tj++) {
            FragU kb;
            kb.u = *(const uint4*)&Kl[(tj * 16 + l15) * 136 + k0 + quad * 8];
            accKK[tj] = __builtin_amdgcn_mfma_f32_16x16x32_bf16(ka.v, kb.v, accKK[tj], 0, 0, 0);
            accQK[tj] = __builtin_amdgcn_mfma_f32_16x16x32_bf16(qa.v, kb.v, accQK[tj], 0, 0, 0);
        }
    }
    __syncthreads();   // lamL/betaL/dlL visible
    // mask + scale; Am -> LDS fp32, P -> global bf16
#pragma unroll
    for (int tj = 0; tj < 4; tj++) {
#pragma unroll
        for (int r = 0; r < 4; r++) {
            int ti_ = w * 16 + quad * 4 + r;
            int j = tj * 16 + l15;
            float e = (j <= ti_) ? expf(Gs[ti_] - Gs[j]) : 0.f;
            Am[ti_ * 66 + j] = (j < ti_) ? betaL[ti_] * e * accKK[tj][r] : 0.f;
            Pbuf[(long)cid * 4096 + ti_ * 64 + j] =
                (j <= ti_) ? f2bf(GDN_SCALE * e * accQK[tj][r]) : (u16)0;
        }
    }
    // wbq, qlq (row-major [64][128])
    {
        int row = t >> 2, seg = (t & 3) * 32;
        float sw = -betaL[row] * lamL[row];
        float sq = GDN_SCALE * lamL[row];
#pragma unroll
        for (int c0 = 0; c0 < 32; c0 += 8) {
            u16 wt[8], qt2[8];
#pragma unroll
            for (int j2 = 0; j2 < 8; j2++) {
                wt[j2]  = f2bf(sw * bf2f(Kl[row * 136 + seg + c0 + j2]));
                qt2[j2] = f2bf(sq * bf2f(Ql[row * 136 + seg + c0 + j2]));
            }
            *(uint4*)&wbq[(long)cid * 8192 + row * 128 + seg + c0] = *(uint4*)wt;
            *(uint4*)&qlq[(long)cid * 8192 + row * 128 + seg + c0] = *(uint4*)qt2;
        }
    }
    // kdq (transposed [128 k][64 t]) — all 256 threads
    {
        int k = t & 127, t0b = (t >> 7) * 32;
#pragma unroll
        for (int t0 = 0; t0 < 32; t0 += 8) {
            u16 tmp[8];
#pragma unroll
            for (int j2 = 0; j2 < 8; j2++)
                tmp[j2] = f2bf(dlL[t0b + t0 + j2] * bf2f(Kl[(t0b + t0 + j2) * 136 + k]));
            *(uint4*)&kdq[(long)cid * 8192 + k * 64 + t0b + t0] = *(uint4*)tmp;
        }
    }
    __syncthreads();
    // fwd-subst: T11 (lanes 0-31 of wave 0), T22 (lanes 0-31 of wave 1), zero T12
    if (t < 32) {
        int c = t;
        for (int i = 0; i < 32; i++) {
            float s = (i == c) ? 1.f : 0.f;
            for (int j = 0; j < i; j++) s -= Am[i * 66 + j] * Tm[j * 66 + c];
            Tm[i * 66 + c] = s;
        }
    } else if (t >= 64 && t < 96) {
        int c = 32 + (t - 64);
        for (int i = 32; i < 64; i++) {
            float s = (i == c) ? 1.f : 0.f;
            for (int j = 32; j < i; j++) s -= Am[i * 66 + j] * Tm[j * 66 + c];
            Tm[i * 66 + c] = s;
        }
    } else if (t >= 128 && t < 192) {
        int idx = t - 128;
        for (int kk = 0; kk < 16; kk++) {
            int e = idx * 16 + kk;
            Tm[(e >> 5) * 66 + 32 + (e & 31)] = 0.f;
        }
    }
    __syncthreads();
    {   // Tt = A21 * T11  (32x32, 4 elems/thread)
        int e0 = t * 4;
#pragma unroll
        for (int kk = 0; kk < 4; kk++) {
            int e = e0 + kk; int i = e >> 5, c = e & 31;
            float s = 0.f;
            for (int j = 0; j < 32; j++) s += Am[(32 + i) * 66 + j] * Tm[j * 66 + c];
            Tt[i * 33 + c] = s;
        }
    }
    __syncthreads();
    {   // T21 = -T22 * Tt
        int e0 = t * 4;
#pragma unroll
        for (int kk = 0; kk < 4; kk++) {
            int e = e0 + kk; int i = e >> 5, c = e & 31;
            float s = 0.f;
            for (int j = 0; j < 32; j++) s -= Tm[(32 + i) * 66 + 32 + j] * Tt[j * 33 + c];
            Tm[(32 + i) * 66 + c] = s;
        }
    }
    __syncthreads();
    {   // T -> global bf16
        int row = t >> 2, c0 = (t & 3) * 16;
        u16 tmp[16];
#pragma unroll
        for (int i = 0; i < 16; i++) tmp[i] = f2bf(Tm[row * 66 + c0 + i]);
        *(uint4*)&Tbuf[(long)cid * 4096 + row * 64 + c0]     = *(uint4*)tmp;
        *(uint4*)&Tbuf[(long)cid * 4096 + row * 64 + c0 + 8] = *(uint4*)(tmp + 8);
    }
}

// ---------------- gdn_chunk v3: direct-global fragments, 512 blocks ----------
__global__ __launch_bounds__(256) void gdn_chunk(
    const u16* __restrict__ vs_g, const float* __restrict__ b_g,
    const u16* __restrict__ Tq, const u16* __restrict__ Pq,
    const u16* __restrict__ wbq, const u16* __restrict__ qlq,
    const u16* __restrict__ kdq, const float* __restrict__ gam_g,
    float* __restrict__ o_g) {
    int orig = blockIdx.x;
    int bid = ((orig & 7) << 6) + (orig >> 3);   // 512 = 8 x 64, bijective
    int dc = bid & 7;
    int bh = bid >> 3;
    int b = bh >> 4, h = bh & 15;
    int t = threadIdx.x;
    int lane = t & 63, w = t >> 6, l15 = lane & 15, quad = lane >> 4;

    __shared__ u16 s0h[16 * 136], s0l[16 * 136];   // S0^T [v][k] hi/lo
    __shared__ float vO[64 * 20];                  // vb / O, [t][v]
    __shared__ u16 rhsT[16 * 72], DT[16 * 72];     // [v][t]

    float4v S0r[2];
    S0r[0] = (float4v){0.f, 0.f, 0.f, 0.f};
    S0r[1] = (float4v){0.f, 0.f, 0.f, 0.f};

    const int orow = t >> 2, oseg = (t & 3) * 4;   // 64 rows x 16 cols

    for (int ch = 0; ch < 16; ch++) {
        int cid = bh * 16 + ch;
        long rowbase = (long)bh * L_SEQ + ch * 64;
        float gam = gam_g[cid];

        const u16* wbp = wbq + (long)cid * 8192 + (w * 16 + l15) * 128 + quad * 8;
        uint4 wbf0 = *(const uint4*)(wbp);
        uint4 wbf1 = *(const uint4*)(wbp + 32);
        uint4 wbf2 = *(const uint4*)(wbp + 64);
        uint4 wbf3 = *(const uint4*)(wbp + 96);

        // ---- phase a: store prev O, load vb, split S0 ----
        if (ch > 0) {
            float4 a = *(const float4*)&vO[orow * 20 + oseg];
            float* d2 = o_g + (((long)b * L_SEQ + (ch - 1) * 64 + orow) * 16 + h) * 128L
                        + dc * 16 + oseg;
            *(float4*)d2 = a;
        }
        {
            float beta = b_g[rowbase + orow];
            uint2 vv = *(const uint2*)(vs_g + (rowbase + orow) * DV + dc * 16 + oseg);
            const u16* vp = (const u16*)&vv;
#pragma unroll
            for (int j2 = 0; j2 < 4; j2++)
                vO[orow * 20 + oseg + j2] = beta * bf2f(vp[j2]);
        }
#pragma unroll
        for (int ktl = 0; ktl < 2; ktl++) {
            int kc = (2 * w + ktl) * 16 + l15;
#pragma unroll
            for (int r = 0; r < 4; r++) {
                float x = S0r[ktl][r];
                u16 hi = f2bf(x);
                float lo = x - bf2f(hi);
                s0h[(quad * 4 + r) * 136 + kc] = hi;
                s0l[(quad * 4 + r) * 136 + kc] = f2bf(lo);
            }
        }
        __syncthreads();

        // ---- phase b: RHS[t][v] = vb + wb*(S0h+S0l) -> rhsT ----
        const u16* Tp = Tq + (long)cid * 4096 + (w * 16 + l15) * 64 + quad * 8;
        uint4 Tf0 = *(const uint4*)(Tp);
        uint4 Tf1 = *(const uint4*)(Tp + 32);
        {
            float4v acc;
#pragma unroll
            for (int r = 0; r < 4; r++)
                acc[r] = vO[(w * 16 + quad * 4 + r) * 20 + l15];
            uint4 wbf[4] = {wbf0, wbf1, wbf2, wbf3};
#pragma unroll
            for (int k0 = 0; k0 < 4; k0++) {
                FragU a, bh_, bl_;
                a.u = wbf[k0];
                bh_.u = *(const uint4*)&s0h[l15 * 136 + k0 * 32 + quad * 8];
                acc = __builtin_amdgcn_mfma_f32_16x16x32_bf16(a.v, bh_.v, acc, 0, 0, 0);
                bl_.u = *(const uint4*)&s0l[l15 * 136 + k0 * 32 + quad * 8];
                acc = __builtin_amdgcn_mfma_f32_16x16x32_bf16(a.v, bl_.v, acc, 0, 0, 0);
            }
            u16 tmp[4] = {f2bf(acc[0]), f2bf(acc[1]), f2bf(acc[2]), f2bf(acc[3])};
            *(uint2*)&rhsT[l15 * 72 + w * 16 + quad * 4] = *(uint2*)tmp;
        }
        __syncthreads();

        // ---- phase c: D = T*RHS -> DT ----
        const u16* qlp = qlq + (long)cid * 8192 + (w * 16 + l15) * 128 + quad * 8;
        uint4 qlf0 = *(const uint4*)(qlp);
        uint4 qlf1 = *(const uint4*)(qlp + 32);
        uint4 qlf2 = *(const uint4*)(qlp + 64);
        uint4 qlf3 = *(const uint4*)(qlp + 96);
        const u16* Pp = Pq + (long)cid * 4096 + (w * 16 + l15) * 64 + quad * 8;
        uint4 Pf0 = *(const uint4*)(Pp);
        uint4 Pf1 = *(const uint4*)(Pp + 32);
        {
            float4v acc = (float4v){0.f, 0.f, 0.f, 0.f};
            uint4 Tf[2] = {Tf0, Tf1};
#pragma unroll
            for (int k0 = 0; k0 < 2; k0++) {
                FragU a, b_;
                a.u = Tf[k0];
                b_.u = *(const uint4*)&rhsT[l15 * 72 + k0 * 32 + quad * 8];
                acc = __builtin_amdgcn_mfma_f32_16x16x32_bf16(a.v, b_.v, acc, 0, 0, 0);
            }
            u16 tmp[4] = {f2bf(acc[0]), f2bf(acc[1]), f2bf(acc[2]), f2bf(acc[3])};
            *(uint2*)&DT[l15 * 72 + w * 16 + quad * 4] = *(uint2*)tmp;
        }
        __syncthreads();

        // ---- phase d: O = ql*S0 + P*D ; S0 = gam*S0 + kd^T D ----
        uint4 kdf[2][2];
#pragma unroll
        for (int ktl = 0; ktl < 2; ktl++) {
            const u16* kdp = kdq + (long)cid * 8192 + ((2 * w + ktl) * 16 + l15) * 64 + quad * 8;
            kdf[ktl][0] = *(const uint4*)(kdp);
            kdf[ktl][1] = *(const uint4*)(kdp + 32);
        }
        {
            float4v acc = (float4v){0.f, 0.f, 0.f, 0.f};
            uint4 qlf[4] = {qlf0, qlf1, qlf2, qlf3};
#pragma unroll
            for (int k0 = 0; k0 < 4; k0++) {
                FragU a, bh_, bl_;
                a.u = qlf[k0];
                bh_.u = *(const uint4*)&s0h[l15 * 136 + k0 * 32 + quad * 8];
                acc = __builtin_amdgcn_mfma_f32_16x16x32_bf16(a.v, bh_.v, acc, 0, 0, 0);
                bl_.u = *(const uint4*)&s0l[l15 * 136 + k0 * 32 + quad * 8];
                acc = __builtin_amdgcn_mfma_f32_16x16x32_bf16(a.v, bl_.v, acc, 0, 0, 0);
            }
            uint4 Pf[2] = {Pf0, Pf1};
#pragma unroll
            for (int k0 = 0; k0 < 2; k0++) {
                FragU a, b_;
                a.u = Pf[k0];
                b_.u = *(const uint4*)&DT[l15 * 72 + k0 * 32 + quad * 8];
                acc = __builtin_amdgcn_mfma_f32_16x16x32_bf16(a.v, b_.v, acc, 0, 0, 0);
            }
#pragma unroll
            for (int r = 0; r < 4; r++)
                vO[(w * 16 + quad * 4 + r) * 20 + l15] = acc[r];
        }
#pragma unroll
        for (int ktl = 0; ktl < 2; ktl++) {
            float4v acc = S0r[ktl];
#pragma unroll
            for (int r = 0; r < 4; r++) acc[r] *= gam;
#pragma unroll
            for (int t0 = 0; t0 < 2; t0++) {
                FragU a, b_;
                a.u = *(const uint4*)&DT[l15 * 72 + t0 * 32 + quad * 8];
                b_.u = kdf[ktl][t0];
                acc = __builtin_amdgcn_mfma_f32_16x16x32_bf16(a.v, b_.v, acc, 0, 0, 0);
            }
            S0r[ktl] = acc;
        }
        __syncthreads();
    }
    {
        float4 a = *(const float4*)&vO[orow * 20 + oseg];
        float* d2 = o_g + (((long)b * L_SEQ + 15 * 64 + orow) * 16 + h) * 128L
                    + dc * 16 + oseg;
        *(float4*)d2 = a;
    }
}

// ---------------- gated RMS norm -> bf16 A2 ----------------------------------
__global__ __launch_bounds__(128) void gated_norm(
    const float* __restrict__ o, const u16* __restrict__ qkvz,
    const float* __restrict__ norm_w, u16* __restrict__ A2) {
    int bid = blockIdx.x;  // (b*L+l)*16 + h
    int t = threadIdx.x;   // 0..127
    float ov = o[(long)bid * 128 + t];
    float s = ov * ov;
#pragma unroll
    for (int off = 32; off > 0; off >>= 1) s += __shfl_down(s, off);
    __shared__ float ws2[2];
    if ((t & 63) == 0) ws2[t >> 6] = s;
    __syncthreads();
    float tot = ws2[0] + ws2[1];
    float rinv = rsqrtf(tot * (1.f / 128.f) + 1e-6f);
    int bl = bid >> 4, h = bid & 15;
    float z = bf2f(qkvz[(long)bl * NQKVZ + CONV_DIM + h * 128 + t]);
    float sig = 1.f / (1.f + expf(-z));
    float val = ov * rinv * norm_w[t] * sig;
    A2[(long)bl * 2048 + h * 128 + t] = f2bf(val);
}

// ---------------- host-side launcher -----------------------------------------
extern "C" void kernel_launch(void* const* d_in, const int* in_sizes, int n_in,
                              void* d_out, int out_size, void* d_ws, size_t ws_size,
                              hipStream_t stream) {
    const float* hs    = (const float*)d_in[0];
    const float* Wqkvz = (const float*)d_in[1];
    const float* Wba   = (const float*)d_in[2];
    const float* convw = (const float*)d_in[3];
    const float* convb = (const float*)d_in[4];
    const float* A_log = (const float*)d_in[5];
    const float* dtb   = (const float*)d_in[6];
    const float* normw = (const float*)d_in[7];
    const float* Wout  = (const float*)d_in[8];

    char* ws = (char*)d_ws;
    size_t off = 0;
    auto alloc = [&](size_t bytes) {
        size_t o = off;
        off = (off + bytes + 255) & ~(size_t)255;
        return o;
    };
    // region0: WqkvzT (bf16) — dead after GEMM1, reused for os (fp32)
    size_t r0 = alloc((size_t)NQKVZ * HID * 2);
    // region1: hs_bf16 — kept through ba_gemm; A2 aliases after
    size_t r1 = alloc((size_t)4096 * HID * 2);
    u16*   WqkvzT = (u16*)(ws + r0);
    float* os     = (float*)(ws + r0);
    u16*   hsb    = (u16*)(ws + r1);
    u16*   A2     = (u16*)(ws + r1);   // written by gated_norm after ba_gemm done
    u16*   qkvz   = (u16*)(ws + alloc((size_t)4096 * NQKVZ * 2));
    u16*   qs     = (u16*)(ws + alloc((size_t)64 * L_SEQ * DK * 2));
    u16*   ks     = (u16*)(ws + alloc((size_t)64 * L_SEQ * DK * 2));
    u16*   vs     = (u16*)(ws + alloc((size_t)64 * L_SEQ * DV * 2));
    float* gs     = (float*)(ws + alloc((size_t)64 * L_SEQ * 4));
    float* bs     = (float*)(ws + alloc((size_t)64 * L_SEQ * 4));
    u16*   WoutT  = (u16*)(ws + alloc((size_t)HID * 2048 * 2));
    u16*   WbaTb  = (u16*)(ws + alloc((size_t)32 * HID * 2));
    u16*   Tbuf   = (u16*)(ws + alloc((size_t)1024 * 4096 * 2));
    u16*   Pbuf   = (u16*)(ws + alloc((size_t)1024 * 4096 * 2));
    u16*   wbq    = (u16*)(ws + alloc((size_t)1024 * 8192 * 2));
    u16*   qlq    = (u16*)(ws + alloc((size_t)1024 * 8192 * 2));
    u16*   kdq    = (u16*)(ws + alloc((size_t)1024 * 8192 * 2));
    float* gamb   = (float*)(ws + alloc((size_t)1024 * 4));
    float* convwT = (float*)(ws + alloc((size_t)4 * CONV_DIM * 4));

    // 1. convert + transposes
    hipLaunchKernelGGL(f32_to_bf16, dim3(4096), dim3(256), 0, stream, hs, hsb);
    hipLaunchKernelGGL(transpose_f32_bf16, dim3(NQKVZ / 32, HID / 32), dim3(256), 0, stream,
                       Wqkvz, WqkvzT, HID, NQKVZ);
    hipLaunchKernelGGL(transpose_f32_bf16, dim3(2048 / 32, 2048 / 32), dim3(256), 0, stream,
                       Wout, WoutT, 2048, 2048);
    hipLaunchKernelGGL(transpose_f32_bf16, dim3(1, HID / 32), dim3(256), 0, stream,
                       Wba, WbaTb, HID, 32);
    hipLaunchKernelGGL(convw_transpose, dim3(CONV_DIM / 256), dim3(256), 0, stream,
                       convw, convwT);

    // 2. GEMM1: qkvz = hs @ W_qkvz (deep-prefetch 4-phase)
    hipLaunchKernelGGL(gemm1_8ph, dim3(512), dim3(512), 0, stream,
                       hsb, WqkvzT, qkvz);

    // 3. ba (MFMA, 128 blocks, wave-split ring) -> g, beta
    hipLaunchKernelGGL(ba_gemm, dim3(128), dim3(256), 0, stream,
                       hsb, WbaTb, A_log, dtb, gs, bs);

    // 4. conv + l2norm -> q,k,v (bf16), LDS-free shfl-reduce + XCD-swizzled
    hipLaunchKernelGGL(conv_qkv, dim3(4096), dim3(256), 0, stream,
                       qkvz, convwT, convb, qs, ks, vs);

    // 5a. chunk prep (parallel): T, P, wb, ql, kd, gam
    hipLaunchKernelGGL(gdn_prep, dim3(1024), dim3(256), 0, stream,
                       ks, qs, gs, bs, Tbuf, Pbuf, wbq, qlq, kdq, gamb);

    // 5b. chunk recurrence (MFMA, direct-global fragments, XCD-swizzled)
    hipLaunchKernelGGL(gdn_chunk, dim3(512), dim3(256), 0, stream,
                       vs, bs, Tbuf, Pbuf, wbq, qlq, kdq, gamb, os);

    // 6. gated RMS norm -> bf16 A2
    hipLaunchKernelGGL(gated_norm, dim3(4096 * NH), dim3(128), 0, stream,
                       os, qkvz, normw, A2);

    // 7. GEMM2: out = A2 @ W_out (256x128 2-phase counted-vmcnt)
    hipLaunchKernelGGL(gemm2_2ph, dim3(256), dim3(512), 0, stream,
                       A2, WoutT, (float*)d_out);
}

// Round 8
// 494.708 us; speedup vs baseline: 1.2116x; 1.0184x over previous
//
#include <hip/hip_runtime.h>

typedef unsigned short u16;
typedef unsigned int u32;
typedef short short8 __attribute__((ext_vector_type(8)));
typedef float float4v __attribute__((ext_vector_type(4)));

#define L_SEQ 1024
#define NB 4
#define NH 16
#define DK 128
#define DV 128
#define HID 2048
#define NQKVZ 8192
#define CONV_DIM 6144
#define GDN_SCALE 0.08838834764831845f  // 128^-0.5

static __device__ __forceinline__ float bf2f(u16 u) {
    union { u32 i; float f; } x; x.i = ((u32)u) << 16; return x.f;
}
static __device__ __forceinline__ u16 f2bf(float f) {
    union { float f; u32 u; } x; x.f = f;
    u32 r = x.u + 0x7FFF + ((x.u >> 16) & 1);
    return (u16)(r >> 16);
}

union FragU { short8 v; uint4 u; };

// async global->LDS, 16B per lane (lane-contiguous LDS dest required).
#define GLOAD_LDS16(g, l)                                        \
    __builtin_amdgcn_global_load_lds(                            \
        (const __attribute__((address_space(1))) void*)(g),      \
        (__attribute__((address_space(3))) void*)(l), 16, 0, 0)

// LDS-only barrier: no vmcnt(0) drain (in-flight global stores/loads keep
// flying). lgkmcnt(0) = my LDS ops done; s_barrier = everyone's done.
// sched_barrier(0) per rule: stop hipcc hoisting past the inline-asm wait.
#define LBAR() do {                                              \
    asm volatile("s_waitcnt lgkmcnt(0)" ::: "memory");           \
    __builtin_amdgcn_s_barrier();                                \
    __builtin_amdgcn_sched_barrier(0); } while (0)

// ---------------- merged preprocessing: convert + transposes -----------------
// 64x64 fp32->bf16 transpose tile: 256B-coalesced reads, 128B-contiguous
// uint4 writes (8 lanes/column), stride-65 LDS (2-way bank = free).
static __device__ __forceinline__ void transpose64(
    const float* __restrict__ in, u16* __restrict__ out, int R, int C,
    int bx, int by, float* tile, int t) {
#pragma unroll
    for (int i = 0; i < 4; i++) {
        int r = (t >> 4) + i * 16;
        int c4 = (t & 15) * 4;
        float4 v = *(const float4*)(in + (long)(by * 64 + r) * C + bx * 64 + c4);
        tile[r * 65 + c4 + 0] = v.x;
        tile[r * 65 + c4 + 1] = v.y;
        tile[r * 65 + c4 + 2] = v.z;
        tile[r * 65 + c4 + 3] = v.w;
    }
    __syncthreads();
#pragma unroll
    for (int p = 0; p < 2; p++) {
        int oc = (t >> 3) + p * 32;
        int orb = (t & 7) * 8;
        u16 vals[8];
#pragma unroll
        for (int k = 0; k < 8; k++) vals[k] = f2bf(tile[(orb + k) * 65 + oc]);
        *(uint4*)(out + (long)(bx * 64 + oc) * R + by * 64 + orb) = *(const uint4*)vals;
    }
}

// blocks: [0,4096) f32->bf16(hs) | [4096,8192) WqkvzT | [8192,9216) WoutT |
// [9216,9280) WbaT (32-tile) | [9280,9304) convwT. All independent.
__global__ __launch_bounds__(256) void prep_all(
    const float* __restrict__ hs, u16* __restrict__ hsb,
    const float* __restrict__ Wqkvz, u16* __restrict__ WqkvzT,
    const float* __restrict__ Wout, u16* __restrict__ WoutT,
    const float* __restrict__ Wba, u16* __restrict__ WbaTb,
    const float* __restrict__ convw, float* __restrict__ convwT) {
    __shared__ float tile[64 * 65];
    int id = blockIdx.x, t = threadIdx.x;
    if (id < 4096) {
        long i = ((long)id * 256 + t) * 8;
        float4 a = *(const float4*)(hs + i);
        float4 b = *(const float4*)(hs + i + 4);
        u16 tmp[8];
        tmp[0] = f2bf(a.x); tmp[1] = f2bf(a.y); tmp[2] = f2bf(a.z); tmp[3] = f2bf(a.w);
        tmp[4] = f2bf(b.x); tmp[5] = f2bf(b.y); tmp[6] = f2bf(b.z); tmp[7] = f2bf(b.w);
        *(uint4*)(hsb + i) = *(const uint4*)tmp;
    } else if (id < 8192) {
        int k = id - 4096;
        transpose64(Wqkvz, WqkvzT, HID, NQKVZ, k & 127, k >> 7, tile, t);
    } else if (id < 9216) {
        int k = id - 8192;
        transpose64(Wout, WoutT, 2048, 2048, k & 31, k >> 5, tile, t);
    } else if (id < 9280) {
        int by = id - 9216;       // Wba 2048x32 -> WbaTb 32x2048 (32-tile)
        int c = t & 31, r0 = t >> 5;
#pragma unroll
        for (int i = 0; i < 4; i++) {
            int r = r0 + i * 8;
            tile[r * 33 + c] = Wba[(long)(by * 32 + r) * 32 + c];
        }
        __syncthreads();
#pragma unroll
        for (int i = 0; i < 4; i++) {
            int r = r0 + i * 8;
            WbaTb[(long)r * HID + by * 32 + c] = f2bf(tile[c * 33 + r]);
        }
    } else {
        int c = (id - 9280) * 256 + t;
        float4 v = *(const float4*)(convw + c * 4);
        convwT[0 * CONV_DIM + c] = v.x;
        convwT[1 * CONV_DIM + c] = v.y;
        convwT[2 * CONV_DIM + c] = v.z;
        convwT[3 * CONV_DIM + c] = v.w;
    }
}

// ---------------- GEMM1: 256x256 tile, BK=64, m201-style 4-phase groups ------
// r2 schedule, measured-best (124.8-125.9 us). FROZEN: r3 remap and r7
// deep-prefetch both failed to beat it -> residual is LDS-issue/barrier cost.
#define G1_LDSU 32768  // u16 per dbuf (64 KB)

__global__ __launch_bounds__(512, 2) void gemm1_8ph(
    const u16* __restrict__ A, const u16* __restrict__ BT,
    u16* __restrict__ C) {
    const int K = HID, N = NQKVZ;
    __shared__ __align__(16) u16 lds[2 * G1_LDSU];  // 128 KB

    int t = threadIdx.x;
    int lane = t & 63, w = t >> 6, l15 = lane & 15, quad = lane >> 4;
    int wm = w & 1, wn = w >> 1;

    int orig = blockIdx.x;
    int wg = (orig & 7) * 64 + (orig >> 3);
    int p = wg >> 6, q = wg & 63;
    long blockM = (long)((p >> 2) * 8 + (q >> 3)) * 256;  // 0..15
    long blockN = (long)((p & 3) * 8 + (q & 7)) * 256;    // 0..31

    int srow = t >> 3;
    int scol = ((t & 7) ^ (srow & 7)) * 8;
    const u16* Ast = A + (blockM + srow) * (long)K + scol;
    const u16* Bst = BT + (blockN + srow) * (long)K + scol;

#define STA(db, qq, T) GLOAD_LDS16(Ast + (long)(qq) * 64 * K + (T) * 64,      \
                                   lds + (db) * G1_LDSU + (qq) * 4096 + t * 8)
#define STB(db, qq, T) GLOAD_LDS16(Bst + (long)(qq) * 64 * K + (T) * 64,      \
                                   lds + (db) * G1_LDSU + 16384 + (qq) * 4096 + t * 8)

    const int rowA0 = (wm * 128 + l15) * 64;
    const int rowB0 = 16384 + (wn * 64 + l15) * 64;
    const int cs0 = ((quad) ^ (l15 & 7)) * 8;        // kk=0 chunk
    const int cs1 = ((4 + quad) ^ (l15 & 7)) * 8;    // kk=1 chunk

    float4v acc[8][4];
#pragma unroll
    for (int mi = 0; mi < 8; mi++)
#pragma unroll
        for (int nj = 0; nj < 4; nj++) acc[mi][nj] = (float4v){0.f, 0.f, 0.f, 0.f};

    STA(0, 0, 0); STA(0, 1, 0); STA(0, 2, 0); STA(0, 3, 0);
    STB(0, 0, 0); STB(0, 1, 0); STB(0, 2, 0); STB(0, 3, 0);
    STA(1, 0, 1); STA(1, 2, 1);
    asm volatile("s_waitcnt vmcnt(2)" ::: "memory");
    __builtin_amdgcn_s_barrier();

    FragU bA[4][2], bB0[2][2], bB1[2][2];

    for (int g = 0; g < 32; ++g) {
        const int c = g & 1, db = c ^ 1;
        const u16* sb = lds + c * G1_LDSU;

        // ---- ph1 (mh0,nh0): 8 A-reads + 4 B-reads; stage T(g+1).Aq1,Aq3 ----
#pragma unroll
        for (int i = 0; i < 4; i++) {
            bA[i][0].u = *(const uint4*)(sb + rowA0 + i * 1024 + cs0);
            bA[i][1].u = *(const uint4*)(sb + rowA0 + i * 1024 + cs1);
        }
#pragma unroll
        for (int j = 0; j < 2; j++) {
            bB0[j][0].u = *(const uint4*)(sb + rowB0 + j * 1024 + cs0);
            bB0[j][1].u = *(const uint4*)(sb + rowB0 + j * 1024 + cs1);
        }
        if (g + 1 < 32) { STA(db, 1, g + 1); STA(db, 3, g + 1); }
        __builtin_amdgcn_s_barrier();
        asm volatile("s_waitcnt lgkmcnt(0)" ::: "memory");
        __builtin_amdgcn_s_setprio(1);
#pragma unroll
        for (int i = 0; i < 4; i++)
#pragma unroll
            for (int j = 0; j < 2; j++) {
                acc[i][j] = __builtin_amdgcn_mfma_f32_16x16x32_bf16(
                    bA[i][0].v, bB0[j][0].v, acc[i][j], 0, 0, 0);
                acc[i][j] = __builtin_amdgcn_mfma_f32_16x16x32_bf16(
                    bA[i][1].v, bB0[j][1].v, acc[i][j], 0, 0, 0);
            }
        __builtin_amdgcn_s_setprio(0);

        // ---- ph2 (mh0,nh1): 4 B-reads; stage T(g+1).Bq0,Bq1 ----
#pragma unroll
        for (int j = 0; j < 2; j++) {
            bB1[j][0].u = *(const uint4*)(sb + rowB0 + (2 + j) * 1024 + cs0);
            bB1[j][1].u = *(const uint4*)(sb + rowB0 + (2 + j) * 1024 + cs1);
        }
        if (g + 1 < 32) { STB(db, 0, g + 1); STB(db, 1, g + 1); }
        __builtin_amdgcn_s_barrier();
        asm volatile("s_waitcnt lgkmcnt(0)" ::: "memory");
        __builtin_amdgcn_s_setprio(1);
#pragma unroll
        for (int i = 0; i < 4; i++)
#pragma unroll
            for (int j = 0; j < 2; j++) {
                acc[i][2 + j] = __builtin_amdgcn_mfma_f32_16x16x32_bf16(
                    bA[i][0].v, bB1[j][0].v, acc[i][2 + j], 0, 0, 0);
                acc[i][2 + j] = __builtin_amdgcn_mfma_f32_16x16x32_bf16(
                    bA[i][1].v, bB1[j][1].v, acc[i][2 + j], 0, 0, 0);
            }
        __builtin_amdgcn_s_setprio(0);

        // ---- ph3 (mh1,nh0): 8 A-reads; stage T(g+1).Bq2,Bq3 ----
#pragma unroll
        for (int i = 0; i < 4; i++) {
            bA[i][0].u = *(const uint4*)(sb + rowA0 + (4 + i) * 1024 + cs0);
            bA[i][1].u = *(const uint4*)(sb + rowA0 + (4 + i) * 1024 + cs1);
        }
        if (g + 1 < 32) { STB(db, 2, g + 1); STB(db, 3, g + 1); }
        __builtin_amdgcn_s_barrier();
        asm volatile("s_waitcnt lgkmcnt(0)" ::: "memory");
        __builtin_amdgcn_s_setprio(1);
#pragma unroll
        for (int i = 0; i < 4; i++)
#pragma unroll
            for (int j = 0; j < 2; j++) {
                acc[4 + i][j] = __builtin_amdgcn_mfma_f32_16x16x32_bf16(
                    bA[i][0].v, bB0[j][0].v, acc[4 + i][j], 0, 0, 0);
                acc[4 + i][j] = __builtin_amdgcn_mfma_f32_16x16x32_bf16(
                    bA[i][1].v, bB0[j][1].v, acc[4 + i][j], 0, 0, 0);
            }
        __builtin_amdgcn_s_setprio(0);

        // ---- ph4 (mh1,nh1): 0 reads; stage T(g+2).Aq0,Aq2 into CURRENT dbuf
        if (g + 2 < 32) { STA(c, 0, g + 2); STA(c, 2, g + 2); }
        __builtin_amdgcn_s_barrier();
        __builtin_amdgcn_s_setprio(1);
#pragma unroll
        for (int i = 0; i < 4; i++)
#pragma unroll
            for (int j = 0; j < 2; j++) {
                acc[4 + i][2 + j] = __builtin_amdgcn_mfma_f32_16x16x32_bf16(
                    bA[i][0].v, bB1[j][0].v, acc[4 + i][2 + j], 0, 0, 0);
                acc[4 + i][2 + j] = __builtin_amdgcn_mfma_f32_16x16x32_bf16(
                    bA[i][1].v, bB1[j][1].v, acc[4 + i][2 + j], 0, 0, 0);
            }
        __builtin_amdgcn_s_setprio(0);

        if (g < 30)       { asm volatile("s_waitcnt vmcnt(2)" ::: "memory"); }
        else if (g == 30) { asm volatile("s_waitcnt vmcnt(0)" ::: "memory"); }
        __builtin_amdgcn_s_barrier();
    }

#pragma unroll
    for (int mi = 0; mi < 8; mi++) {
        long row0 = blockM + wm * 128 + mi * 16 + quad * 4;
#pragma unroll
        for (int nj = 0; nj < 4; nj++) {
            long col = blockN + wn * 64 + nj * 16 + l15;
#pragma unroll
            for (int r = 0; r < 4; r++)
                C[(row0 + r) * N + col] = f2bf(acc[mi][nj][r]);
        }
    }
#undef STA
#undef STB
}

// ---------------- GEMM2: 256x128 tile, BK=64, 2-phase, counted vmcnt ---------
#define G2_LDSU 24576  // u16 per dbuf (48 KB)

__global__ __launch_bounds__(512) void gemm2_2ph(
    const u16* __restrict__ A, const u16* __restrict__ BT,
    float* __restrict__ C) {
    const int K = HID, N = 2048;
    __shared__ __align__(16) u16 lds[2 * G2_LDSU];  // 96 KB

    int t = threadIdx.x;
    int lane = t & 63, w = t >> 6, l15 = lane & 15, quad = lane >> 4;
    int wm = w & 1, wn = w >> 1;

    int orig = blockIdx.x;
    int x = orig & 7, q = orig >> 3;           // q in 0..31
    long blockM = (long)((x >> 2) * 8 + (q >> 2)) * 256;   // 0..15
    long blockN = (long)((x & 3) * 4 + (q & 3)) * 128;     // 0..15

    int srow = t >> 3;
    int scol = ((t & 7) ^ (srow & 7)) * 8;
    const u16* Ast = A + (blockM + srow) * (long)K + scol;
    const u16* Bst = BT + (blockN + srow) * (long)K + scol;

#define STA2(db, qq, T) GLOAD_LDS16(Ast + (long)(qq) * 64 * K + (T) * 64,     \
                                    lds + (db) * G2_LDSU + (qq) * 4096 + t * 8)
#define STB2(db, hh, T) GLOAD_LDS16(Bst + (long)(hh) * 64 * K + (T) * 64,     \
                                    lds + (db) * G2_LDSU + 16384 + (hh) * 4096 + t * 8)

    const int cs0 = ((quad) ^ (l15 & 7)) * 8;
    const int cs1 = ((4 + quad) ^ (l15 & 7)) * 8;
    int offA[8], offB[2];
#pragma unroll
    for (int mi = 0; mi < 8; mi++)
        offA[mi] = (wm * 2 + (mi >> 2)) * 4096 + (((mi & 3) * 16 + l15)) * 64;
#pragma unroll
    for (int nj = 0; nj < 2; nj++)
        offB[nj] = 16384 + (wn >> 1) * 4096 + ((wn & 1) * 32 + nj * 16 + l15) * 64;

    float4v acc[8][2];
#pragma unroll
    for (int mi = 0; mi < 8; mi++)
#pragma unroll
        for (int nj = 0; nj < 2; nj++) acc[mi][nj] = (float4v){0.f, 0.f, 0.f, 0.f};

    STA2(0, 0, 0); STA2(0, 2, 0); STB2(0, 0, 0); STB2(0, 1, 0);
    STA2(0, 1, 0); STA2(0, 3, 0);
    STA2(1, 0, 1); STA2(1, 2, 1); STB2(1, 0, 1); STB2(1, 1, 1);
    asm volatile("s_waitcnt vmcnt(6)" ::: "memory");
    __builtin_amdgcn_s_barrier();

    FragU fA[4][2], fB[2][2];

    for (int g = 0; g < 32; ++g) {
        const int c = g & 1, db = c ^ 1;
        const u16* sb = lds + c * G2_LDSU;

        // ---- ph1 (mh0): reads A0-3 (8) + B (4); stage A13(g+1) -> db ----
#pragma unroll
        for (int i = 0; i < 4; i++) {
            fA[i][0].u = *(const uint4*)(sb + offA[i] + cs0);
            fA[i][1].u = *(const uint4*)(sb + offA[i] + cs1);
        }
#pragma unroll
        for (int j = 0; j < 2; j++) {
            fB[j][0].u = *(const uint4*)(sb + offB[j] + cs0);
            fB[j][1].u = *(const uint4*)(sb + offB[j] + cs1);
        }
        if (g < 31) { STA2(db, 1, g + 1); STA2(db, 3, g + 1); }
        asm volatile("s_waitcnt lgkmcnt(8)" ::: "memory");
        __builtin_amdgcn_s_barrier();
        __builtin_amdgcn_s_setprio(1);
#pragma unroll
        for (int i = 0; i < 4; i++)
#pragma unroll
            for (int j = 0; j < 2; j++) {
                acc[i][j] = __builtin_amdgcn_mfma_f32_16x16x32_bf16(
                    fA[i][0].v, fB[j][0].v, acc[i][j], 0, 0, 0);
                acc[i][j] = __builtin_amdgcn_mfma_f32_16x16x32_bf16(
                    fA[i][1].v, fB[j][1].v, acc[i][j], 0, 0, 0);
            }
        __builtin_amdgcn_s_setprio(0);

        // ---- ph2 (mh1): W2 wait; reads A4-7; stage A02+B(g+2) -> cur ----
        if (g < 31) { asm volatile("s_waitcnt vmcnt(6)" ::: "memory"); }
        else        { asm volatile("s_waitcnt vmcnt(0)" ::: "memory"); }
        __builtin_amdgcn_s_barrier();
        if (g < 30) { STA2(c, 0, g + 2); STA2(c, 2, g + 2);
                      STB2(c, 0, g + 2); STB2(c, 1, g + 2); }
#pragma unroll
        for (int i = 0; i < 4; i++) {
            fA[i][0].u = *(const uint4*)(sb + offA[4 + i] + cs0);
            fA[i][1].u = *(const uint4*)(sb + offA[4 + i] + cs1);
        }
        __builtin_amdgcn_s_setprio(1);
#pragma unroll
        for (int i = 0; i < 4; i++)
#pragma unroll
            for (int j = 0; j < 2; j++) {
                acc[4 + i][j] = __builtin_amdgcn_mfma_f32_16x16x32_bf16(
                    fA[i][0].v, fB[j][0].v, acc[4 + i][j], 0, 0, 0);
                acc[4 + i][j] = __builtin_amdgcn_mfma_f32_16x16x32_bf16(
                    fA[i][1].v, fB[j][1].v, acc[4 + i][j], 0, 0, 0);
            }
        __builtin_amdgcn_s_setprio(0);

        if (g < 30)       { asm volatile("s_waitcnt vmcnt(6)" ::: "memory"); }
        else if (g == 30) { asm volatile("s_waitcnt vmcnt(2)" ::: "memory"); }
        if (g < 31) __builtin_amdgcn_s_barrier();
    }

#pragma unroll
    for (int mi = 0; mi < 8; mi++) {
        long row0 = blockM + wm * 128 + mi * 16 + quad * 4;
#pragma unroll
        for (int nj = 0; nj < 2; nj++) {
            long col = blockN + wn * 32 + nj * 16 + l15;
#pragma unroll
            for (int r = 0; r < 4; r++)
                C[(row0 + r) * N + col] = acc[mi][nj][r];
        }
    }
#undef STA2
#undef STB2
}

// ---------------- ba as MFMA GEMM, 128 blocks, wave-split staging ------------
__global__ __launch_bounds__(256) void ba_gemm(
    const u16* __restrict__ hsb, const u16* __restrict__ WbaTb,
    const float* __restrict__ A_log, const float* __restrict__ dtb,
    float* __restrict__ gout, float* __restrict__ bout) {
    __shared__ u16 As[2][32 * 32];
    __shared__ u16 Bs[2][32 * 32];
    int t = threadIdx.x;
    int lane = t & 63, w = t >> 6, l15 = lane & 15, quad = lane >> 4;
    long blockM = (long)blockIdx.x * 32;

    float4v acc = (float4v){0.f, 0.f, 0.f, 0.f};

    int sidx = t & 127;
    const u16* Sg = (t < 128)
        ? hsb + (blockM + (sidx >> 2)) * (long)HID + (sidx & 3) * 8
        : WbaTb + (long)(sidx >> 2) * HID + (sidx & 3) * 8;
    u16* Sl0 = (t < 128) ? As[0] + sidx * 8 : Bs[0] + sidx * 8;
    u16* Sl1 = (t < 128) ? As[1] + sidx * 8 : Bs[1] + sidx * 8;

    GLOAD_LDS16(Sg + 0, Sl0);
    GLOAD_LDS16(Sg + 32, Sl1);

    const int wr = (w >> 1) * 16, wc = (w & 1) * 16;

    for (int k0 = 0; k0 < HID; k0 += 32) {
        int buf = (k0 >> 5) & 1;
        if (k0 < HID - 64) { asm volatile("s_waitcnt vmcnt(1)" ::: "memory"); }
        else               { asm volatile("s_waitcnt vmcnt(0)" ::: "memory"); }
        __builtin_amdgcn_s_barrier();
        FragU fa, fb;
        fa.u = *(const uint4*)(As[buf] + (wr + l15) * 32 + quad * 8);
        fb.u = *(const uint4*)(Bs[buf] + (wc + l15) * 32 + quad * 8);
        asm volatile("s_waitcnt lgkmcnt(0)" ::: "memory");
        __builtin_amdgcn_sched_barrier(0);
        __builtin_amdgcn_s_barrier();     // all reads done before overwrite
        if (k0 + 64 < HID) GLOAD_LDS16(Sg + k0 + 64, buf ? Sl1 : Sl0);
        acc = __builtin_amdgcn_mfma_f32_16x16x32_bf16(fa.v, fb.v, acc, 0, 0, 0);
    }

    {
        int n = wc + l15;
#pragma unroll
        for (int r = 0; r < 4; r++) {
            long m = blockM + wr + quad * 4 + r;
            int b = (int)(m >> 10), l = (int)(m & 1023);
            float v = acc[r];
            if (n < 16) {
                bout[((long)(b * NH + n)) * L_SEQ + l] = 1.f / (1.f + expf(-v));
            } else {
                int h = n - 16;
                float x = v + dtb[h];
                float sp = (x > 20.f) ? x : log1pf(expf(x));
                gout[((long)(b * NH + h)) * L_SEQ + l] = -expf(A_log[h]) * sp;
            }
        }
    }
}

// ---------------- conv(KS=4) + l2norm(q,k) + split v -> bf16 (v3) ------------
// LDS-free: 16 threads of a head are contiguous lanes; l2norm = 4 shfl_xor.
__global__ __launch_bounds__(256) void conv_qkv(
    const u16* __restrict__ qkvz, const float* __restrict__ wT,
    const float* __restrict__ conv_b,
    u16* __restrict__ qs, u16* __restrict__ ks, u16* __restrict__ vs) {
    int orig = blockIdx.x;
    int bl = ((orig & 7) << 9) + (orig >> 3);   // XCD swizzle, bijective
    int b = bl >> 10, l = bl & 1023;
    int t = threadIdx.x;
    const int ok3 = (l >= 3), ok2 = (l >= 2), ok1 = (l >= 1);
    const int h = t >> 4;
    const int d = (t & 15) * 8;

#pragma unroll
    for (int pass = 0; pass < 3; pass++) {
        int c = pass * 2048 + t * 8;
        long rowbase = (long)(b * L_SEQ + l) * NQKVZ + c;
        uint4 x0 = *(const uint4*)(qkvz + rowbase);
        uint4 x1 = ok1 ? *(const uint4*)(qkvz + rowbase - 1L * NQKVZ) : (uint4){0, 0, 0, 0};
        uint4 x2 = ok2 ? *(const uint4*)(qkvz + rowbase - 2L * NQKVZ) : (uint4){0, 0, 0, 0};
        uint4 x3 = ok3 ? *(const uint4*)(qkvz + rowbase - 3L * NQKVZ) : (uint4){0, 0, 0, 0};
        float w3[8], w2[8], w1[8], w0[8], bb[8];
        *(float4*)&w3[0] = *(const float4*)(wT + 0 * CONV_DIM + c);
        *(float4*)&w3[4] = *(const float4*)(wT + 0 * CONV_DIM + c + 4);
        *(float4*)&w2[0] = *(const float4*)(wT + 1 * CONV_DIM + c);
        *(float4*)&w2[4] = *(const float4*)(wT + 1 * CONV_DIM + c + 4);
        *(float4*)&w1[0] = *(const float4*)(wT + 2 * CONV_DIM + c);
        *(float4*)&w1[4] = *(const float4*)(wT + 2 * CONV_DIM + c + 4);
        *(float4*)&w0[0] = *(const float4*)(wT + 3 * CONV_DIM + c);
        *(float4*)&w0[4] = *(const float4*)(wT + 3 * CONV_DIM + c + 4);
        *(float4*)&bb[0] = *(const float4*)(conv_b + c);
        *(float4*)&bb[4] = *(const float4*)(conv_b + c + 4);
        const u16* p0 = (const u16*)&x0;
        const u16* p1 = (const u16*)&x1;
        const u16* p2 = (const u16*)&x2;
        const u16* p3 = (const u16*)&x3;
        float v[8];
#pragma unroll
        for (int j = 0; j < 8; j++) {
            float a = bb[j] + bf2f(p0[j]) * w0[j];
            if (ok1) a += bf2f(p1[j]) * w1[j];
            if (ok2) a += bf2f(p2[j]) * w2[j];
            if (ok3) a += bf2f(p3[j]) * w3[j];
            v[j] = a;
        }
        u16 outv[8];
        if (pass < 2) {
            float s = 0.f;
#pragma unroll
            for (int j = 0; j < 8; j++) s += v[j] * v[j];
            s += __shfl_xor(s, 1);
            s += __shfl_xor(s, 2);
            s += __shfl_xor(s, 4);
            s += __shfl_xor(s, 8);
            float r = rsqrtf(s + 1e-6f);
#pragma unroll
            for (int j = 0; j < 8; j++) outv[j] = f2bf(v[j] * r);
            u16* dst = (pass == 0) ? qs : ks;
            *(uint4*)&dst[(((long)(b * NH + h)) * L_SEQ + l) * DK + d] = *(const uint4*)outv;
        } else {
#pragma unroll
            for (int j = 0; j < 8; j++) outv[j] = f2bf(v[j]);
            *(uint4*)&vs[(((long)(b * NH + h)) * L_SEQ + l) * DV + d] = *(const uint4*)outv;
        }
    }
}

// ---------------- gdn_prep v2: per-chunk T, P, wb, ql, kd, gam ---------------
// All barriers are LDS-only (LBAR): no vmcnt drain -> the 48KB of wbq/qlq/kdq
// and P global stores overlap the serial fwd-subst solve.
__global__ __launch_bounds__(256) void gdn_prep(
    const u16* __restrict__ ks_g, const u16* __restrict__ qs_g,
    const float* __restrict__ g_g, const float* __restrict__ b_g,
    u16* __restrict__ Tbuf, u16* __restrict__ Pbuf,
    u16* __restrict__ wbq, u16* __restrict__ qlq, u16* __restrict__ kdq,
    float* __restrict__ gam_g) {
    int cid = blockIdx.x;
    int bh = cid >> 4;
    int ch = cid & 15;
    long rowbase = (long)bh * L_SEQ + ch * 64;
    int t = threadIdx.x;
    int lane = t & 63, w = t >> 6, l15 = lane & 15, quad = lane >> 4;

    __shared__ u16 Kl[64 * 136];
    __shared__ u16 Ql[64 * 136];
    __shared__ float Am[64 * 66];
    __shared__ float Tm[64 * 66];
    __shared__ float Tt[32 * 33];
    __shared__ float Gs[64], lamL[64], betaL[64], dlL[64];

    {   // stage K,Q rows bf16 -> padded LDS; stage g, beta
        int row = t >> 2, seg = (t & 3) * 32;
        const u16* ksrc = ks_g + (rowbase + row) * DK + seg;
        const u16* qsrc = qs_g + (rowbase + row) * DK + seg;
        *(uint4*)&Kl[row * 136 + seg]      = *(const uint4*)ksrc;
        *(uint4*)&Kl[row * 136 + seg + 8]  = *(const uint4*)(ksrc + 8);
        *(uint4*)&Kl[row * 136 + seg + 16] = *(const uint4*)(ksrc + 16);
        *(uint4*)&Kl[row * 136 + seg + 24] = *(const uint4*)(ksrc + 24);
        *(uint4*)&Ql[row * 136 + seg]      = *(const uint4*)qsrc;
        *(uint4*)&Ql[row * 136 + seg + 8]  = *(const uint4*)(qsrc + 8);
        *(uint4*)&Ql[row * 136 + seg + 16] = *(const uint4*)(qsrc + 16);
        *(uint4*)&Ql[row * 136 + seg + 24] = *(const uint4*)(qsrc + 24);
        if (t < 64) Gs[t] = g_g[rowbase + t];
        else if (t < 128) betaL[t - 64] = b_g[rowbase + t - 64];
    }
    LBAR();
    if (t < 64) {   // inclusive prefix scan (Kogge-Stone, wave 0)
        float gv = Gs[t];
#pragma unroll
        for (int off = 1; off < 64; off <<= 1) {
            float n = __shfl_up(gv, off);
            if (lane >= off) gv += n;
        }
        Gs[t] = gv;
    }
    LBAR();
    if (t < 64) {
        float G63 = Gs[63];
        float lm = expf(Gs[t]);
        lamL[t] = lm;
        dlL[t] = expf(G63 - Gs[t]);
        if (t == 0) gam_g[cid] = expf(G63);
    }
    // MFMA: KK^T and QK^T (wave w = row-stripe w*16)
    float4v accKK[4], accQK[4];
#pragma unroll
    for (int tj = 0; tj < 4; tj++) {
        accKK[tj] = (float4v){0.f, 0.f, 0.f, 0.f};
        accQK[tj] = (float4v){0.f, 0.f, 0.f, 0.f};
    }
#pragma unroll
    for (int k0 = 0; k0 < 128; k0 += 32) {
        FragU ka, qa;
        ka.u = *(const uint4*)&Kl[(w * 16 + l15) * 136 + k0 + quad * 8];
        qa.u = *(const uint4*)&Ql[(w * 16 + l15) * 136 + k0 + quad * 8];
#pragma unroll
        for (int tj = 0; tj < 4; tj++) {
            FragU kb;
            kb.u = *(const uint4*)&Kl[(tj * 16 + l15) * 136 + k0 + quad * 8];
            accKK[tj] = __builtin_amdgcn_mfma_f32_16x16x32_bf16(ka.v, kb.v, accKK[tj], 0, 0, 0);
            accQK[tj] = __builtin_amdgcn_mfma_f32_16x16x32_bf16(qa.v, kb.v, accQK[tj], 0, 0, 0);
        }
    }
    LBAR();   // lamL/betaL/dlL visible
    // mask + scale; Am -> LDS fp32, P -> global bf16
#pragma unroll
    for (int tj = 0; tj < 4; tj++) {
#pragma unroll
        for (int r = 0; r < 4; r++) {
            int ti_ = w * 16 + quad * 4 + r;
            int j = tj * 16 + l15;
            float e = (j <= ti_) ? expf(Gs[ti_] - Gs[j]) : 0.f;
            Am[ti_ * 66 + j] = (j < ti_) ? betaL[ti_] * e * accKK[tj][r] : 0.f;
            Pbuf[(long)cid * 4096 + ti_ * 64 + j] =
                (j <= ti_) ? f2bf(GDN_SCALE * e * accQK[tj][r]) : (u16)0;
        }
    }
    // wbq, qlq (row-major [64][128])
    {
        int row = t >> 2, seg = (t & 3) * 32;
        float sw = -betaL[row] * lamL[row];
        float sq = GDN_SCALE * lamL[row];
#pragma unroll
        for (int c0 = 0; c0 < 32; c0 += 8) {
            u16 wt[8], qt2[8];
#pragma unroll
            for (int j2 = 0; j2 < 8; j2++) {
                wt[j2]  = f2bf(sw * bf2f(Kl[row * 136 + seg + c0 + j2]));
                qt2[j2] = f2bf(sq * bf2f(Ql[row * 136 + seg + c0 + j2]));
            }
            *(uint4*)&wbq[(long)cid * 8192 + row * 128 + seg + c0] = *(uint4*)wt;
            *(uint4*)&qlq[(long)cid * 8192 + row * 128 + seg + c0] = *(uint4*)qt2;
        }
    }
    // kdq (transposed [128 k][64 t]) — all 256 threads
    {
        int k = t & 127, t0b = (t >> 7) * 32;
#pragma unroll
        for (int t0 = 0; t0 < 32; t0 += 8) {
            u16 tmp[8];
#pragma unroll
            for (int j2 = 0; j2 < 8; j2++)
                tmp[j2] = f2bf(dlL[t0b + t0 + j2] * bf2f(Kl[(t0b + t0 + j2) * 136 + k]));
            *(uint4*)&kdq[(long)cid * 8192 + k * 64 + t0b + t0] = *(uint4*)tmp;
        }
    }
    LBAR();
    // fwd-subst: T11 (lanes 0-31 of wave 0), T22 (lanes 0-31 of wave 1), zero T12
    if (t < 32) {
        int c = t;
        for (int i = 0; i < 32; i++) {
            float s = (i == c) ? 1.f : 0.f;
            for (int j = 0; j < i; j++) s -= Am[i * 66 + j] * Tm[j * 66 + c];
            Tm[i * 66 + c] = s;
        }
    } else if (t >= 64 && t < 96) {
        int c = 32 + (t - 64);
        for (int i = 32; i < 64; i++) {
            float s = (i == c) ? 1.f : 0.f;
            for (int j = 32; j < i; j++) s -= Am[i * 66 + j] * Tm[j * 66 + c];
            Tm[i * 66 + c] = s;
        }
    } else if (t >= 128 && t < 192) {
        int idx = t - 128;
        for (int kk = 0; kk < 16; kk++) {
            int e = idx * 16 + kk;
            Tm[(e >> 5) * 66 + 32 + (e & 31)] = 0.f;
        }
    }
    LBAR();
    {   // Tt = A21 * T11  (32x32, 4 elems/thread)
        int e0 = t * 4;
#pragma unroll
        for (int kk = 0; kk < 4; kk++) {
            int e = e0 + kk; int i = e >> 5, c = e & 31;
            float s = 0.f;
            for (int j = 0; j < 32; j++) s += Am[(32 + i) * 66 + j] * Tm[j * 66 + c];
            Tt[i * 33 + c] = s;
        }
    }
    LBAR();
    {   // T21 = -T22 * Tt
        int e0 = t * 4;
#pragma unroll
        for (int kk = 0; kk < 4; kk++) {
            int e = e0 + kk; int i = e >> 5, c = e & 31;
            float s = 0.f;
            for (int j = 0; j < 32; j++) s -= Tm[(32 + i) * 66 + 32 + j] * Tt[j * 33 + c];
            Tm[(32 + i) * 66 + c] = s;
        }
    }
    LBAR();
    {   // T -> global bf16
        int row = t >> 2, c0 = (t & 3) * 16;
        u16 tmp[16];
#pragma unroll
        for (int i = 0; i < 16; i++) tmp[i] = f2bf(Tm[row * 66 + c0 + i]);
        *(uint4*)&Tbuf[(long)cid * 4096 + row * 64 + c0]     = *(uint4*)tmp;
        *(uint4*)&Tbuf[(long)cid * 4096 + row * 64 + c0 + 8] = *(uint4*)(tmp + 8);
    }
}

// ---------------- gdn_chunk v3: direct-global fragments, 512 blocks ----------
// All barriers LDS-only (LBAR): the per-chunk O global store and fragment
// loads keep flying across phase boundaries instead of draining 64x/block.
__global__ __launch_bounds__(256) void gdn_chunk(
    const u16* __restrict__ vs_g, const float* __restrict__ b_g,
    const u16* __restrict__ Tq, const u16* __restrict__ Pq,
    const u16* __restrict__ wbq, const u16* __restrict__ qlq,
    const u16* __restrict__ kdq, const float* __restrict__ gam_g,
    float* __restrict__ o_g) {
    int orig = blockIdx.x;
    int bid = ((orig & 7) << 6) + (orig >> 3);   // 512 = 8 x 64, bijective
    int dc = bid & 7;
    int bh = bid >> 3;
    int b = bh >> 4, h = bh & 15;
    int t = threadIdx.x;
    int lane = t & 63, w = t >> 6, l15 = lane & 15, quad = lane >> 4;

    __shared__ u16 s0h[16 * 136], s0l[16 * 136];   // S0^T [v][k] hi/lo
    __shared__ float vO[64 * 20];                  // vb / O, [t][v]
    __shared__ u16 rhsT[16 * 72], DT[16 * 72];     // [v][t]

    float4v S0r[2];
    S0r[0] = (float4v){0.f, 0.f, 0.f, 0.f};
    S0r[1] = (float4v){0.f, 0.f, 0.f, 0.f};

    const int orow = t >> 2, oseg = (t & 3) * 4;   // 64 rows x 16 cols

    for (int ch = 0; ch < 16; ch++) {
        int cid = bh * 16 + ch;
        long rowbase = (long)bh * L_SEQ + ch * 64;
        float gam = gam_g[cid];

        const u16* wbp = wbq + (long)cid * 8192 + (w * 16 + l15) * 128 + quad * 8;
        uint4 wbf0 = *(const uint4*)(wbp);
        uint4 wbf1 = *(const uint4*)(wbp + 32);
        uint4 wbf2 = *(const uint4*)(wbp + 64);
        uint4 wbf3 = *(const uint4*)(wbp + 96);

        // ---- phase a: store prev O, load vb, split S0 ----
        if (ch > 0) {
            float4 a = *(const float4*)&vO[orow * 20 + oseg];
            float* d2 = o_g + (((long)b * L_SEQ + (ch - 1) * 64 + orow) * 16 + h) * 128L
                        + dc * 16 + oseg;
            *(float4*)d2 = a;
        }
        {
            float beta = b_g[rowbase + orow];
            uint2 vv = *(const uint2*)(vs_g + (rowbase + orow) * DV + dc * 16 + oseg);
            const u16* vp = (const u16*)&vv;
#pragma unroll
            for (int j2 = 0; j2 < 4; j2++)
                vO[orow * 20 + oseg + j2] = beta * bf2f(vp[j2]);
        }
#pragma unroll
        for (int ktl = 0; ktl < 2; ktl++) {
            int kc = (2 * w + ktl) * 16 + l15;
#pragma unroll
            for (int r = 0; r < 4; r++) {
                float x = S0r[ktl][r];
                u16 hi = f2bf(x);
                float lo = x - bf2f(hi);
                s0h[(quad * 4 + r) * 136 + kc] = hi;
                s0l[(quad * 4 + r) * 136 + kc] = f2bf(lo);
            }
        }
        LBAR();

        // ---- phase b: RHS[t][v] = vb + wb*(S0h+S0l) -> rhsT ----
        const u16* Tp = Tq + (long)cid * 4096 + (w * 16 + l15) * 64 + quad * 8;
        uint4 Tf0 = *(const uint4*)(Tp);
        uint4 Tf1 = *(const uint4*)(Tp + 32);
        {
            float4v acc;
#pragma unroll
            for (int r = 0; r < 4; r++)
                acc[r] = vO[(w * 16 + quad * 4 + r) * 20 + l15];
            uint4 wbf[4] = {wbf0, wbf1, wbf2, wbf3};
#pragma unroll
            for (int k0 = 0; k0 < 4; k0++) {
                FragU a, bh_, bl_;
                a.u = wbf[k0];
                bh_.u = *(const uint4*)&s0h[l15 * 136 + k0 * 32 + quad * 8];
                acc = __builtin_amdgcn_mfma_f32_16x16x32_bf16(a.v, bh_.v, acc, 0, 0, 0);
                bl_.u = *(const uint4*)&s0l[l15 * 136 + k0 * 32 + quad * 8];
                acc = __builtin_amdgcn_mfma_f32_16x16x32_bf16(a.v, bl_.v, acc, 0, 0, 0);
            }
            u16 tmp[4] = {f2bf(acc[0]), f2bf(acc[1]), f2bf(acc[2]), f2bf(acc[3])};
            *(uint2*)&rhsT[l15 * 72 + w * 16 + quad * 4] = *(uint2*)tmp;
        }
        LBAR();

        // ---- phase c: D = T*RHS -> DT ----
        const u16* qlp = qlq + (long)cid * 8192 + (w * 16 + l15) * 128 + quad * 8;
        uint4 qlf0 = *(const uint4*)(qlp);
        uint4 qlf1 = *(const uint4*)(qlp + 32);
        uint4 qlf2 = *(const uint4*)(qlp + 64);
        uint4 qlf3 = *(const uint4*)(qlp + 96);
        const u16* Pp = Pq + (long)cid * 4096 + (w * 16 + l15) * 64 + quad * 8;
        uint4 Pf0 = *(const uint4*)(Pp);
        uint4 Pf1 = *(const uint4*)(Pp + 32);
        {
            float4v acc = (float4v){0.f, 0.f, 0.f, 0.f};
            uint4 Tf[2] = {Tf0, Tf1};
#pragma unroll
            for (int k0 = 0; k0 < 2; k0++) {
                FragU a, b_;
                a.u = Tf[k0];
                b_.u = *(const uint4*)&rhsT[l15 * 72 + k0 * 32 + quad * 8];
                acc = __builtin_amdgcn_mfma_f32_16x16x32_bf16(a.v, b_.v, acc, 0, 0, 0);
            }
            u16 tmp[4] = {f2bf(acc[0]), f2bf(acc[1]), f2bf(acc[2]), f2bf(acc[3])};
            *(uint2*)&DT[l15 * 72 + w * 16 + quad * 4] = *(uint2*)tmp;
        }
        LBAR();

        // ---- phase d: O = ql*S0 + P*D ; S0 = gam*S0 + kd^T D ----
        uint4 kdf[2][2];
#pragma unroll
        for (int ktl = 0; ktl < 2; ktl++) {
            const u16* kdp = kdq + (long)cid * 8192 + ((2 * w + ktl) * 16 + l15) * 64 + quad * 8;
            kdf[ktl][0] = *(const uint4*)(kdp);
            kdf[ktl][1] = *(const uint4*)(kdp + 32);
        }
        {
            float4v acc = (float4v){0.f, 0.f, 0.f, 0.f};
            uint4 qlf[4] = {qlf0, qlf1, qlf2, qlf3};
#pragma unroll
            for (int k0 = 0; k0 < 4; k0++) {
                FragU a, bh_, bl_;
                a.u = qlf[k0];
                bh_.u = *(const uint4*)&s0h[l15 * 136 + k0 * 32 + quad * 8];
                acc = __builtin_amdgcn_mfma_f32_16x16x32_bf16(a.v, bh_.v, acc, 0, 0, 0);
                bl_.u = *(const uint4*)&s0l[l15 * 136 + k0 * 32 + quad * 8];
                acc = __builtin_amdgcn_mfma_f32_16x16x32_bf16(a.v, bl_.v, acc, 0, 0, 0);
            }
            uint4 Pf[2] = {Pf0, Pf1};
#pragma unroll
            for (int k0 = 0; k0 < 2; k0++) {
                FragU a, b_;
                a.u = Pf[k0];
                b_.u = *(const uint4*)&DT[l15 * 72 + k0 * 32 + quad * 8];
                acc = __builtin_amdgcn_mfma_f32_16x16x32_bf16(a.v, b_.v, acc, 0, 0, 0);
            }
#pragma unroll
            for (int r = 0; r < 4; r++)
                vO[(w * 16 + quad * 4 + r) * 20 + l15] = acc[r];
        }
#pragma unroll
        for (int ktl = 0; ktl < 2; ktl++) {
            float4v acc = S0r[ktl];
#pragma unroll
            for (int r = 0; r < 4; r++) acc[r] *= gam;
#pragma unroll
            for (int t0 = 0; t0 < 2; t0++) {
                FragU a, b_;
                a.u = *(const uint4*)&DT[l15 * 72 + t0 * 32 + quad * 8];
                b_.u = kdf[ktl][t0];
                acc = __builtin_amdgcn_mfma_f32_16x16x32_bf16(a.v, b_.v, acc, 0, 0, 0);
            }
            S0r[ktl] = acc;
        }
        LBAR();
    }
    {
        float4 a = *(const float4*)&vO[orow * 20 + oseg];
        float* d2 = o_g + (((long)b * L_SEQ + 15 * 64 + orow) * 16 + h) * 128L
                    + dc * 16 + oseg;
        *(float4*)d2 = a;
    }
}

// ---------------- gated RMS norm -> bf16 A2 ----------------------------------
__global__ __launch_bounds__(128) void gated_norm(
    const float* __restrict__ o, const u16* __restrict__ qkvz,
    const float* __restrict__ norm_w, u16* __restrict__ A2) {
    int bid = blockIdx.x;  // (b*L+l)*16 + h
    int t = threadIdx.x;   // 0..127
    float ov = o[(long)bid * 128 + t];
    float s = ov * ov;
#pragma unroll
    for (int off = 32; off > 0; off >>= 1) s += __shfl_down(s, off);
    __shared__ float ws2[2];
    if ((t & 63) == 0) ws2[t >> 6] = s;
    __syncthreads();
    float tot = ws2[0] + ws2[1];
    float rinv = rsqrtf(tot * (1.f / 128.f) + 1e-6f);
    int bl = bid >> 4, h = bid & 15;
    float z = bf2f(qkvz[(long)bl * NQKVZ + CONV_DIM + h * 128 + t]);
    float sig = 1.f / (1.f + expf(-z));
    float val = ov * rinv * norm_w[t] * sig;
    A2[(long)bl * 2048 + h * 128 + t] = f2bf(val);
}

// ---------------- host-side launcher -----------------------------------------
extern "C" void kernel_launch(void* const* d_in, const int* in_sizes, int n_in,
                              void* d_out, int out_size, void* d_ws, size_t ws_size,
                              hipStream_t stream) {
    const float* hs    = (const float*)d_in[0];
    const float* Wqkvz = (const float*)d_in[1];
    const float* Wba   = (const float*)d_in[2];
    const float* convw = (const float*)d_in[3];
    const float* convb = (const float*)d_in[4];
    const float* A_log = (const float*)d_in[5];
    const float* dtb   = (const float*)d_in[6];
    const float* normw = (const float*)d_in[7];
    const float* Wout  = (const float*)d_in[8];

    char* ws = (char*)d_ws;
    size_t off = 0;
    auto alloc = [&](size_t bytes) {
        size_t o = off;
        off = (off + bytes + 255) & ~(size_t)255;
        return o;
    };
    // region0: WqkvzT (bf16) — dead after GEMM1, reused for os (fp32)
    size_t r0 = alloc((size_t)NQKVZ * HID * 2);
    // region1: hs_bf16 — kept through ba_gemm; A2 aliases after
    size_t r1 = alloc((size_t)4096 * HID * 2);
    u16*   WqkvzT = (u16*)(ws + r0);
    float* os     = (float*)(ws + r0);
    u16*   hsb    = (u16*)(ws + r1);
    u16*   A2     = (u16*)(ws + r1);   // written by gated_norm after ba_gemm done
    u16*   qkvz   = (u16*)(ws + alloc((size_t)4096 * NQKVZ * 2));
    u16*   qs     = (u16*)(ws + alloc((size_t)64 * L_SEQ * DK * 2));
    u16*   ks     = (u16*)(ws + alloc((size_t)64 * L_SEQ * DK * 2));
    u16*   vs     = (u16*)(ws + alloc((size_t)64 * L_SEQ * DV * 2));
    float* gs     = (float*)(ws + alloc((size_t)64 * L_SEQ * 4));
    float* bs     = (float*)(ws + alloc((size_t)64 * L_SEQ * 4));
    u16*   WoutT  = (u16*)(ws + alloc((size_t)HID * 2048 * 2));
    u16*   WbaTb  = (u16*)(ws + alloc((size_t)32 * HID * 2));
    u16*   Tbuf   = (u16*)(ws + alloc((size_t)1024 * 4096 * 2));
    u16*   Pbuf   = (u16*)(ws + alloc((size_t)1024 * 4096 * 2));
    u16*   wbq    = (u16*)(ws + alloc((size_t)1024 * 8192 * 2));
    u16*   qlq    = (u16*)(ws + alloc((size_t)1024 * 8192 * 2));
    u16*   kdq    = (u16*)(ws + alloc((size_t)1024 * 8192 * 2));
    float* gamb   = (float*)(ws + alloc((size_t)1024 * 4));
    float* convwT = (float*)(ws + alloc((size_t)4 * CONV_DIM * 4));

    // 1. merged preprocessing: convert + all transposes (1 dispatch)
    hipLaunchKernelGGL(prep_all, dim3(9304), dim3(256), 0, stream,
                       hs, hsb, Wqkvz, WqkvzT, Wout, WoutT, Wba, WbaTb,
                       convw, convwT);

    // 2. GEMM1: qkvz = hs @ W_qkvz (r2 schedule, frozen)
    hipLaunchKernelGGL(gemm1_8ph, dim3(512), dim3(512), 0, stream,
                       hsb, WqkvzT, qkvz);

    // 3. ba (MFMA, 128 blocks, wave-split ring) -> g, beta
    hipLaunchKernelGGL(ba_gemm, dim3(128), dim3(256), 0, stream,
                       hsb, WbaTb, A_log, dtb, gs, bs);

    // 4. conv + l2norm -> q,k,v (bf16), LDS-free shfl-reduce + XCD-swizzled
    hipLaunchKernelGGL(conv_qkv, dim3(4096), dim3(256), 0, stream,
                       qkvz, convwT, convb, qs, ks, vs);

    // 5a. chunk prep (parallel): T, P, wb, ql, kd, gam
    hipLaunchKernelGGL(gdn_prep, dim3(1024), dim3(256), 0, stream,
                       ks, qs, gs, bs, Tbuf, Pbuf, wbq, qlq, kdq, gamb);

    // 5b. chunk recurrence (MFMA, direct-global fragments, XCD-swizzled)
    hipLaunchKernelGGL(gdn_chunk, dim3(512), dim3(256), 0, stream,
                       vs, bs, Tbuf, Pbuf, wbq, qlq, kdq, gamb, os);

    // 6. gated RMS norm -> bf16 A2
    hipLaunchKernelGGL(gated_norm, dim3(4096 * NH), dim3(128), 0, stream,
                       os, qkvz, normw, A2);

    // 7. GEMM2: out = A2 @ W_out (256x128 2-phase counted-vmcnt)
    hipLaunchKernelGGL(gemm2_2ph, dim3(256), dim3(512), 0, stream,
                       A2, WoutT, (float*)d_out);
}